// Round 1
// baseline (1218.889 us; speedup 1.0000x reference)
//
#include <hip/hip_runtime.h>
#include <hip/hip_bf16.h>

// GraphSAINT 2-layer GCN forward on MI355X.
// Pipeline: degree count -> exclusive scan -> counting-sort edges by dst (CSR)
//           -> gemm1 (x@W1, row-scaled by dis) -> agg1 (CSR gather-sum)
//           -> BN stats -> gemm2 (BN+ReLU fused into A-load, row-scaled)
//           -> agg2 -> output.
// GCN identity used: out[d] = dis[d]*(sum_{e:dst=d} g[src] + g[d]) + b,
// where g[n] = dis[n]*(h[n]@W), dis[n] = rsqrt(deg_in[n]+1).

#define IN_F  128
#define HID_F 256
#define OUT_F 64

__global__ void count_kernel(const int* __restrict__ dst, int* __restrict__ deg_e, int E) {
    int i = blockIdx.x * 256 + threadIdx.x;
    if (i < E) atomicAdd(&deg_e[dst[i]], 1);
}

// Block-level exclusive scan (Hillis-Steele in LDS); also computes dis = rsqrt(deg+1).
__global__ void scan1_kernel(const int* __restrict__ deg_e, int* __restrict__ offsets,
                             int* __restrict__ blocksums, float* __restrict__ dis, int N) {
    __shared__ int sh[512];
    int i = blockIdx.x * 512 + threadIdx.x;
    int v = (i < N) ? deg_e[i] : 0;
    if (i < N) dis[i] = rsqrtf((float)(v + 1));
    sh[threadIdx.x] = v;
    __syncthreads();
    for (int off = 1; off < 512; off <<= 1) {
        int t = (threadIdx.x >= off) ? sh[threadIdx.x - off] : 0;
        __syncthreads();
        sh[threadIdx.x] += t;
        __syncthreads();
    }
    if (i < N) offsets[i] = sh[threadIdx.x] - v;  // exclusive within block
    if (threadIdx.x == 511) blocksums[blockIdx.x] = sh[511];
}

__global__ void scan2_kernel(int* __restrict__ blocksums, int nb) {
    if (threadIdx.x == 0) {
        int acc = 0;
        for (int b = 0; b < nb; b++) { int v = blocksums[b]; blocksums[b] = acc; acc += v; }
    }
}

__global__ void scan3_kernel(int* __restrict__ offsets, const int* __restrict__ blocksums,
                             int* __restrict__ cursor, int N) {
    int i = blockIdx.x * 512 + threadIdx.x;
    if (i < N) {
        int o = offsets[i] + blocksums[blockIdx.x];
        offsets[i] = o;
        cursor[i] = o;
    }
}

__global__ void scatter_kernel(const int* __restrict__ src, const int* __restrict__ dst,
                               int* __restrict__ cursor, int* __restrict__ ssrc, int E) {
    int i = blockIdx.x * 256 + threadIdx.x;
    if (i < E) {
        int d = dst[i];
        int pos = atomicAdd(&cursor[d], 1);
        ssrc[pos] = src[i];
    }
}

// g1[n][j] = dis[n] * sum_k x[n][k]*W1[k][j].  32 nodes x 256 cols per block.
__global__ void gemm1_kernel(const float* __restrict__ x, const float* __restrict__ W1,
                             const float* __restrict__ dis, float* __restrict__ g1, int N) {
    __shared__ float xs[32][IN_F];
    int j = threadIdx.x;            // output column 0..255
    int n0 = blockIdx.x * 32;
    for (int t = threadIdx.x; t < 32 * IN_F; t += 256) {
        int n = t >> 7, k = t & 127;
        int node = n0 + n;
        xs[n][k] = (node < N) ? x[(size_t)node * IN_F + k] : 0.f;
    }
    __syncthreads();
    float acc[32];
#pragma unroll
    for (int n = 0; n < 32; n++) acc[n] = 0.f;
    for (int k = 0; k < IN_F; k++) {
        float w = W1[k * HID_F + j];
#pragma unroll
        for (int n = 0; n < 32; n++) acc[n] = fmaf(xs[n][k], w, acc[n]);
    }
    for (int n = 0; n < 32; n++) {
        int node = n0 + n;
        if (node < N) g1[(size_t)node * HID_F + j] = dis[node] * acc[n];
    }
}

// out1[n][j] = dis[n]*(g1[n][j] + sum over CSR bucket of g1[src][j]) + b1[j]
__global__ void agg1_kernel(const float* __restrict__ g1, const int* __restrict__ ssrc,
                            const int* __restrict__ offsets, const int* __restrict__ deg_e,
                            const float* __restrict__ dis, const float* __restrict__ b1,
                            float* __restrict__ out1, int N) {
    int n = blockIdx.x;
    int j = threadIdx.x;
    float acc = g1[(size_t)n * HID_F + j];  // self-loop term
    int start = offsets[n], cnt = deg_e[n];
    for (int i = 0; i < cnt; i++) {
        int s = ssrc[start + i];
        acc += g1[(size_t)s * HID_F + j];
    }
    out1[(size_t)n * HID_F + j] = dis[n] * acc + b1[j];
}

__global__ void bnreduce_kernel(const float* __restrict__ out1, float* __restrict__ sums,
                                float* __restrict__ sumsq, int N) {
    int j = threadIdx.x;
    int r0 = blockIdx.x * 256;
    float s = 0.f, sq = 0.f;
    for (int r = 0; r < 256; r++) {
        int row = r0 + r;
        if (row < N) {
            float v = out1[(size_t)row * HID_F + j];
            s += v;
            sq += v * v;
        }
    }
    atomicAdd(&sums[j], s);
    atomicAdd(&sumsq[j], sq);
}

__global__ void bnfinal_kernel(float* __restrict__ bn, const float* __restrict__ gamma,
                               const float* __restrict__ beta, int N) {
    int j = threadIdx.x;
    float invN = 1.0f / (float)N;
    float mean = bn[j] * invN;
    float var = bn[256 + j] * invN - mean * mean;
    float sc = gamma[j] * rsqrtf(fmaxf(var, 0.f) + 1e-5f);
    bn[512 + j] = sc;                 // scale
    bn[768 + j] = beta[j] - mean * sc;  // bias
}

// g2[n][j] = dis[n] * sum_k relu(out1[n][k]*bnscale[k]+bnbias[k]) * W2[k][j]
// 64 nodes x 64 cols per block; 4 waves, each wave owns 16 nodes.
__global__ void gemm2_kernel(const float* __restrict__ out1, const float* __restrict__ W2,
                             const float* __restrict__ dis, const float* __restrict__ bn,
                             float* __restrict__ g2, int N) {
    __shared__ float as[64][65];
    const float* bnscale = bn + 512;
    const float* bnbias  = bn + 768;
    int j = threadIdx.x & 63;
    int grp = threadIdx.x >> 6;  // 0..3
    int n0 = blockIdx.x * 64;
    float acc[16];
#pragma unroll
    for (int i = 0; i < 16; i++) acc[i] = 0.f;
    for (int kc = 0; kc < HID_F; kc += 64) {
        __syncthreads();
        for (int t = threadIdx.x; t < 64 * 64; t += 256) {
            int n = t >> 6, kk = t & 63;
            int node = n0 + n;
            float v = 0.f;
            if (node < N) {
                v = out1[(size_t)node * HID_F + kc + kk];
                v = fmaf(v, bnscale[kc + kk], bnbias[kc + kk]);
                v = v > 0.f ? v : 0.f;
            }
            as[n][kk] = v;
        }
        __syncthreads();
        for (int kk = 0; kk < 64; kk++) {
            float w = W2[(kc + kk) * OUT_F + j];
#pragma unroll
            for (int i = 0; i < 16; i++)
                acc[i] = fmaf(as[grp * 16 + i][kk], w, acc[i]);
        }
    }
#pragma unroll
    for (int i = 0; i < 16; i++) {
        int node = n0 + grp * 16 + i;
        if (node < N) g2[(size_t)node * OUT_F + j] = dis[node] * acc[i];
    }
}

// out[n][j] = dis[n]*(g2[n][j] + bucket sum) + b2[j].  4 nodes/block, 1 wave each.
__global__ void agg2_kernel(const float* __restrict__ g2, const int* __restrict__ ssrc,
                            const int* __restrict__ offsets, const int* __restrict__ deg_e,
                            const float* __restrict__ dis, const float* __restrict__ b2,
                            float* __restrict__ out, int N) {
    int wave = threadIdx.x >> 6;
    int j = threadIdx.x & 63;
    int n = blockIdx.x * 4 + wave;
    if (n >= N) return;
    float acc = g2[(size_t)n * OUT_F + j];
    int start = offsets[n], cnt = deg_e[n];
    for (int i = 0; i < cnt; i++) {
        int s = ssrc[start + i];
        acc += g2[(size_t)s * OUT_F + j];
    }
    out[(size_t)n * OUT_F + j] = dis[n] * acc + b2[j];
}

extern "C" void kernel_launch(void* const* d_in, const int* in_sizes, int n_in,
                              void* d_out, int out_size, void* d_ws, size_t ws_size,
                              hipStream_t stream) {
    const float* x      = (const float*)d_in[0];
    const int*   edges  = (const int*)d_in[1];
    const float* W1     = (const float*)d_in[2];
    const float* b1     = (const float*)d_in[3];
    const float* gamma1 = (const float*)d_in[4];
    const float* beta1  = (const float*)d_in[5];
    const float* W2     = (const float*)d_in[6];
    const float* b2     = (const float*)d_in[7];
    float* out = (float*)d_out;

    int N = in_sizes[0] / IN_F;
    int E = in_sizes[1] / 2;
    const int* src = edges;
    const int* dst = edges + E;

    // Workspace carve-up (~213 MB total; g2 aliases g1, which is dead by gemm2).
    char* ws = (char*)d_ws;
    size_t off = 0;
    auto alloc = [&](size_t bytes) -> void* {
        void* p = ws + off;
        off += (bytes + 255) & ~(size_t)255;
        return p;
    };
    int*   deg_e     = (int*)alloc((size_t)N * 4);
    int*   offsets   = (int*)alloc((size_t)N * 4);
    int*   cursor    = (int*)alloc((size_t)N * 4);
    int*   blocksums = (int*)alloc(1024);
    float* dis       = (float*)alloc((size_t)N * 4);
    int*   ssrc      = (int*)alloc((size_t)E * 4);
    float* g1        = (float*)alloc((size_t)N * HID_F * 4);
    float* out1      = (float*)alloc((size_t)N * HID_F * 4);
    float* bn        = (float*)alloc(4 * 256 * 4);  // sums | sumsq | scale | bias
    float* g2        = g1;  // alias: g1 last read in agg1, g2 first written in gemm2

    hipMemsetAsync(deg_e, 0, (size_t)N * 4, stream);
    hipMemsetAsync(bn, 0, 2 * 256 * 4, stream);

    count_kernel<<<(E + 255) / 256, 256, 0, stream>>>(dst, deg_e, E);

    int nb1 = (N + 511) / 512;
    scan1_kernel<<<nb1, 512, 0, stream>>>(deg_e, offsets, blocksums, dis, N);
    scan2_kernel<<<1, 64, 0, stream>>>(blocksums, nb1);
    scan3_kernel<<<nb1, 512, 0, stream>>>(offsets, blocksums, cursor, N);
    scatter_kernel<<<(E + 255) / 256, 256, 0, stream>>>(src, dst, cursor, ssrc, E);

    gemm1_kernel<<<(N + 31) / 32, 256, 0, stream>>>(x, W1, dis, g1, N);
    agg1_kernel<<<N, 256, 0, stream>>>(g1, ssrc, offsets, deg_e, dis, b1, out1, N);
    bnreduce_kernel<<<(N + 255) / 256, 256, 0, stream>>>(out1, bn, bn + 256, N);
    bnfinal_kernel<<<1, 256, 0, stream>>>(bn, gamma1, beta1, N);
    gemm2_kernel<<<(N + 63) / 64, 256, 0, stream>>>(out1, W2, dis, bn, g2, N);
    agg2_kernel<<<(N + 3) / 4, 256, 0, stream>>>(g2, ssrc, offsets, deg_e, dis, b2, out, N);
}

// Round 3
// 744.144 us; speedup vs baseline: 1.6380x; 1.6380x over previous
//
#include <hip/hip_runtime.h>
#include <hip/hip_bf16.h>

// GraphSAINT 2-layer GCN forward on MI355X.
// Key identity: aggregation commutes with the linear transform.
// Layer 1: z[d] = dis[d]*(sum_e dis[s]*x[s] + dis[d]*x[d])  (128-dim gather),
//          out1 = z @ W1 + b1.
// Layer 2: g2[n] = dis[n]*(relu(bn(out1[n])) @ W2)  (GEMM first),
//          out[d] = dis[d]*(sum_e g2[s] + g2[d]) + b2  (64-dim gather).
// dis[n] = rsqrt(deg_in[n] + 1)  (self-loops).

#define IN_F  128
#define HID_F 256
#define OUT_F 64

__device__ __forceinline__ int bcast_i(int v, int l) {
    return __builtin_amdgcn_readlane(v, l);
}
__device__ __forceinline__ float bcast_f(float v, int l) {
    return __int_as_float(__builtin_amdgcn_readlane(__float_as_int(v), l));
}

__global__ void count_kernel(const int* __restrict__ dst, int* __restrict__ deg_e, int E) {
    int i = blockIdx.x * 256 + threadIdx.x;
    if (i < E) atomicAdd(&deg_e[dst[i]], 1);
}

// Block-level exclusive scan; also computes dis = rsqrt(deg+1).
__global__ void scan1_kernel(const int* __restrict__ deg_e, int* __restrict__ offsets,
                             int* __restrict__ blocksums, float* __restrict__ dis, int N) {
    __shared__ int sh[512];
    int i = blockIdx.x * 512 + threadIdx.x;
    int v = (i < N) ? deg_e[i] : 0;
    if (i < N) dis[i] = rsqrtf((float)(v + 1));
    sh[threadIdx.x] = v;
    __syncthreads();
    for (int off = 1; off < 512; off <<= 1) {
        int t = (threadIdx.x >= off) ? sh[threadIdx.x - off] : 0;
        __syncthreads();
        sh[threadIdx.x] += t;
        __syncthreads();
    }
    if (i < N) offsets[i] = sh[threadIdx.x] - v;
    if (threadIdx.x == 511) blocksums[blockIdx.x] = sh[511];
}

__global__ void scan2_kernel(int* __restrict__ blocksums, int nb) {
    if (threadIdx.x == 0) {
        int acc = 0;
        for (int b = 0; b < nb; b++) { int v = blocksums[b]; blocksums[b] = acc; acc += v; }
    }
}

__global__ void scan3_kernel(int* __restrict__ offsets, const int* __restrict__ blocksums,
                             int* __restrict__ cursor, int N) {
    int i = blockIdx.x * 512 + threadIdx.x;
    if (i < N) {
        int o = offsets[i] + blocksums[blockIdx.x];
        offsets[i] = o;
        cursor[i] = o;
    }
}

// Counting-sort edges by dst; also stash dis[src] per edge for the layer-1 gather.
__global__ void scatter_kernel(const int* __restrict__ src, const int* __restrict__ dst,
                               const float* __restrict__ dis, int* __restrict__ cursor,
                               int* __restrict__ ssrc, float* __restrict__ sdis, int E) {
    int i = blockIdx.x * 256 + threadIdx.x;
    if (i < E) {
        int d = dst[i];
        int s = src[i];
        int pos = atomicAdd(&cursor[d], 1);
        ssrc[pos] = s;
        sdis[pos] = dis[s];
    }
}

// z[d] = dis[d]*(sum_e dis[s]*x[s] + dis[d]*x[d]).  One wave per node, float2 lanes.
__global__ void aggx_kernel(const float* __restrict__ x, const int* __restrict__ ssrc,
                            const float* __restrict__ sdis, const int* __restrict__ offsets,
                            const int* __restrict__ deg_e, const float* __restrict__ dis,
                            float* __restrict__ z, int N) {
    int lane = threadIdx.x & 63;
    int n = blockIdx.x * 4 + (threadIdx.x >> 6);
    if (n >= N) return;
    float dn = dis[n];
    float2 self = ((const float2*)(x + (size_t)n * IN_F))[lane];
    float accx = dn * self.x, accy = dn * self.y;
    int start = offsets[n], cnt = deg_e[n];
    for (int base = 0; base < cnt; base += 64) {
        int idx = base + lane;
        int sv = 0; float dv = 0.f;
        if (idx < cnt) { sv = ssrc[start + idx]; dv = sdis[start + idx]; }
        int m = min(64, cnt - base);
#pragma unroll 4
        for (int j = 0; j < m; j++) {
            int s = bcast_i(sv, j);          // SGPR-uniform row index
            float ds = bcast_f(dv, j);
            float2 v = ((const float2*)(x + (size_t)s * IN_F))[lane];
            accx = fmaf(ds, v.x, accx);
            accy = fmaf(ds, v.y, accy);
        }
    }
    ((float2*)(z + (size_t)n * IN_F))[lane] = make_float2(dn * accx, dn * accy);
}

// out1 = z @ W1 + b1.  Tile 32 nodes x 256 cols; thread owns 16 nodes x 2 cols.
__global__ __launch_bounds__(256) void gemm1_kernel(const float* __restrict__ z,
                                                    const float* __restrict__ W1,
                                                    const float* __restrict__ b1,
                                                    float* __restrict__ out1, int N) {
    __shared__ float4 zs[32][32];  // [node][k/4] = 16 KB
    int t = threadIdx.x;
    int n0 = blockIdx.x * 32;
    int half = t >> 7;       // 0..1 -> node half
    int c = (t & 127) * 2;   // col pair
    for (int i = t; i < 32 * 32; i += 256) {
        int n = i >> 5, k4 = i & 31;
        int node = n0 + n;
        zs[n][k4] = (node < N) ? ((const float4*)(z + (size_t)node * IN_F))[k4]
                               : make_float4(0.f, 0.f, 0.f, 0.f);
    }
    __syncthreads();
    float acc[16][2];
#pragma unroll
    for (int i = 0; i < 16; i++) { acc[i][0] = 0.f; acc[i][1] = 0.f; }
    for (int k0 = 0; k0 < 32; k0++) {
        float2 w0 = *(const float2*)(W1 + (size_t)(4 * k0 + 0) * HID_F + c);
        float2 w1 = *(const float2*)(W1 + (size_t)(4 * k0 + 1) * HID_F + c);
        float2 w2 = *(const float2*)(W1 + (size_t)(4 * k0 + 2) * HID_F + c);
        float2 w3 = *(const float2*)(W1 + (size_t)(4 * k0 + 3) * HID_F + c);
#pragma unroll
        for (int i = 0; i < 16; i++) {
            float4 zv = zs[half * 16 + i][k0];  // wave-broadcast LDS read
            acc[i][0] = fmaf(zv.x, w0.x, acc[i][0]);
            acc[i][1] = fmaf(zv.x, w0.y, acc[i][1]);
            acc[i][0] = fmaf(zv.y, w1.x, acc[i][0]);
            acc[i][1] = fmaf(zv.y, w1.y, acc[i][1]);
            acc[i][0] = fmaf(zv.z, w2.x, acc[i][0]);
            acc[i][1] = fmaf(zv.z, w2.y, acc[i][1]);
            acc[i][0] = fmaf(zv.w, w3.x, acc[i][0]);
            acc[i][1] = fmaf(zv.w, w3.y, acc[i][1]);
        }
    }
    float2 bb = *(const float2*)(b1 + c);
#pragma unroll
    for (int i = 0; i < 16; i++) {
        int node = n0 + half * 16 + i;
        if (node < N)
            *(float2*)(out1 + (size_t)node * HID_F + c) =
                make_float2(acc[i][0] + bb.x, acc[i][1] + bb.y);
    }
}

// Per-column sum and sum-of-squares of out1 (for BN).  128 rows per block.
__global__ void bnreduce_kernel(const float* __restrict__ out1, float* __restrict__ sums,
                                float* __restrict__ sumsq, int N) {
    int j = threadIdx.x;
    int r0 = blockIdx.x * 128;
    float s = 0.f, sq = 0.f;
    int rend = min(128, N - r0);
    for (int r = 0; r < rend; r++) {
        float v = out1[(size_t)(r0 + r) * HID_F + j];
        s += v;
        sq = fmaf(v, v, sq);
    }
    atomicAdd(&sums[j], s);
    atomicAdd(&sumsq[j], sq);
}

__global__ void bnfinal_kernel(float* __restrict__ bn, const float* __restrict__ gamma,
                               const float* __restrict__ beta, int N) {
    int j = threadIdx.x;
    float invN = 1.0f / (float)N;
    float mean = bn[j] * invN;
    float var = bn[256 + j] * invN - mean * mean;
    float sc = gamma[j] * rsqrtf(fmaxf(var, 0.f) + 1e-5f);
    bn[512 + j] = sc;
    bn[768 + j] = beta[j] - mean * sc;
}

// g2[n] = dis[n]*(relu(bn(out1[n])) @ W2).  Tile 64 nodes x 64 cols; thread owns 4x4.
__global__ __launch_bounds__(256) void gemm2_kernel(const float* __restrict__ out1,
                                                    const float* __restrict__ W2,
                                                    const float* __restrict__ dis,
                                                    const float* __restrict__ bn,
                                                    float* __restrict__ g2, int N) {
    __shared__ float as[64][68];  // +4 pad -> conflict-free 4-row broadcast reads
    const float* bnscale = bn + 512;
    const float* bnbias  = bn + 768;
    int t = threadIdx.x;
    int n0 = blockIdx.x * 64;
    int tc = t & 15, tr = t >> 4;
    int c4 = tc * 4;
    float acc[4][4];
#pragma unroll
    for (int i = 0; i < 4; i++)
#pragma unroll
        for (int jj = 0; jj < 4; jj++) acc[i][jj] = 0.f;
    for (int kc = 0; kc < HID_F; kc += 64) {
        // stage 64x64 A-chunk with BN+ReLU fused (64*16 float4s over 256 threads)
        for (int i = t; i < 64 * 16; i += 256) {
            int n = i >> 4, k4 = (i & 15) * 4;
            int node = n0 + n;
            float4 v = make_float4(0.f, 0.f, 0.f, 0.f);
            if (node < N) {
                v = *(const float4*)(out1 + (size_t)node * HID_F + kc + k4);
                float4 scl = *(const float4*)(bnscale + kc + k4);
                float4 bia = *(const float4*)(bnbias + kc + k4);
                v.x = fmaxf(fmaf(v.x, scl.x, bia.x), 0.f);
                v.y = fmaxf(fmaf(v.y, scl.y, bia.y), 0.f);
                v.z = fmaxf(fmaf(v.z, scl.z, bia.z), 0.f);
                v.w = fmaxf(fmaf(v.w, scl.w, bia.w), 0.f);
            }
            *(float4*)(&as[n][k4]) = v;
        }
        __syncthreads();
        for (int kk = 0; kk < 64; kk++) {
            float4 w = *(const float4*)(W2 + (size_t)(kc + kk) * OUT_F + c4);
            float a0 = as[tr * 4 + 0][kk];
            float a1 = as[tr * 4 + 1][kk];
            float a2 = as[tr * 4 + 2][kk];
            float a3 = as[tr * 4 + 3][kk];
            acc[0][0] = fmaf(a0, w.x, acc[0][0]); acc[0][1] = fmaf(a0, w.y, acc[0][1]);
            acc[0][2] = fmaf(a0, w.z, acc[0][2]); acc[0][3] = fmaf(a0, w.w, acc[0][3]);
            acc[1][0] = fmaf(a1, w.x, acc[1][0]); acc[1][1] = fmaf(a1, w.y, acc[1][1]);
            acc[1][2] = fmaf(a1, w.z, acc[1][2]); acc[1][3] = fmaf(a1, w.w, acc[1][3]);
            acc[2][0] = fmaf(a2, w.x, acc[2][0]); acc[2][1] = fmaf(a2, w.y, acc[2][1]);
            acc[2][2] = fmaf(a2, w.z, acc[2][2]); acc[2][3] = fmaf(a2, w.w, acc[2][3]);
            acc[3][0] = fmaf(a3, w.x, acc[3][0]); acc[3][1] = fmaf(a3, w.y, acc[3][1]);
            acc[3][2] = fmaf(a3, w.z, acc[3][2]); acc[3][3] = fmaf(a3, w.w, acc[3][3]);
        }
        __syncthreads();
    }
#pragma unroll
    for (int i = 0; i < 4; i++) {
        int node = n0 + tr * 4 + i;
        if (node < N) {
            float dn = dis[node];
            *(float4*)(g2 + (size_t)node * OUT_F + c4) =
                make_float4(dn * acc[i][0], dn * acc[i][1], dn * acc[i][2], dn * acc[i][3]);
        }
    }
}

// out[d] = dis[d]*(sum_e g2[s] + g2[d]) + b2.  One wave per node, 1 float/lane.
__global__ void agg2_kernel(const float* __restrict__ g2, const int* __restrict__ ssrc,
                            const int* __restrict__ offsets, const int* __restrict__ deg_e,
                            const float* __restrict__ dis, const float* __restrict__ b2,
                            float* __restrict__ out, int N) {
    int lane = threadIdx.x & 63;
    int n = blockIdx.x * 4 + (threadIdx.x >> 6);
    if (n >= N) return;
    float acc = g2[(size_t)n * OUT_F + lane];
    int start = offsets[n], cnt = deg_e[n];
    for (int base = 0; base < cnt; base += 64) {
        int idx = base + lane;
        int sv = 0;
        if (idx < cnt) sv = ssrc[start + idx];
        int m = min(64, cnt - base);
#pragma unroll 4
        for (int j = 0; j < m; j++) {
            int s = bcast_i(sv, j);
            acc += g2[(size_t)s * OUT_F + lane];
        }
    }
    out[(size_t)n * OUT_F + lane] = fmaf(dis[n], acc, b2[lane]);
}

extern "C" void kernel_launch(void* const* d_in, const int* in_sizes, int n_in,
                              void* d_out, int out_size, void* d_ws, size_t ws_size,
                              hipStream_t stream) {
    const float* x      = (const float*)d_in[0];
    const int*   edges  = (const int*)d_in[1];
    const float* W1     = (const float*)d_in[2];
    const float* b1     = (const float*)d_in[3];
    const float* gamma1 = (const float*)d_in[4];
    const float* beta1  = (const float*)d_in[5];
    const float* W2     = (const float*)d_in[6];
    const float* b2     = (const float*)d_in[7];
    float* out = (float*)d_out;

    int N = in_sizes[0] / IN_F;
    int E = in_sizes[1] / 2;
    const int* src = edges;
    const int* dst = edges + E;

    char* ws = (char*)d_ws;
    size_t off = 0;
    auto alloc = [&](size_t bytes) -> void* {
        void* p = ws + off;
        off += (bytes + 255) & ~(size_t)255;
        return p;
    };
    int*   deg_e     = (int*)alloc((size_t)N * 4);
    int*   offsets   = (int*)alloc((size_t)N * 4);
    int*   cursor    = (int*)alloc((size_t)N * 4);
    int*   blocksums = (int*)alloc(1024);
    float* dis       = (float*)alloc((size_t)N * 4);
    int*   ssrc      = (int*)alloc((size_t)E * 4);
    float* sdis      = (float*)alloc((size_t)E * 4);
    float* z         = (float*)alloc((size_t)N * IN_F * 4);
    float* out1      = (float*)alloc((size_t)N * HID_F * 4);
    float* bn        = (float*)alloc(4 * 256 * 4);  // sums | sumsq | scale | bias
    float* g2        = z;  // alias: z dead after gemm1; g2 (25.6 MB) < z (51.2 MB)

    hipMemsetAsync(deg_e, 0, (size_t)N * 4, stream);
    hipMemsetAsync(bn, 0, 2 * 256 * 4, stream);

    count_kernel<<<(E + 255) / 256, 256, 0, stream>>>(dst, deg_e, E);

    int nb1 = (N + 511) / 512;
    scan1_kernel<<<nb1, 512, 0, stream>>>(deg_e, offsets, blocksums, dis, N);
    scan2_kernel<<<1, 64, 0, stream>>>(blocksums, nb1);
    scan3_kernel<<<nb1, 512, 0, stream>>>(offsets, blocksums, cursor, N);
    scatter_kernel<<<(E + 255) / 256, 256, 0, stream>>>(src, dst, dis, cursor, ssrc, sdis, E);

    aggx_kernel<<<(N + 3) / 4, 256, 0, stream>>>(x, ssrc, sdis, offsets, deg_e, dis, z, N);
    gemm1_kernel<<<(N + 31) / 32, 256, 0, stream>>>(z, W1, b1, out1, N);
    bnreduce_kernel<<<(N + 127) / 128, 256, 0, stream>>>(out1, bn, bn + 256, N);
    bnfinal_kernel<<<1, 256, 0, stream>>>(bn, gamma1, beta1, N);
    gemm2_kernel<<<(N + 63) / 64, 256, 0, stream>>>(out1, W2, dis, bn, g2, N);
    agg2_kernel<<<(N + 3) / 4, 256, 0, stream>>>(g2, ssrc, offsets, deg_e, dis, b2, out, N);
}

// Round 4
// 692.987 us; speedup vs baseline: 1.7589x; 1.0738x over previous
//
#include <hip/hip_runtime.h>
#include <hip/hip_bf16.h>

// GraphSAINT 2-layer GCN forward on MI355X.
// Layer 1: xs[n] = bf16(dis[n]*x[n]);  z[d] = dis[d]*(sum_e xs[s] + xs[d]);
//          out1 = z @ W1 + b1  (fp32 GEMM).
// Layer 2: gs[n] = bf16(dis[n]*(relu(bn(out1[n])) @ W2));
//          out[d] = dis[d]*(sum_e gs[s] + gs[d]) + b2.
// dis[n] = rsqrt(deg_in[n]+1).  Gathers use bf16 rows (half the bytes), fp32 accum.

#define IN_F  128
#define HID_F 256
#define OUT_F 64

typedef unsigned int uint;

__device__ __forceinline__ int bcast_i(int v, int l) {
    return __builtin_amdgcn_readlane(v, l);
}
__device__ __forceinline__ unsigned short f2bf(float f) {
    unsigned int u = __float_as_uint(f);
    unsigned int r = (u + 0x7fffu + ((u >> 16) & 1u)) >> 16;  // RNE
    return (unsigned short)r;
}
__device__ __forceinline__ float bf_lo(uint u) { return __uint_as_float(u << 16); }
__device__ __forceinline__ float bf_hi(uint u) { return __uint_as_float(u & 0xffff0000u); }

__global__ void count_kernel(const int* __restrict__ dst, int* __restrict__ deg_e, int E) {
    int i = blockIdx.x * 256 + threadIdx.x;
    if (i < E) atomicAdd(&deg_e[dst[i]], 1);
}

__global__ void scan1_kernel(const int* __restrict__ deg_e, int* __restrict__ offsets,
                             int* __restrict__ blocksums, float* __restrict__ dis, int N) {
    __shared__ int sh[512];
    int i = blockIdx.x * 512 + threadIdx.x;
    int v = (i < N) ? deg_e[i] : 0;
    if (i < N) dis[i] = rsqrtf((float)(v + 1));
    sh[threadIdx.x] = v;
    __syncthreads();
    for (int off = 1; off < 512; off <<= 1) {
        int t = (threadIdx.x >= off) ? sh[threadIdx.x - off] : 0;
        __syncthreads();
        sh[threadIdx.x] += t;
        __syncthreads();
    }
    if (i < N) offsets[i] = sh[threadIdx.x] - v;
    if (threadIdx.x == 511) blocksums[blockIdx.x] = sh[511];
}

__global__ void scan2_kernel(int* __restrict__ blocksums, int nb) {
    if (threadIdx.x == 0) {
        int acc = 0;
        for (int b = 0; b < nb; b++) { int v = blocksums[b]; blocksums[b] = acc; acc += v; }
    }
}

__global__ void scan3_kernel(int* __restrict__ offsets, const int* __restrict__ blocksums,
                             int* __restrict__ cursor, int N) {
    int i = blockIdx.x * 512 + threadIdx.x;
    if (i < N) {
        int o = offsets[i] + blocksums[blockIdx.x];
        offsets[i] = o;
        cursor[i] = o;
    }
}

// xs[n][k] = bf16(dis[n]*x[n][k]), packed 2/uint.  One thread per 2 floats.
__global__ void xprep_kernel(const float* __restrict__ x, const float* __restrict__ dis,
                             uint* __restrict__ xs, int N) {
    int i = blockIdx.x * 256 + threadIdx.x;
    if (i < N * (IN_F / 2)) {
        int n = i >> 6;
        float dn = dis[n];
        float2 v = ((const float2*)x)[i];
        xs[i] = (uint)f2bf(dn * v.x) | ((uint)f2bf(dn * v.y) << 16);
    }
}

// Counting-sort edges by dst (bare src index).
__global__ void scatter_kernel(const int* __restrict__ src, const int* __restrict__ dst,
                               int* __restrict__ cursor, int* __restrict__ ssrc, int E) {
    int i = blockIdx.x * 256 + threadIdx.x;
    if (i < E) {
        int d = dst[i];
        int s = src[i];
        int pos = atomicAdd(&cursor[d], 1);
        ssrc[pos] = s;
    }
}

// z[d] = dis[d]*(sum_e xs[s] + xs[d]).  One wave per node; 2 edges per iteration
// (lanes 0-31 edge A, lanes 32-63 edge B; 8B bf16x4 per lane = 256B row each).
__global__ void aggx_kernel(const uint* __restrict__ xs, const int* __restrict__ ssrc,
                            const int* __restrict__ offsets, const int* __restrict__ deg_e,
                            const float* __restrict__ dis, float* __restrict__ z, int N) {
    int lane = threadIdx.x & 63;
    int n = blockIdx.x * 4 + (threadIdx.x >> 6);
    if (n >= N) return;
    int half = lane >> 5;
    int ck = lane & 31;  // covers cols 4*ck..4*ck+3
    float4 acc = make_float4(0.f, 0.f, 0.f, 0.f);
    int start = offsets[n], cnt = deg_e[n];
    for (int base = 0; base < cnt; base += 64) {
        int m = min(64, cnt - base);
        int idx = base + lane;
        int cl = idx < cnt ? idx : cnt - 1;
        int sv = ssrc[start + cl];
        int pairs = (m + 1) >> 1;
#pragma unroll 4
        for (int p = 0; p < pairs; p++) {
            int e1 = 2 * p + 1;
            int s0 = bcast_i(sv, 2 * p);
            int s1 = bcast_i(sv, e1 < m ? e1 : 2 * p);
            float w1 = (e1 < m) ? 1.f : 0.f;
            int s = half ? s1 : s0;
            float w = half ? w1 : 1.f;
            uint2 u = *(const uint2*)(xs + (size_t)s * 64 + ck * 2);
            acc.x = fmaf(w, bf_lo(u.x), acc.x);
            acc.y = fmaf(w, bf_hi(u.x), acc.y);
            acc.z = fmaf(w, bf_lo(u.y), acc.z);
            acc.w = fmaf(w, bf_hi(u.y), acc.w);
        }
    }
    acc.x += __shfl_down(acc.x, 32);
    acc.y += __shfl_down(acc.y, 32);
    acc.z += __shfl_down(acc.z, 32);
    acc.w += __shfl_down(acc.w, 32);
    if (half == 0) {
        uint2 u = *(const uint2*)(xs + (size_t)n * 64 + ck * 2);  // self term
        acc.x += bf_lo(u.x);
        acc.y += bf_hi(u.x);
        acc.z += bf_lo(u.y);
        acc.w += bf_hi(u.y);
        float dn = dis[n];
        ((float4*)(z + (size_t)n * IN_F))[ck] =
            make_float4(dn * acc.x, dn * acc.y, dn * acc.z, dn * acc.w);
    }
}

// out1 = z @ W1 + b1.  Tile 32 nodes x 256 cols; thread owns 16 nodes x 2 cols.
__global__ __launch_bounds__(256) void gemm1_kernel(const float* __restrict__ z,
                                                    const float* __restrict__ W1,
                                                    const float* __restrict__ b1,
                                                    float* __restrict__ out1, int N) {
    __shared__ float4 zs[32][32];
    int t = threadIdx.x;
    int n0 = blockIdx.x * 32;
    int half = t >> 7;
    int c = (t & 127) * 2;
    for (int i = t; i < 32 * 32; i += 256) {
        int n = i >> 5, k4 = i & 31;
        int node = n0 + n;
        zs[n][k4] = (node < N) ? ((const float4*)(z + (size_t)node * IN_F))[k4]
                               : make_float4(0.f, 0.f, 0.f, 0.f);
    }
    __syncthreads();
    float acc[16][2];
#pragma unroll
    for (int i = 0; i < 16; i++) { acc[i][0] = 0.f; acc[i][1] = 0.f; }
    for (int k0 = 0; k0 < 32; k0++) {
        float2 w0 = *(const float2*)(W1 + (size_t)(4 * k0 + 0) * HID_F + c);
        float2 w1 = *(const float2*)(W1 + (size_t)(4 * k0 + 1) * HID_F + c);
        float2 w2 = *(const float2*)(W1 + (size_t)(4 * k0 + 2) * HID_F + c);
        float2 w3 = *(const float2*)(W1 + (size_t)(4 * k0 + 3) * HID_F + c);
#pragma unroll
        for (int i = 0; i < 16; i++) {
            float4 zv = zs[half * 16 + i][k0];
            acc[i][0] = fmaf(zv.x, w0.x, acc[i][0]);
            acc[i][1] = fmaf(zv.x, w0.y, acc[i][1]);
            acc[i][0] = fmaf(zv.y, w1.x, acc[i][0]);
            acc[i][1] = fmaf(zv.y, w1.y, acc[i][1]);
            acc[i][0] = fmaf(zv.z, w2.x, acc[i][0]);
            acc[i][1] = fmaf(zv.z, w2.y, acc[i][1]);
            acc[i][0] = fmaf(zv.w, w3.x, acc[i][0]);
            acc[i][1] = fmaf(zv.w, w3.y, acc[i][1]);
        }
    }
    float2 bb = *(const float2*)(b1 + c);
#pragma unroll
    for (int i = 0; i < 16; i++) {
        int node = n0 + half * 16 + i;
        if (node < N)
            *(float2*)(out1 + (size_t)node * HID_F + c) =
                make_float2(acc[i][0] + bb.x, acc[i][1] + bb.y);
    }
}

__global__ void bnreduce_kernel(const float* __restrict__ out1, float* __restrict__ sums,
                                float* __restrict__ sumsq, int N) {
    int j = threadIdx.x;
    int r0 = blockIdx.x * 128;
    float s = 0.f, sq = 0.f;
    int rend = min(128, N - r0);
    for (int r = 0; r < rend; r++) {
        float v = out1[(size_t)(r0 + r) * HID_F + j];
        s += v;
        sq = fmaf(v, v, sq);
    }
    atomicAdd(&sums[j], s);
    atomicAdd(&sumsq[j], sq);
}

__global__ void bnfinal_kernel(float* __restrict__ bn, const float* __restrict__ gamma,
                               const float* __restrict__ beta, int N) {
    int j = threadIdx.x;
    float invN = 1.0f / (float)N;
    float mean = bn[j] * invN;
    float var = bn[256 + j] * invN - mean * mean;
    float sc = gamma[j] * rsqrtf(fmaxf(var, 0.f) + 1e-5f);
    bn[512 + j] = sc;
    bn[768 + j] = beta[j] - mean * sc;
}

// gs[n] = bf16(dis[n]*(relu(bn(out1[n])) @ W2)).  64x64 tile; thread owns 4x4.
__global__ __launch_bounds__(256) void gemm2_kernel(const float* __restrict__ out1,
                                                    const float* __restrict__ W2,
                                                    const float* __restrict__ dis,
                                                    const float* __restrict__ bn,
                                                    uint* __restrict__ gs, int N) {
    __shared__ float as[64][68];
    const float* bnscale = bn + 512;
    const float* bnbias  = bn + 768;
    int t = threadIdx.x;
    int n0 = blockIdx.x * 64;
    int tc = t & 15, tr = t >> 4;
    int c4 = tc * 4;
    float acc[4][4];
#pragma unroll
    for (int i = 0; i < 4; i++)
#pragma unroll
        for (int jj = 0; jj < 4; jj++) acc[i][jj] = 0.f;
    for (int kc = 0; kc < HID_F; kc += 64) {
        for (int i = t; i < 64 * 16; i += 256) {
            int n = i >> 4, k4 = (i & 15) * 4;
            int node = n0 + n;
            float4 v = make_float4(0.f, 0.f, 0.f, 0.f);
            if (node < N) {
                v = *(const float4*)(out1 + (size_t)node * HID_F + kc + k4);
                float4 scl = *(const float4*)(bnscale + kc + k4);
                float4 bia = *(const float4*)(bnbias + kc + k4);
                v.x = fmaxf(fmaf(v.x, scl.x, bia.x), 0.f);
                v.y = fmaxf(fmaf(v.y, scl.y, bia.y), 0.f);
                v.z = fmaxf(fmaf(v.z, scl.z, bia.z), 0.f);
                v.w = fmaxf(fmaf(v.w, scl.w, bia.w), 0.f);
            }
            *(float4*)(&as[n][k4]) = v;
        }
        __syncthreads();
        for (int kk = 0; kk < 64; kk++) {
            float4 w = *(const float4*)(W2 + (size_t)(kc + kk) * OUT_F + c4);
            float a0 = as[tr * 4 + 0][kk];
            float a1 = as[tr * 4 + 1][kk];
            float a2 = as[tr * 4 + 2][kk];
            float a3 = as[tr * 4 + 3][kk];
            acc[0][0] = fmaf(a0, w.x, acc[0][0]); acc[0][1] = fmaf(a0, w.y, acc[0][1]);
            acc[0][2] = fmaf(a0, w.z, acc[0][2]); acc[0][3] = fmaf(a0, w.w, acc[0][3]);
            acc[1][0] = fmaf(a1, w.x, acc[1][0]); acc[1][1] = fmaf(a1, w.y, acc[1][1]);
            acc[1][2] = fmaf(a1, w.z, acc[1][2]); acc[1][3] = fmaf(a1, w.w, acc[1][3]);
            acc[2][0] = fmaf(a2, w.x, acc[2][0]); acc[2][1] = fmaf(a2, w.y, acc[2][1]);
            acc[2][2] = fmaf(a2, w.z, acc[2][2]); acc[2][3] = fmaf(a2, w.w, acc[2][3]);
            acc[3][0] = fmaf(a3, w.x, acc[3][0]); acc[3][1] = fmaf(a3, w.y, acc[3][1]);
            acc[3][2] = fmaf(a3, w.z, acc[3][2]); acc[3][3] = fmaf(a3, w.w, acc[3][3]);
        }
        __syncthreads();
    }
#pragma unroll
    for (int i = 0; i < 4; i++) {
        int node = n0 + tr * 4 + i;
        if (node < N) {
            float dn = dis[node];
            uint2 o;
            o.x = (uint)f2bf(dn * acc[i][0]) | ((uint)f2bf(dn * acc[i][1]) << 16);
            o.y = (uint)f2bf(dn * acc[i][2]) | ((uint)f2bf(dn * acc[i][3]) << 16);
            *(uint2*)(gs + (size_t)node * (OUT_F / 2) + tc * 2) = o;
        }
    }
}

// out[d] = dis[d]*(sum_e gs[s] + gs[d]) + b2.  One wave per node; 4 edges per
// iteration (16-lane groups; 8B bf16x4 per lane = 128B row each).
__global__ void agg2_kernel(const uint* __restrict__ gs, const int* __restrict__ ssrc,
                            const int* __restrict__ offsets, const int* __restrict__ deg_e,
                            const float* __restrict__ dis, const float* __restrict__ b2,
                            float* __restrict__ out, int N) {
    int lane = threadIdx.x & 63;
    int n = blockIdx.x * 4 + (threadIdx.x >> 6);
    if (n >= N) return;
    int grp = lane >> 4;
    int ck = lane & 15;  // covers cols 4*ck..4*ck+3
    int b0 = grp & 1, b1g = grp >> 1;
    float4 acc = make_float4(0.f, 0.f, 0.f, 0.f);
    int start = offsets[n], cnt = deg_e[n];
    for (int base = 0; base < cnt; base += 64) {
        int m = min(64, cnt - base);
        int idx = base + lane;
        int cl = idx < cnt ? idx : cnt - 1;
        int sv = ssrc[start + cl];
        int quads = (m + 3) >> 2;
#pragma unroll 4
        for (int q = 0; q < quads; q++) {
            int e0 = 4 * q, e1 = e0 + 1, e2 = e0 + 2, e3 = e0 + 3;
            int s0 = bcast_i(sv, e0);
            int s1 = bcast_i(sv, e1 < m ? e1 : e0);
            int s2 = bcast_i(sv, e2 < m ? e2 : e0);
            int s3 = bcast_i(sv, e3 < m ? e3 : e0);
            float w1 = e1 < m ? 1.f : 0.f;
            float w2 = e2 < m ? 1.f : 0.f;
            float w3 = e3 < m ? 1.f : 0.f;
            int sA = b0 ? s1 : s0;
            int sB = b0 ? s3 : s2;
            int s = b1g ? sB : sA;
            float wA = b0 ? w1 : 1.f;
            float wB = b0 ? w3 : w2;
            float w = b1g ? wB : wA;
            uint2 u = *(const uint2*)(gs + (size_t)s * (OUT_F / 2) + ck * 2);
            acc.x = fmaf(w, bf_lo(u.x), acc.x);
            acc.y = fmaf(w, bf_hi(u.x), acc.y);
            acc.z = fmaf(w, bf_lo(u.y), acc.z);
            acc.w = fmaf(w, bf_hi(u.y), acc.w);
        }
    }
    acc.x += __shfl_down(acc.x, 32);
    acc.y += __shfl_down(acc.y, 32);
    acc.z += __shfl_down(acc.z, 32);
    acc.w += __shfl_down(acc.w, 32);
    acc.x += __shfl_down(acc.x, 16);
    acc.y += __shfl_down(acc.y, 16);
    acc.z += __shfl_down(acc.z, 16);
    acc.w += __shfl_down(acc.w, 16);
    if (grp == 0) {
        uint2 u = *(const uint2*)(gs + (size_t)n * (OUT_F / 2) + ck * 2);  // self
        acc.x += bf_lo(u.x);
        acc.y += bf_hi(u.x);
        acc.z += bf_lo(u.y);
        acc.w += bf_hi(u.y);
        float dn = dis[n];
        float4 bb = ((const float4*)b2)[ck];
        ((float4*)(out + (size_t)n * OUT_F))[ck] =
            make_float4(fmaf(dn, acc.x, bb.x), fmaf(dn, acc.y, bb.y),
                        fmaf(dn, acc.z, bb.z), fmaf(dn, acc.w, bb.w));
    }
}

extern "C" void kernel_launch(void* const* d_in, const int* in_sizes, int n_in,
                              void* d_out, int out_size, void* d_ws, size_t ws_size,
                              hipStream_t stream) {
    const float* x      = (const float*)d_in[0];
    const int*   edges  = (const int*)d_in[1];
    const float* W1     = (const float*)d_in[2];
    const float* b1     = (const float*)d_in[3];
    const float* gamma1 = (const float*)d_in[4];
    const float* beta1  = (const float*)d_in[5];
    const float* W2     = (const float*)d_in[6];
    const float* b2     = (const float*)d_in[7];
    float* out = (float*)d_out;

    int N = in_sizes[0] / IN_F;
    int E = in_sizes[1] / 2;
    const int* src = edges;
    const int* dst = edges + E;

    char* ws = (char*)d_ws;
    size_t off = 0;
    auto alloc = [&](size_t bytes) -> void* {
        void* p = ws + off;
        off += (bytes + 255) & ~(size_t)255;
        return p;
    };
    int*   deg_e     = (int*)alloc((size_t)N * 4);
    int*   offsets   = (int*)alloc((size_t)N * 4);
    int*   cursor    = (int*)alloc((size_t)N * 4);
    int*   blocksums = (int*)alloc(1024);
    float* dis       = (float*)alloc((size_t)N * 4);
    int*   ssrc      = (int*)alloc((size_t)E * 4);
    uint*  xs        = (uint*)alloc((size_t)N * (IN_F / 2) * 4);   // bf16 dis*x
    float* z         = (float*)alloc((size_t)N * IN_F * 4);
    float* out1      = (float*)alloc((size_t)N * HID_F * 4);
    float* bn        = (float*)alloc(4 * 256 * 4);
    uint*  gs        = (uint*)z;  // alias: z dead after gemm1; gs = 12.8 MB

    hipMemsetAsync(deg_e, 0, (size_t)N * 4, stream);
    hipMemsetAsync(bn, 0, 2 * 256 * 4, stream);

    count_kernel<<<(E + 255) / 256, 256, 0, stream>>>(dst, deg_e, E);

    int nb1 = (N + 511) / 512;
    scan1_kernel<<<nb1, 512, 0, stream>>>(deg_e, offsets, blocksums, dis, N);
    xprep_kernel<<<(N * (IN_F / 2) + 255) / 256, 256, 0, stream>>>(x, dis, xs, N);
    scan2_kernel<<<1, 64, 0, stream>>>(blocksums, nb1);
    scan3_kernel<<<nb1, 512, 0, stream>>>(offsets, blocksums, cursor, N);
    scatter_kernel<<<(E + 255) / 256, 256, 0, stream>>>(src, dst, cursor, ssrc, E);

    aggx_kernel<<<(N + 3) / 4, 256, 0, stream>>>(xs, ssrc, offsets, deg_e, dis, z, N);
    gemm1_kernel<<<(N + 31) / 32, 256, 0, stream>>>(z, W1, b1, out1, N);
    bnreduce_kernel<<<(N + 127) / 128, 256, 0, stream>>>(out1, bn, bn + 256, N);
    bnfinal_kernel<<<1, 256, 0, stream>>>(bn, gamma1, beta1, N);
    gemm2_kernel<<<(N + 63) / 64, 256, 0, stream>>>(out1, W2, dis, bn, gs, N);
    agg2_kernel<<<(N + 3) / 4, 256, 0, stream>>>(gs, ssrc, offsets, deg_e, dis, b2, out, N);
}

// Round 5
// 531.625 us; speedup vs baseline: 2.2928x; 1.3035x over previous
//
#include <hip/hip_runtime.h>
#include <hip/hip_bf16.h>

// GraphSAINT 2-layer GCN forward on MI355X.
// Layer 1: xs[n] = bf16(dis[n]*x[n]);  z[d] = dis[d]*(sum_e xs[s] + xs[d]);
//          out1 = z @ W1 + b1  (fp32 GEMM).
// Layer 2: gs[n] = bf16(dis[n]*(relu(bn(out1[n])) @ W2));
//          out[d] = dis[d]*(sum_e gs[s] + gs[d]) + b2.
// CSR built via 2-level radix sort (coarse bucket = dst>>8) so cursor atomics
// live in LDS and scattered writes land in 16 KB hot windows (no 64B-line amp).

#define IN_F  128
#define HID_F 256
#define OUT_F 64
#define BK_SHIFT 8
#define BK_SIZE  256
#define CHUNK    8192

typedef unsigned int uint;

__device__ __forceinline__ int bcast_i(int v, int l) {
    return __builtin_amdgcn_readlane(v, l);
}
__device__ __forceinline__ unsigned short f2bf(float f) {
    unsigned int u = __float_as_uint(f);
    unsigned int r = (u + 0x7fffu + ((u >> 16) & 1u)) >> 16;  // RNE
    return (unsigned short)r;
}
__device__ __forceinline__ float bf_lo(uint u) { return __uint_as_float(u << 16); }
__device__ __forceinline__ float bf_hi(uint u) { return __uint_as_float(u & 0xffff0000u); }

// --- sort pipeline -----------------------------------------------------------

__global__ void bucket_hist_kernel(const int* __restrict__ dst, int* __restrict__ bhist,
                                   int E, int NB) {
    __shared__ int h[512];
    for (int i = threadIdx.x; i < NB; i += 256) h[i] = 0;
    __syncthreads();
    int base = blockIdx.x * CHUNK;
    int end = min(base + CHUNK, E);
    for (int i = base + threadIdx.x; i < end; i += 256)
        atomicAdd(&h[dst[i] >> BK_SHIFT], 1);
    __syncthreads();
    for (int i = threadIdx.x; i < NB; i += 256)
        if (h[i]) atomicAdd(&bhist[i], h[i]);
}

// Single block: exclusive scan of bhist (NB <= 512) -> bbase, bcursor.
__global__ void bucket_scan_kernel(const int* __restrict__ bhist, int* __restrict__ bbase,
                                   int* __restrict__ bcursor, int NB, int E) {
    __shared__ int sh[512];
    int t = threadIdx.x;
    int v = (t < NB) ? bhist[t] : 0;
    sh[t] = v;
    __syncthreads();
    for (int off = 1; off < 512; off <<= 1) {
        int u = (t >= off) ? sh[t - off] : 0;
        __syncthreads();
        sh[t] += u;
        __syncthreads();
    }
    if (t < NB) { int b = sh[t] - v; bbase[t] = b; bcursor[t] = b; }
    if (t == 0) bbase[NB] = E;
}

// Pack edges into coarse buckets: ebuf[pos] = src | (dst&255)<<24  (N < 2^24).
__global__ void bucket_scatter_kernel(const int* __restrict__ src, const int* __restrict__ dst,
                                      int* __restrict__ bcursor, uint* __restrict__ ebuf,
                                      int E, int NB) {
    __shared__ int h[512];
    __shared__ int cur[512];
    for (int i = threadIdx.x; i < NB; i += 256) h[i] = 0;
    __syncthreads();
    int base = blockIdx.x * CHUNK;
    int end = min(base + CHUNK, E);
    for (int i = base + threadIdx.x; i < end; i += 256)
        atomicAdd(&h[dst[i] >> BK_SHIFT], 1);
    __syncthreads();
    for (int i = threadIdx.x; i < NB; i += 256)
        cur[i] = h[i] ? atomicAdd(&bcursor[i], h[i]) : 0;  // one reservation per bucket
    __syncthreads();
    for (int i = base + threadIdx.x; i < end; i += 256) {
        int d = dst[i], s = src[i];
        int b = d >> BK_SHIFT;
        int pos = atomicAdd(&cur[b], 1);  // LDS cursor
        ebuf[pos] = (uint)s | ((uint)(d & (BK_SIZE - 1)) << 24);
    }
}

// One block per bucket: LDS count/scan/sort; writes deg, offsets, dis, ssrc.
__global__ void bucket_build_kernel(const uint* __restrict__ ebuf, const int* __restrict__ bbase,
                                    int* __restrict__ deg_e, int* __restrict__ offsets,
                                    float* __restrict__ dis, int* __restrict__ ssrc, int N) {
    __shared__ int cnt[256], off[256], cur[256];
    int b = blockIdx.x;
    int t = threadIdx.x;
    cnt[t] = 0;
    __syncthreads();
    int e0 = bbase[b], e1 = bbase[b + 1];
    for (int i = e0 + t; i < e1; i += 256)
        atomicAdd(&cnt[ebuf[i] >> 24], 1);
    __syncthreads();
    int v = cnt[t];
    off[t] = v;
    __syncthreads();
    for (int o = 1; o < 256; o <<= 1) {
        int u = (t >= o) ? off[t - o] : 0;
        __syncthreads();
        off[t] += u;
        __syncthreads();
    }
    int excl = off[t] - v;
    int d = b * BK_SIZE + t;
    if (d < N) {
        deg_e[d] = v;
        offsets[d] = e0 + excl;
        dis[d] = rsqrtf((float)(v + 1));
    }
    cur[t] = excl;
    __syncthreads();
    for (int i = e0 + t; i < e1; i += 256) {
        uint e = ebuf[i];
        int ld = e >> 24;
        int pos = atomicAdd(&cur[ld], 1);       // LDS cursor
        ssrc[e0 + pos] = (int)(e & 0xFFFFFFu);  // 16 KB hot window per bucket
    }
}

// --- compute pipeline --------------------------------------------------------

// xs[n][k] = bf16(dis[n]*x[n][k]), packed 2/uint.
__global__ void xprep_kernel(const float* __restrict__ x, const float* __restrict__ dis,
                             uint* __restrict__ xs, int N) {
    int i = blockIdx.x * 256 + threadIdx.x;
    if (i < N * (IN_F / 2)) {
        int n = i >> 6;
        float dn = dis[n];
        float2 v = ((const float2*)x)[i];
        xs[i] = (uint)f2bf(dn * v.x) | ((uint)f2bf(dn * v.y) << 16);
    }
}

// z[d] = dis[d]*(sum_e xs[s] + xs[d]).  One wave per node; 2 edges/iteration.
__global__ void aggx_kernel(const uint* __restrict__ xs, const int* __restrict__ ssrc,
                            const int* __restrict__ offsets, const int* __restrict__ deg_e,
                            const float* __restrict__ dis, float* __restrict__ z, int N) {
    int lane = threadIdx.x & 63;
    int n = blockIdx.x * 4 + (threadIdx.x >> 6);
    if (n >= N) return;
    int half = lane >> 5;
    int ck = lane & 31;
    float4 acc = make_float4(0.f, 0.f, 0.f, 0.f);
    int start = offsets[n], cnt = deg_e[n];
    for (int base = 0; base < cnt; base += 64) {
        int m = min(64, cnt - base);
        int idx = base + lane;
        int cl = idx < cnt ? idx : cnt - 1;
        int sv = ssrc[start + cl];
        int pairs = (m + 1) >> 1;
#pragma unroll 4
        for (int p = 0; p < pairs; p++) {
            int e1 = 2 * p + 1;
            int s0 = bcast_i(sv, 2 * p);
            int s1 = bcast_i(sv, e1 < m ? e1 : 2 * p);
            float w1 = (e1 < m) ? 1.f : 0.f;
            int s = half ? s1 : s0;
            float w = half ? w1 : 1.f;
            uint2 u = *(const uint2*)(xs + (size_t)s * 64 + ck * 2);
            acc.x = fmaf(w, bf_lo(u.x), acc.x);
            acc.y = fmaf(w, bf_hi(u.x), acc.y);
            acc.z = fmaf(w, bf_lo(u.y), acc.z);
            acc.w = fmaf(w, bf_hi(u.y), acc.w);
        }
    }
    acc.x += __shfl_down(acc.x, 32);
    acc.y += __shfl_down(acc.y, 32);
    acc.z += __shfl_down(acc.z, 32);
    acc.w += __shfl_down(acc.w, 32);
    if (half == 0) {
        uint2 u = *(const uint2*)(xs + (size_t)n * 64 + ck * 2);
        acc.x += bf_lo(u.x);
        acc.y += bf_hi(u.x);
        acc.z += bf_lo(u.y);
        acc.w += bf_hi(u.y);
        float dn = dis[n];
        ((float4*)(z + (size_t)n * IN_F))[ck] =
            make_float4(dn * acc.x, dn * acc.y, dn * acc.z, dn * acc.w);
    }
}

// out1 = z @ W1 + b1.  Tile 32 nodes x 256 cols; thread owns 16 nodes x 2 cols.
__global__ __launch_bounds__(256) void gemm1_kernel(const float* __restrict__ z,
                                                    const float* __restrict__ W1,
                                                    const float* __restrict__ b1,
                                                    float* __restrict__ out1, int N) {
    __shared__ float4 zs[32][32];
    int t = threadIdx.x;
    int n0 = blockIdx.x * 32;
    int half = t >> 7;
    int c = (t & 127) * 2;
    for (int i = t; i < 32 * 32; i += 256) {
        int n = i >> 5, k4 = i & 31;
        int node = n0 + n;
        zs[n][k4] = (node < N) ? ((const float4*)(z + (size_t)node * IN_F))[k4]
                               : make_float4(0.f, 0.f, 0.f, 0.f);
    }
    __syncthreads();
    float acc[16][2];
#pragma unroll
    for (int i = 0; i < 16; i++) { acc[i][0] = 0.f; acc[i][1] = 0.f; }
    for (int k0 = 0; k0 < 32; k0++) {
        float2 w0 = *(const float2*)(W1 + (size_t)(4 * k0 + 0) * HID_F + c);
        float2 w1 = *(const float2*)(W1 + (size_t)(4 * k0 + 1) * HID_F + c);
        float2 w2 = *(const float2*)(W1 + (size_t)(4 * k0 + 2) * HID_F + c);
        float2 w3 = *(const float2*)(W1 + (size_t)(4 * k0 + 3) * HID_F + c);
#pragma unroll
        for (int i = 0; i < 16; i++) {
            float4 zv = zs[half * 16 + i][k0];
            acc[i][0] = fmaf(zv.x, w0.x, acc[i][0]);
            acc[i][1] = fmaf(zv.x, w0.y, acc[i][1]);
            acc[i][0] = fmaf(zv.y, w1.x, acc[i][0]);
            acc[i][1] = fmaf(zv.y, w1.y, acc[i][1]);
            acc[i][0] = fmaf(zv.z, w2.x, acc[i][0]);
            acc[i][1] = fmaf(zv.z, w2.y, acc[i][1]);
            acc[i][0] = fmaf(zv.w, w3.x, acc[i][0]);
            acc[i][1] = fmaf(zv.w, w3.y, acc[i][1]);
        }
    }
    float2 bb = *(const float2*)(b1 + c);
#pragma unroll
    for (int i = 0; i < 16; i++) {
        int node = n0 + half * 16 + i;
        if (node < N)
            *(float2*)(out1 + (size_t)node * HID_F + c) =
                make_float2(acc[i][0] + bb.x, acc[i][1] + bb.y);
    }
}

__global__ void bnreduce_kernel(const float* __restrict__ out1, float* __restrict__ sums,
                                float* __restrict__ sumsq, int N) {
    int j = threadIdx.x;
    int r0 = blockIdx.x * 128;
    float s = 0.f, sq = 0.f;
    int rend = min(128, N - r0);
    for (int r = 0; r < rend; r++) {
        float v = out1[(size_t)(r0 + r) * HID_F + j];
        s += v;
        sq = fmaf(v, v, sq);
    }
    atomicAdd(&sums[j], s);
    atomicAdd(&sumsq[j], sq);
}

__global__ void bnfinal_kernel(float* __restrict__ bn, const float* __restrict__ gamma,
                               const float* __restrict__ beta, int N) {
    int j = threadIdx.x;
    float invN = 1.0f / (float)N;
    float mean = bn[j] * invN;
    float var = bn[256 + j] * invN - mean * mean;
    float sc = gamma[j] * rsqrtf(fmaxf(var, 0.f) + 1e-5f);
    bn[512 + j] = sc;
    bn[768 + j] = beta[j] - mean * sc;
}

// gs[n] = bf16(dis[n]*(relu(bn(out1[n])) @ W2)).  64x64 tile; thread owns 4x4.
__global__ __launch_bounds__(256) void gemm2_kernel(const float* __restrict__ out1,
                                                    const float* __restrict__ W2,
                                                    const float* __restrict__ dis,
                                                    const float* __restrict__ bn,
                                                    uint* __restrict__ gs, int N) {
    __shared__ float as[64][68];
    const float* bnscale = bn + 512;
    const float* bnbias  = bn + 768;
    int t = threadIdx.x;
    int n0 = blockIdx.x * 64;
    int tc = t & 15, tr = t >> 4;
    int c4 = tc * 4;
    float acc[4][4];
#pragma unroll
    for (int i = 0; i < 4; i++)
#pragma unroll
        for (int jj = 0; jj < 4; jj++) acc[i][jj] = 0.f;
    for (int kc = 0; kc < HID_F; kc += 64) {
        for (int i = t; i < 64 * 16; i += 256) {
            int n = i >> 4, k4 = (i & 15) * 4;
            int node = n0 + n;
            float4 v = make_float4(0.f, 0.f, 0.f, 0.f);
            if (node < N) {
                v = *(const float4*)(out1 + (size_t)node * HID_F + kc + k4);
                float4 scl = *(const float4*)(bnscale + kc + k4);
                float4 bia = *(const float4*)(bnbias + kc + k4);
                v.x = fmaxf(fmaf(v.x, scl.x, bia.x), 0.f);
                v.y = fmaxf(fmaf(v.y, scl.y, bia.y), 0.f);
                v.z = fmaxf(fmaf(v.z, scl.z, bia.z), 0.f);
                v.w = fmaxf(fmaf(v.w, scl.w, bia.w), 0.f);
            }
            *(float4*)(&as[n][k4]) = v;
        }
        __syncthreads();
        for (int kk = 0; kk < 64; kk++) {
            float4 w = *(const float4*)(W2 + (size_t)(kc + kk) * OUT_F + c4);
            float a0 = as[tr * 4 + 0][kk];
            float a1 = as[tr * 4 + 1][kk];
            float a2 = as[tr * 4 + 2][kk];
            float a3 = as[tr * 4 + 3][kk];
            acc[0][0] = fmaf(a0, w.x, acc[0][0]); acc[0][1] = fmaf(a0, w.y, acc[0][1]);
            acc[0][2] = fmaf(a0, w.z, acc[0][2]); acc[0][3] = fmaf(a0, w.w, acc[0][3]);
            acc[1][0] = fmaf(a1, w.x, acc[1][0]); acc[1][1] = fmaf(a1, w.y, acc[1][1]);
            acc[1][2] = fmaf(a1, w.z, acc[1][2]); acc[1][3] = fmaf(a1, w.w, acc[1][3]);
            acc[2][0] = fmaf(a2, w.x, acc[2][0]); acc[2][1] = fmaf(a2, w.y, acc[2][1]);
            acc[2][2] = fmaf(a2, w.z, acc[2][2]); acc[2][3] = fmaf(a2, w.w, acc[2][3]);
            acc[3][0] = fmaf(a3, w.x, acc[3][0]); acc[3][1] = fmaf(a3, w.y, acc[3][1]);
            acc[3][2] = fmaf(a3, w.z, acc[3][2]); acc[3][3] = fmaf(a3, w.w, acc[3][3]);
        }
        __syncthreads();
    }
#pragma unroll
    for (int i = 0; i < 4; i++) {
        int node = n0 + tr * 4 + i;
        if (node < N) {
            float dn = dis[node];
            uint2 o;
            o.x = (uint)f2bf(dn * acc[i][0]) | ((uint)f2bf(dn * acc[i][1]) << 16);
            o.y = (uint)f2bf(dn * acc[i][2]) | ((uint)f2bf(dn * acc[i][3]) << 16);
            *(uint2*)(gs + (size_t)node * (OUT_F / 2) + tc * 2) = o;
        }
    }
}

// out[d] = dis[d]*(sum_e gs[s] + gs[d]) + b2.  One wave per node; 4 edges/iter.
__global__ void agg2_kernel(const uint* __restrict__ gs, const int* __restrict__ ssrc,
                            const int* __restrict__ offsets, const int* __restrict__ deg_e,
                            const float* __restrict__ dis, const float* __restrict__ b2,
                            float* __restrict__ out, int N) {
    int lane = threadIdx.x & 63;
    int n = blockIdx.x * 4 + (threadIdx.x >> 6);
    if (n >= N) return;
    int grp = lane >> 4;
    int ck = lane & 15;
    int b0 = grp & 1, b1g = grp >> 1;
    float4 acc = make_float4(0.f, 0.f, 0.f, 0.f);
    int start = offsets[n], cnt = deg_e[n];
    for (int base = 0; base < cnt; base += 64) {
        int m = min(64, cnt - base);
        int idx = base + lane;
        int cl = idx < cnt ? idx : cnt - 1;
        int sv = ssrc[start + cl];
        int quads = (m + 3) >> 2;
#pragma unroll 4
        for (int q = 0; q < quads; q++) {
            int e0 = 4 * q, e1 = e0 + 1, e2 = e0 + 2, e3 = e0 + 3;
            int s0 = bcast_i(sv, e0);
            int s1 = bcast_i(sv, e1 < m ? e1 : e0);
            int s2 = bcast_i(sv, e2 < m ? e2 : e0);
            int s3 = bcast_i(sv, e3 < m ? e3 : e0);
            float w1 = e1 < m ? 1.f : 0.f;
            float w2 = e2 < m ? 1.f : 0.f;
            float w3 = e3 < m ? 1.f : 0.f;
            int sA = b0 ? s1 : s0;
            int sB = b0 ? s3 : s2;
            int s = b1g ? sB : sA;
            float wA = b0 ? w1 : 1.f;
            float wB = b0 ? w3 : w2;
            float w = b1g ? wB : wA;
            uint2 u = *(const uint2*)(gs + (size_t)s * (OUT_F / 2) + ck * 2);
            acc.x = fmaf(w, bf_lo(u.x), acc.x);
            acc.y = fmaf(w, bf_hi(u.x), acc.y);
            acc.z = fmaf(w, bf_lo(u.y), acc.z);
            acc.w = fmaf(w, bf_hi(u.y), acc.w);
        }
    }
    acc.x += __shfl_down(acc.x, 32);
    acc.y += __shfl_down(acc.y, 32);
    acc.z += __shfl_down(acc.z, 32);
    acc.w += __shfl_down(acc.w, 32);
    acc.x += __shfl_down(acc.x, 16);
    acc.y += __shfl_down(acc.y, 16);
    acc.z += __shfl_down(acc.z, 16);
    acc.w += __shfl_down(acc.w, 16);
    if (grp == 0) {
        uint2 u = *(const uint2*)(gs + (size_t)n * (OUT_F / 2) + ck * 2);
        acc.x += bf_lo(u.x);
        acc.y += bf_hi(u.x);
        acc.z += bf_lo(u.y);
        acc.w += bf_hi(u.y);
        float dn = dis[n];
        float4 bb = ((const float4*)b2)[ck];
        ((float4*)(out + (size_t)n * OUT_F))[ck] =
            make_float4(fmaf(dn, acc.x, bb.x), fmaf(dn, acc.y, bb.y),
                        fmaf(dn, acc.z, bb.z), fmaf(dn, acc.w, bb.w));
    }
}

extern "C" void kernel_launch(void* const* d_in, const int* in_sizes, int n_in,
                              void* d_out, int out_size, void* d_ws, size_t ws_size,
                              hipStream_t stream) {
    const float* x      = (const float*)d_in[0];
    const int*   edges  = (const int*)d_in[1];
    const float* W1     = (const float*)d_in[2];
    const float* b1     = (const float*)d_in[3];
    const float* gamma1 = (const float*)d_in[4];
    const float* beta1  = (const float*)d_in[5];
    const float* W2     = (const float*)d_in[6];
    const float* b2     = (const float*)d_in[7];
    float* out = (float*)d_out;

    int N = in_sizes[0] / IN_F;
    int E = in_sizes[1] / 2;
    const int* src = edges;
    const int* dst = edges + E;
    int NB = (N + BK_SIZE - 1) / BK_SIZE;          // 391 for N=100000 (<=512)
    int nchunks = (E + CHUNK - 1) / CHUNK;

    char* ws = (char*)d_ws;
    size_t off = 0;
    auto alloc = [&](size_t bytes) -> void* {
        void* p = ws + off;
        off += (bytes + 255) & ~(size_t)255;
        return p;
    };
    int*   deg_e   = (int*)alloc((size_t)N * 4);
    int*   offsets = (int*)alloc((size_t)N * 4);
    float* dis     = (float*)alloc((size_t)N * 4);
    int*   bhist   = (int*)alloc(512 * 4);
    int*   bbase   = (int*)alloc(513 * 4);
    int*   bcursor = (int*)alloc(512 * 4);
    int*   ssrc    = (int*)alloc((size_t)E * 4);
    uint*  ebuf    = (uint*)alloc((size_t)E * 4);
    uint*  xs      = (uint*)alloc((size_t)N * (IN_F / 2) * 4);
    float* z       = (float*)alloc((size_t)N * IN_F * 4);
    float* out1    = (float*)alloc((size_t)N * HID_F * 4);
    float* bn      = (float*)alloc(4 * 256 * 4);
    uint*  gs      = (uint*)z;  // alias: z dead after gemm1

    hipMemsetAsync(bhist, 0, 512 * 4, stream);
    hipMemsetAsync(bn, 0, 2 * 256 * 4, stream);

    bucket_hist_kernel<<<nchunks, 256, 0, stream>>>(dst, bhist, E, NB);
    bucket_scan_kernel<<<1, 512, 0, stream>>>(bhist, bbase, bcursor, NB, E);
    bucket_scatter_kernel<<<nchunks, 256, 0, stream>>>(src, dst, bcursor, ebuf, E, NB);
    bucket_build_kernel<<<NB, 256, 0, stream>>>(ebuf, bbase, deg_e, offsets, dis, ssrc, N);

    xprep_kernel<<<(N * (IN_F / 2) + 255) / 256, 256, 0, stream>>>(x, dis, xs, N);
    aggx_kernel<<<(N + 3) / 4, 256, 0, stream>>>(xs, ssrc, offsets, deg_e, dis, z, N);
    gemm1_kernel<<<(N + 31) / 32, 256, 0, stream>>>(z, W1, b1, out1, N);
    bnreduce_kernel<<<(N + 127) / 128, 256, 0, stream>>>(out1, bn, bn + 256, N);
    bnfinal_kernel<<<1, 256, 0, stream>>>(bn, gamma1, beta1, N);
    gemm2_kernel<<<(N + 63) / 64, 256, 0, stream>>>(out1, W2, dis, bn, gs, N);
    agg2_kernel<<<(N + 3) / 4, 256, 0, stream>>>(gs, ssrc, offsets, deg_e, dis, b2, out, N);
}

// Round 6
// 429.496 us; speedup vs baseline: 2.8380x; 1.2378x over previous
//
#include <hip/hip_runtime.h>
#include <hip/hip_bf16.h>

// GraphSAINT 2-layer GCN forward on MI355X.
// Layer 1: xs[n] = bf16(dis[n]*x[n]);  zb[d] = bf16(dis[d]*(sum_e xs[s] + xs[d]));
//          out1b = bf16(zb @ W1 + b1)   (bf16 MFMA, fp32 accum).
// Layer 2: gs[n] = bf16(dis[n]*(relu(bn(out1b[n])) @ W2))  (bf16 MFMA);
//          out[d] = dis[d]*(sum_e gs[s] + gs[d]) + b2  (fp32).
// CSR via 2-level radix sort (bucket = dst>>8): LDS cursors, 16KB hot windows.

#define IN_F  128
#define HID_F 256
#define OUT_F 64
#define BK_SHIFT 8
#define BK_SIZE  256
#define CHUNK    8192

typedef unsigned int uint;
typedef unsigned short ushort;
typedef short bf16x8 __attribute__((ext_vector_type(8)));
typedef float f32x4 __attribute__((ext_vector_type(4)));

__device__ __forceinline__ int bcast_i(int v, int l) {
    return __builtin_amdgcn_readlane(v, l);
}
__device__ __forceinline__ ushort f2bf(float f) {
    uint u = __float_as_uint(f);
    uint r = (u + 0x7fffu + ((u >> 16) & 1u)) >> 16;  // RNE
    return (ushort)r;
}
__device__ __forceinline__ float bf_lo(uint u) { return __uint_as_float(u << 16); }
__device__ __forceinline__ float bf_hi(uint u) { return __uint_as_float(u & 0xffff0000u); }

// --- sort pipeline -----------------------------------------------------------

__global__ void bucket_hist_kernel(const int* __restrict__ dst, int* __restrict__ bhist,
                                   int E, int NB) {
    __shared__ int h[512];
    for (int i = threadIdx.x; i < NB; i += 256) h[i] = 0;
    __syncthreads();
    int base = blockIdx.x * CHUNK;
    int end = min(base + CHUNK, E);
    for (int i = base + threadIdx.x; i < end; i += 256)
        atomicAdd(&h[dst[i] >> BK_SHIFT], 1);
    __syncthreads();
    for (int i = threadIdx.x; i < NB; i += 256)
        if (h[i]) atomicAdd(&bhist[i], h[i]);
}

__global__ void bucket_scan_kernel(const int* __restrict__ bhist, int* __restrict__ bbase,
                                   int* __restrict__ bcursor, int NB, int E) {
    __shared__ int sh[512];
    int t = threadIdx.x;
    int v = (t < NB) ? bhist[t] : 0;
    sh[t] = v;
    __syncthreads();
    for (int off = 1; off < 512; off <<= 1) {
        int u = (t >= off) ? sh[t - off] : 0;
        __syncthreads();
        sh[t] += u;
        __syncthreads();
    }
    if (t < NB) { int b = sh[t] - v; bbase[t] = b; bcursor[t] = b; }
    if (t == 0) bbase[NB] = E;
}

__global__ void bucket_scatter_kernel(const int* __restrict__ src, const int* __restrict__ dst,
                                      int* __restrict__ bcursor, uint* __restrict__ ebuf,
                                      int E, int NB) {
    __shared__ int h[512];
    __shared__ int cur[512];
    for (int i = threadIdx.x; i < NB; i += 256) h[i] = 0;
    __syncthreads();
    int base = blockIdx.x * CHUNK;
    int end = min(base + CHUNK, E);
    for (int i = base + threadIdx.x; i < end; i += 256)
        atomicAdd(&h[dst[i] >> BK_SHIFT], 1);
    __syncthreads();
    for (int i = threadIdx.x; i < NB; i += 256)
        cur[i] = h[i] ? atomicAdd(&bcursor[i], h[i]) : 0;
    __syncthreads();
    for (int i = base + threadIdx.x; i < end; i += 256) {
        int d = dst[i], s = src[i];
        int b = d >> BK_SHIFT;
        int pos = atomicAdd(&cur[b], 1);
        ebuf[pos] = (uint)s | ((uint)(d & (BK_SIZE - 1)) << 24);
    }
}

__global__ void bucket_build_kernel(const uint* __restrict__ ebuf, const int* __restrict__ bbase,
                                    int* __restrict__ deg_e, int* __restrict__ offsets,
                                    float* __restrict__ dis, int* __restrict__ ssrc, int N) {
    __shared__ int cnt[256], off[256], cur[256];
    int b = blockIdx.x;
    int t = threadIdx.x;
    cnt[t] = 0;
    __syncthreads();
    int e0 = bbase[b], e1 = bbase[b + 1];
    for (int i = e0 + t; i < e1; i += 256)
        atomicAdd(&cnt[ebuf[i] >> 24], 1);
    __syncthreads();
    int v = cnt[t];
    off[t] = v;
    __syncthreads();
    for (int o = 1; o < 256; o <<= 1) {
        int u = (t >= o) ? off[t - o] : 0;
        __syncthreads();
        off[t] += u;
        __syncthreads();
    }
    int excl = off[t] - v;
    int d = b * BK_SIZE + t;
    if (d < N) {
        deg_e[d] = v;
        offsets[d] = e0 + excl;
        dis[d] = rsqrtf((float)(v + 1));
    }
    cur[t] = excl;
    __syncthreads();
    for (int i = e0 + t; i < e1; i += 256) {
        uint e = ebuf[i];
        int ld = e >> 24;
        int pos = atomicAdd(&cur[ld], 1);
        ssrc[e0 + pos] = (int)(e & 0xFFFFFFu);
    }
}

// --- weight repack (once per launch, tiny) -----------------------------------
// B-fragment layout: Wp[((kc*NCOL + c)*32) + kk] = bf16(W[(kc*32+kk)*NCOL + c]).

__global__ void w1prep_kernel(const float* __restrict__ W1, ushort* __restrict__ W1bp) {
    int i = blockIdx.x * 256 + threadIdx.x;  // 4*256*32 = 32768
    int kk = i & 31, c = (i >> 5) & 255, kc = i >> 13;
    W1bp[i] = f2bf(W1[(size_t)(kc * 32 + kk) * HID_F + c]);
}

__global__ void w2prep_kernel(const float* __restrict__ W2, ushort* __restrict__ W2bp) {
    int i = blockIdx.x * 256 + threadIdx.x;  // 8*64*32 = 16384
    int kk = i & 31, c = (i >> 5) & 63, kc = i >> 11;
    W2bp[i] = f2bf(W2[(size_t)(kc * 32 + kk) * OUT_F + c]);
}

// --- compute pipeline --------------------------------------------------------

__global__ void xprep_kernel(const float* __restrict__ x, const float* __restrict__ dis,
                             uint* __restrict__ xs, int N) {
    int i = blockIdx.x * 256 + threadIdx.x;
    if (i < N * (IN_F / 2)) {
        int n = i >> 6;
        float dn = dis[n];
        float2 v = ((const float2*)x)[i];
        xs[i] = (uint)f2bf(dn * v.x) | ((uint)f2bf(dn * v.y) << 16);
    }
}

// zb[d] = bf16(dis[d]*(sum_e xs[s] + xs[d])).  One wave per node; 2 edges/iter.
__global__ void aggx_kernel(const uint* __restrict__ xs, const int* __restrict__ ssrc,
                            const int* __restrict__ offsets, const int* __restrict__ deg_e,
                            const float* __restrict__ dis, uint* __restrict__ zb, int N) {
    int lane = threadIdx.x & 63;
    int n = blockIdx.x * 4 + (threadIdx.x >> 6);
    if (n >= N) return;
    int half = lane >> 5;
    int ck = lane & 31;
    float4 acc = make_float4(0.f, 0.f, 0.f, 0.f);
    int start = offsets[n], cnt = deg_e[n];
    for (int base = 0; base < cnt; base += 64) {
        int m = min(64, cnt - base);
        int idx = base + lane;
        int cl = idx < cnt ? idx : cnt - 1;
        int sv = ssrc[start + cl];
        int pairs = (m + 1) >> 1;
#pragma unroll 4
        for (int p = 0; p < pairs; p++) {
            int e1 = 2 * p + 1;
            int s0 = bcast_i(sv, 2 * p);
            int s1 = bcast_i(sv, e1 < m ? e1 : 2 * p);
            float w1 = (e1 < m) ? 1.f : 0.f;
            int s = half ? s1 : s0;
            float w = half ? w1 : 1.f;
            uint2 u = *(const uint2*)(xs + (size_t)s * 64 + ck * 2);
            acc.x = fmaf(w, bf_lo(u.x), acc.x);
            acc.y = fmaf(w, bf_hi(u.x), acc.y);
            acc.z = fmaf(w, bf_lo(u.y), acc.z);
            acc.w = fmaf(w, bf_hi(u.y), acc.w);
        }
    }
    acc.x += __shfl_down(acc.x, 32);
    acc.y += __shfl_down(acc.y, 32);
    acc.z += __shfl_down(acc.z, 32);
    acc.w += __shfl_down(acc.w, 32);
    if (half == 0) {
        uint2 u = *(const uint2*)(xs + (size_t)n * 64 + ck * 2);
        acc.x += bf_lo(u.x);
        acc.y += bf_hi(u.x);
        acc.z += bf_lo(u.y);
        acc.w += bf_hi(u.y);
        float dn = dis[n];
        uint2 o;
        o.x = (uint)f2bf(dn * acc.x) | ((uint)f2bf(dn * acc.y) << 16);
        o.y = (uint)f2bf(dn * acc.z) | ((uint)f2bf(dn * acc.w) << 16);
        *(uint2*)(zb + (size_t)n * 64 + ck * 2) = o;
    }
}

// out1b = bf16(zb @ W1 + b1).  Block: 64 nodes x 256 cols, 4 waves; each wave
// a 64-col stripe = 4x4 MFMA 16x16x32 tiles over K=128 (4 chunks).
__global__ __launch_bounds__(256) void gemm1_kernel(const uint* __restrict__ zb,
                                                    const uint* __restrict__ W1bp,
                                                    const float* __restrict__ b1,
                                                    ushort* __restrict__ out1b, int N) {
    __shared__ uint A[64][68];  // [row][k/2], stride 68 -> 16B-aligned, 2-way free
    int t = threadIdx.x;
    int n0 = blockIdx.x * 64;
    for (int i = t; i < 64 * 16; i += 256) {
        int r = i >> 4, q = i & 15;
        int node = n0 + r;
        uint4 v = make_uint4(0u, 0u, 0u, 0u);
        if (node < N) v = *(const uint4*)(zb + (size_t)node * 64 + q * 4);
        *(uint4*)(&A[r][q * 4]) = v;
    }
    __syncthreads();
    int wave = t >> 6, lane = t & 63;
    int quad = lane >> 4, lrow = lane & 15;
    f32x4 acc[4][4];
#pragma unroll
    for (int m = 0; m < 4; m++)
#pragma unroll
        for (int nt = 0; nt < 4; nt++) acc[m][nt] = (f32x4)(0.f);
#pragma unroll
    for (int kc = 0; kc < 4; kc++) {
        bf16x8 bfr[4];
#pragma unroll
        for (int nt = 0; nt < 4; nt++) {
            int c = wave * 64 + nt * 16 + lrow;
            bfr[nt] = *(const bf16x8*)(W1bp + ((size_t)(kc * 256 + c) * 16 + quad * 4));
        }
        bf16x8 afr[4];
#pragma unroll
        for (int m = 0; m < 4; m++)
            afr[m] = *(const bf16x8*)(&A[m * 16 + lrow][kc * 16 + quad * 4]);
#pragma unroll
        for (int m = 0; m < 4; m++)
#pragma unroll
            for (int nt = 0; nt < 4; nt++)
                acc[m][nt] = __builtin_amdgcn_mfma_f32_16x16x32_bf16(
                    afr[m], bfr[nt], acc[m][nt], 0, 0, 0);
    }
#pragma unroll
    for (int nt = 0; nt < 4; nt++) {
        int c = wave * 64 + nt * 16 + lrow;
        float bb = b1[c];
#pragma unroll
        for (int m = 0; m < 4; m++) {
#pragma unroll
            for (int r = 0; r < 4; r++) {
                int node = n0 + m * 16 + quad * 4 + r;
                if (node < N) out1b[(size_t)node * HID_F + c] = f2bf(acc[m][nt][r] + bb);
            }
        }
    }
}

// Per-column BN stats from bf16 out1.
__global__ void bnreduce_kernel(const ushort* __restrict__ out1b, float* __restrict__ sums,
                                float* __restrict__ sumsq, int N) {
    int j = threadIdx.x;
    int r0 = blockIdx.x * 128;
    float s = 0.f, sq = 0.f;
    int rend = min(128, N - r0);
    for (int r = 0; r < rend; r++) {
        float v = __uint_as_float((uint)out1b[(size_t)(r0 + r) * HID_F + j] << 16);
        s += v;
        sq = fmaf(v, v, sq);
    }
    atomicAdd(&sums[j], s);
    atomicAdd(&sumsq[j], sq);
}

__global__ void bnfinal_kernel(float* __restrict__ bn, const float* __restrict__ gamma,
                               const float* __restrict__ beta, int N) {
    int j = threadIdx.x;
    float invN = 1.0f / (float)N;
    float mean = bn[j] * invN;
    float var = bn[256 + j] * invN - mean * mean;
    float sc = gamma[j] * rsqrtf(fmaxf(var, 0.f) + 1e-5f);
    bn[512 + j] = sc;
    bn[768 + j] = beta[j] - mean * sc;
}

// gs = bf16(dis * (relu(bn(out1b)) @ W2)).  Block: 64 nodes x 64 cols, 4 waves;
// each wave a 16-col stripe = 4x1 MFMA tiles over K=256 (8 chunks).
__global__ __launch_bounds__(256) void gemm2_kernel(const ushort* __restrict__ out1b,
                                                    const uint* __restrict__ W2bp,
                                                    const float* __restrict__ dis,
                                                    const float* __restrict__ bn,
                                                    ushort* __restrict__ gs, int N) {
    __shared__ uint A[64][132];  // [row][k/2], stride 132 -> 16B-aligned
    const float* bnscale = bn + 512;
    const float* bnbias  = bn + 768;
    const uint* out1u = (const uint*)out1b;
    int t = threadIdx.x;
    int n0 = blockIdx.x * 64;
    for (int i = t; i < 64 * 64; i += 256) {  // uint2 = 4 cols each
        int r = i >> 6, u2 = i & 63;
        int node = n0 + r;
        uint2 p = make_uint2(0u, 0u);
        if (node < N) {
            uint2 v = *(const uint2*)(out1u + (size_t)node * 128 + u2 * 2);
            float4 scl = *(const float4*)(bnscale + u2 * 4);
            float4 bia = *(const float4*)(bnbias + u2 * 4);
            float r0 = fmaxf(fmaf(bf_lo(v.x), scl.x, bia.x), 0.f);
            float r1 = fmaxf(fmaf(bf_hi(v.x), scl.y, bia.y), 0.f);
            float r2 = fmaxf(fmaf(bf_lo(v.y), scl.z, bia.z), 0.f);
            float r3 = fmaxf(fmaf(bf_hi(v.y), scl.w, bia.w), 0.f);
            p.x = (uint)f2bf(r0) | ((uint)f2bf(r1) << 16);
            p.y = (uint)f2bf(r2) | ((uint)f2bf(r3) << 16);
        }
        *(uint2*)(&A[r][u2 * 2]) = p;
    }
    __syncthreads();
    int wave = t >> 6, lane = t & 63;
    int quad = lane >> 4, lrow = lane & 15;
    int c = wave * 16 + lrow;
    f32x4 acc[4];
#pragma unroll
    for (int m = 0; m < 4; m++) acc[m] = (f32x4)(0.f);
#pragma unroll
    for (int kc = 0; kc < 8; kc++) {
        bf16x8 bfr = *(const bf16x8*)(W2bp + ((size_t)(kc * 64 + c) * 16 + quad * 4));
#pragma unroll
        for (int m = 0; m < 4; m++) {
            bf16x8 afr = *(const bf16x8*)(&A[m * 16 + lrow][kc * 16 + quad * 4]);
            acc[m] = __builtin_amdgcn_mfma_f32_16x16x32_bf16(afr, bfr, acc[m], 0, 0, 0);
        }
    }
#pragma unroll
    for (int m = 0; m < 4; m++) {
#pragma unroll
        for (int r = 0; r < 4; r++) {
            int node = n0 + m * 16 + quad * 4 + r;
            if (node < N) gs[(size_t)node * OUT_F + c] = f2bf(dis[node] * acc[m][r]);
        }
    }
}

// out[d] = dis[d]*(sum_e gs[s] + gs[d]) + b2.  One wave per node; 4 edges/iter.
__global__ void agg2_kernel(const uint* __restrict__ gs, const int* __restrict__ ssrc,
                            const int* __restrict__ offsets, const int* __restrict__ deg_e,
                            const float* __restrict__ dis, const float* __restrict__ b2,
                            float* __restrict__ out, int N) {
    int lane = threadIdx.x & 63;
    int n = blockIdx.x * 4 + (threadIdx.x >> 6);
    if (n >= N) return;
    int grp = lane >> 4;
    int ck = lane & 15;
    int b0 = grp & 1, b1g = grp >> 1;
    float4 acc = make_float4(0.f, 0.f, 0.f, 0.f);
    int start = offsets[n], cnt = deg_e[n];
    for (int base = 0; base < cnt; base += 64) {
        int m = min(64, cnt - base);
        int idx = base + lane;
        int cl = idx < cnt ? idx : cnt - 1;
        int sv = ssrc[start + cl];
        int quads = (m + 3) >> 2;
#pragma unroll 4
        for (int q = 0; q < quads; q++) {
            int e0 = 4 * q, e1 = e0 + 1, e2 = e0 + 2, e3 = e0 + 3;
            int s0 = bcast_i(sv, e0);
            int s1 = bcast_i(sv, e1 < m ? e1 : e0);
            int s2 = bcast_i(sv, e2 < m ? e2 : e0);
            int s3 = bcast_i(sv, e3 < m ? e3 : e0);
            float w1 = e1 < m ? 1.f : 0.f;
            float w2 = e2 < m ? 1.f : 0.f;
            float w3 = e3 < m ? 1.f : 0.f;
            int sA = b0 ? s1 : s0;
            int sB = b0 ? s3 : s2;
            int s = b1g ? sB : sA;
            float wA = b0 ? w1 : 1.f;
            float wB = b0 ? w3 : w2;
            float w = b1g ? wB : wA;
            uint2 u = *(const uint2*)(gs + (size_t)s * (OUT_F / 2) + ck * 2);
            acc.x = fmaf(w, bf_lo(u.x), acc.x);
            acc.y = fmaf(w, bf_hi(u.x), acc.y);
            acc.z = fmaf(w, bf_lo(u.y), acc.z);
            acc.w = fmaf(w, bf_hi(u.y), acc.w);
        }
    }
    acc.x += __shfl_down(acc.x, 32);
    acc.y += __shfl_down(acc.y, 32);
    acc.z += __shfl_down(acc.z, 32);
    acc.w += __shfl_down(acc.w, 32);
    acc.x += __shfl_down(acc.x, 16);
    acc.y += __shfl_down(acc.y, 16);
    acc.z += __shfl_down(acc.z, 16);
    acc.w += __shfl_down(acc.w, 16);
    if (grp == 0) {
        uint2 u = *(const uint2*)(gs + (size_t)n * (OUT_F / 2) + ck * 2);
        acc.x += bf_lo(u.x);
        acc.y += bf_hi(u.x);
        acc.z += bf_lo(u.y);
        acc.w += bf_hi(u.y);
        float dn = dis[n];
        float4 bb = ((const float4*)b2)[ck];
        ((float4*)(out + (size_t)n * OUT_F))[ck] =
            make_float4(fmaf(dn, acc.x, bb.x), fmaf(dn, acc.y, bb.y),
                        fmaf(dn, acc.z, bb.z), fmaf(dn, acc.w, bb.w));
    }
}

extern "C" void kernel_launch(void* const* d_in, const int* in_sizes, int n_in,
                              void* d_out, int out_size, void* d_ws, size_t ws_size,
                              hipStream_t stream) {
    const float* x      = (const float*)d_in[0];
    const int*   edges  = (const int*)d_in[1];
    const float* W1     = (const float*)d_in[2];
    const float* b1     = (const float*)d_in[3];
    const float* gamma1 = (const float*)d_in[4];
    const float* beta1  = (const float*)d_in[5];
    const float* W2     = (const float*)d_in[6];
    const float* b2     = (const float*)d_in[7];
    float* out = (float*)d_out;

    int N = in_sizes[0] / IN_F;
    int E = in_sizes[1] / 2;
    const int* src = edges;
    const int* dst = edges + E;
    int NB = (N + BK_SIZE - 1) / BK_SIZE;
    int nchunks = (E + CHUNK - 1) / CHUNK;

    char* ws = (char*)d_ws;
    size_t off = 0;
    auto alloc = [&](size_t bytes) -> void* {
        void* p = ws + off;
        off += (bytes + 255) & ~(size_t)255;
        return p;
    };
    int*    deg_e   = (int*)alloc((size_t)N * 4);
    int*    offsets = (int*)alloc((size_t)N * 4);
    float*  dis     = (float*)alloc((size_t)N * 4);
    int*    bhist   = (int*)alloc(512 * 4);
    int*    bbase   = (int*)alloc(513 * 4);
    int*    bcursor = (int*)alloc(512 * 4);
    int*    ssrc    = (int*)alloc((size_t)E * 4);
    uint*   ebuf    = (uint*)alloc((size_t)E * 4);
    uint*   xs      = (uint*)alloc((size_t)N * (IN_F / 2) * 4);
    uint*   zb      = (uint*)alloc((size_t)N * (IN_F / 2) * 4);   // bf16 z
    ushort* out1b   = (ushort*)alloc((size_t)N * HID_F * 2);      // bf16 out1
    float*  bn      = (float*)alloc(4 * 256 * 4);
    ushort* W1bp    = (ushort*)alloc(4 * 256 * 32 * 2);
    ushort* W2bp    = (ushort*)alloc(8 * 64 * 32 * 2);
    ushort* gs      = (ushort*)zb;  // alias: zb dead after gemm1

    hipMemsetAsync(bhist, 0, 512 * 4, stream);
    hipMemsetAsync(bn, 0, 2 * 256 * 4, stream);

    bucket_hist_kernel<<<nchunks, 256, 0, stream>>>(dst, bhist, E, NB);
    bucket_scan_kernel<<<1, 512, 0, stream>>>(bhist, bbase, bcursor, NB, E);
    bucket_scatter_kernel<<<nchunks, 256, 0, stream>>>(src, dst, bcursor, ebuf, E, NB);
    bucket_build_kernel<<<NB, 256, 0, stream>>>(ebuf, bbase, deg_e, offsets, dis, ssrc, N);

    w1prep_kernel<<<128, 256, 0, stream>>>(W1, W1bp);
    w2prep_kernel<<<64, 256, 0, stream>>>(W2, W2bp);

    xprep_kernel<<<(N * (IN_F / 2) + 255) / 256, 256, 0, stream>>>(x, dis, xs, N);
    aggx_kernel<<<(N + 3) / 4, 256, 0, stream>>>(xs, ssrc, offsets, deg_e, dis, zb, N);
    gemm1_kernel<<<(N + 63) / 64, 256, 0, stream>>>(zb, (const uint*)W1bp, b1, out1b, N);
    bnreduce_kernel<<<(N + 127) / 128, 256, 0, stream>>>(out1b, bn, bn + 256, N);
    bnfinal_kernel<<<1, 256, 0, stream>>>(bn, gamma1, beta1, N);
    gemm2_kernel<<<(N + 63) / 64, 256, 0, stream>>>(out1b, (const uint*)W2bp, dis, bn, gs, N);
    agg2_kernel<<<(N + 3) / 4, 256, 0, stream>>>((const uint*)gs, ssrc, offsets, deg_e, dis,
                                                 b2, out, N);
}

// Round 7
// 404.200 us; speedup vs baseline: 3.0156x; 1.0626x over previous
//
#include <hip/hip_runtime.h>
#include <hip/hip_bf16.h>

// GraphSAINT 2-layer GCN forward on MI355X.
// Layer 1: xs[n] = bf16(dis[n]*x[n]);  zb[d] = bf16(dis[d]*(sum_e xs[s] + xs[d]));
//          out1b = bf16(zb @ W1 + b1)   (bf16 MFMA, fp32 accum).
// Layer 2: gs[n] = bf16(dis[n]*(relu(bn(out1b[n])) @ W2))  (bf16 MFMA);
//          out[d] = dis[d]*(sum_e gs[s] + gs[d]) + b2  (fp32).
// CSR via 2-level radix sort (bucket = dst>>8); edge lists sentinel-padded to
// a multiple of 4 (sentinel row N is all-zeros) so agg loops are branch-free.

#define IN_F  128
#define HID_F 256
#define OUT_F 64
#define BK_SHIFT 8
#define BK_SIZE  256
#define CHUNK    8192

typedef unsigned int uint;
typedef unsigned short ushort;
typedef short bf16x8 __attribute__((ext_vector_type(8)));
typedef float f32x4 __attribute__((ext_vector_type(4)));

__device__ __forceinline__ int bcast_i(int v, int l) {
    return __builtin_amdgcn_readlane(v, l);
}
__device__ __forceinline__ ushort f2bf(float f) {
    uint u = __float_as_uint(f);
    uint r = (u + 0x7fffu + ((u >> 16) & 1u)) >> 16;  // RNE
    return (ushort)r;
}
__device__ __forceinline__ float bf_lo(uint u) { return __uint_as_float(u << 16); }
__device__ __forceinline__ float bf_hi(uint u) { return __uint_as_float(u & 0xffff0000u); }

// --- sort pipeline -----------------------------------------------------------

__global__ void bucket_hist_kernel(const int* __restrict__ dst, int* __restrict__ bhist,
                                   int E, int NB) {
    __shared__ int h[512];
    for (int i = threadIdx.x; i < NB; i += 256) h[i] = 0;
    __syncthreads();
    int base = blockIdx.x * CHUNK;
    int end = min(base + CHUNK, E);
    for (int i = base + threadIdx.x; i < end; i += 256)
        atomicAdd(&h[dst[i] >> BK_SHIFT], 1);
    __syncthreads();
    for (int i = threadIdx.x; i < NB; i += 256)
        if (h[i]) atomicAdd(&bhist[i], h[i]);
}

__global__ void bucket_scan_kernel(const int* __restrict__ bhist, int* __restrict__ bbase,
                                   int* __restrict__ bcursor, int NB, int E) {
    __shared__ int sh[512];
    int t = threadIdx.x;
    int v = (t < NB) ? bhist[t] : 0;
    sh[t] = v;
    __syncthreads();
    for (int off = 1; off < 512; off <<= 1) {
        int u = (t >= off) ? sh[t - off] : 0;
        __syncthreads();
        sh[t] += u;
        __syncthreads();
    }
    if (t < NB) { int b = sh[t] - v; bbase[t] = b; bcursor[t] = b; }
    if (t == 0) bbase[NB] = E;
}

__global__ void bucket_scatter_kernel(const int* __restrict__ src, const int* __restrict__ dst,
                                      int* __restrict__ bcursor, uint* __restrict__ ebuf,
                                      int E, int NB) {
    __shared__ int h[512];
    __shared__ int cur[512];
    for (int i = threadIdx.x; i < NB; i += 256) h[i] = 0;
    __syncthreads();
    int base = blockIdx.x * CHUNK;
    int end = min(base + CHUNK, E);
    for (int i = base + threadIdx.x; i < end; i += 256)
        atomicAdd(&h[dst[i] >> BK_SHIFT], 1);
    __syncthreads();
    for (int i = threadIdx.x; i < NB; i += 256)
        cur[i] = h[i] ? atomicAdd(&bcursor[i], h[i]) : 0;
    __syncthreads();
    for (int i = base + threadIdx.x; i < end; i += 256) {
        int d = dst[i], s = src[i];
        int b = d >> BK_SHIFT;
        int pos = atomicAdd(&cur[b], 1);
        ebuf[pos] = (uint)s | ((uint)(d & (BK_SIZE - 1)) << 24);
    }
}

// One block per bucket.  Pads each node's edge list to a multiple of 4 with
// sentinel src = N (zero feature row); padded bucket region base = bbase[b]+768*b.
__global__ void bucket_build_kernel(const uint* __restrict__ ebuf, const int* __restrict__ bbase,
                                    int* __restrict__ deg_e, int* __restrict__ offsets,
                                    float* __restrict__ dis, int* __restrict__ ssrc, int N) {
    __shared__ int cnt[256], off[256], cur[256];
    int b = blockIdx.x;
    int t = threadIdx.x;
    cnt[t] = 0;
    __syncthreads();
    int e0 = bbase[b], e1 = bbase[b + 1];
    for (int i = e0 + t; i < e1; i += 256)
        atomicAdd(&cnt[ebuf[i] >> 24], 1);
    __syncthreads();
    int v = cnt[t];
    int vpad = (v + 3) & ~3;
    off[t] = vpad;
    __syncthreads();
    for (int o = 1; o < 256; o <<= 1) {
        int u = (t >= o) ? off[t - o] : 0;
        __syncthreads();
        off[t] += u;
        __syncthreads();
    }
    int excl = off[t] - vpad;
    int base_pad = e0 + b * 768;
    int d = b * BK_SIZE + t;
    if (d < N) {
        deg_e[d] = vpad;                       // padded loop bound for aggs
        offsets[d] = base_pad + excl;
        dis[d] = rsqrtf((float)(v + 1));
    }
    cur[t] = excl;
    __syncthreads();
    for (int i = e0 + t; i < e1; i += 256) {
        uint e = ebuf[i];
        int ld = e >> 24;
        int pos = atomicAdd(&cur[ld], 1);
        ssrc[base_pad + pos] = (int)(e & 0xFFFFFFu);
    }
    __syncthreads();
    for (int i = v; i < vpad; i++)             // sentinel fill (<=3 per node)
        ssrc[base_pad + excl + i] = N;
}

// --- weight repack (once per launch, tiny) -----------------------------------
// B-fragment layout: Wp[((kc*NCOL + c)*32) + kk] = bf16(W[(kc*32+kk)*NCOL + c]).
__global__ void wprep_kernel(const float* __restrict__ W1, const float* __restrict__ W2,
                             ushort* __restrict__ W1bp, ushort* __restrict__ W2bp) {
    int i = blockIdx.x * 256 + threadIdx.x;  // 32768 + 16384
    if (i < 32768) {
        int kk = i & 31, c = (i >> 5) & 255, kc = i >> 13;
        W1bp[i] = f2bf(W1[(size_t)(kc * 32 + kk) * HID_F + c]);
    } else {
        int j = i - 32768;
        int kk = j & 31, c = (j >> 5) & 63, kc = j >> 11;
        W2bp[j] = f2bf(W2[(size_t)(kc * 32 + kk) * OUT_F + c]);
    }
}

// --- compute pipeline --------------------------------------------------------

// xs has N+1 rows; row N is zeros (sentinel).
__global__ void xprep_kernel(const float* __restrict__ x, const float* __restrict__ dis,
                             uint* __restrict__ xs, int N) {
    int i = blockIdx.x * 256 + threadIdx.x;
    if (i < (N + 1) * (IN_F / 2)) {
        int n = i >> 6;
        if (n >= N) { xs[i] = 0u; return; }
        float dn = dis[n];
        float2 v = ((const float2*)x)[i];
        xs[i] = (uint)f2bf(dn * v.x) | ((uint)f2bf(dn * v.y) << 16);
    }
}

// zb[d] = bf16(dis[d]*(sum_e xs[s] + xs[d])).  One wave per node; 4 edges/round,
// 16-lane groups, uint4 (16B) per lane.  Edge lists are sentinel-padded to 4.
__global__ void aggx_kernel(const uint* __restrict__ xs, const int* __restrict__ ssrc,
                            const int* __restrict__ offsets, const int* __restrict__ deg_e,
                            const float* __restrict__ dis, uint* __restrict__ zb, int N) {
    int lane = threadIdx.x & 63;
    int n = blockIdx.x * 4 + (threadIdx.x >> 6);
    if (n >= N) return;
    int grp = lane >> 4;
    int ck = lane & 15;
    bool g0 = (grp & 1) != 0, g1 = (grp & 2) != 0;
    float acc[8];
#pragma unroll
    for (int i = 0; i < 8; i++) acc[i] = 0.f;
    int start = offsets[n], cnt = deg_e[n];  // cnt % 4 == 0
    for (int base = 0; base < cnt; base += 64) {
        int m = min(64, cnt - base);
        int idx = base + lane;
        int sv = ssrc[start + (idx < cnt ? idx : cnt - 1)];
        int rounds = m >> 2;
#pragma unroll 2
        for (int q = 0; q < rounds; q++) {
            int s0 = bcast_i(sv, 4 * q + 0);
            int s1 = bcast_i(sv, 4 * q + 1);
            int s2 = bcast_i(sv, 4 * q + 2);
            int s3 = bcast_i(sv, 4 * q + 3);
            int sA = g0 ? s1 : s0;
            int sB = g0 ? s3 : s2;
            int s = g1 ? sB : sA;
            uint4 u = *(const uint4*)(xs + ((size_t)s << 6) + (ck << 2));
            acc[0] += bf_lo(u.x); acc[1] += bf_hi(u.x);
            acc[2] += bf_lo(u.y); acc[3] += bf_hi(u.y);
            acc[4] += bf_lo(u.z); acc[5] += bf_hi(u.z);
            acc[6] += bf_lo(u.w); acc[7] += bf_hi(u.w);
        }
    }
#pragma unroll
    for (int i = 0; i < 8; i++) acc[i] += __shfl_down(acc[i], 32);
#pragma unroll
    for (int i = 0; i < 8; i++) acc[i] += __shfl_down(acc[i], 16);
    if (grp == 0) {
        uint4 u = *(const uint4*)(xs + ((size_t)n << 6) + (ck << 2));  // self
        acc[0] += bf_lo(u.x); acc[1] += bf_hi(u.x);
        acc[2] += bf_lo(u.y); acc[3] += bf_hi(u.y);
        acc[4] += bf_lo(u.z); acc[5] += bf_hi(u.z);
        acc[6] += bf_lo(u.w); acc[7] += bf_hi(u.w);
        float dn = dis[n];
        uint4 o;
        o.x = (uint)f2bf(dn * acc[0]) | ((uint)f2bf(dn * acc[1]) << 16);
        o.y = (uint)f2bf(dn * acc[2]) | ((uint)f2bf(dn * acc[3]) << 16);
        o.z = (uint)f2bf(dn * acc[4]) | ((uint)f2bf(dn * acc[5]) << 16);
        o.w = (uint)f2bf(dn * acc[6]) | ((uint)f2bf(dn * acc[7]) << 16);
        *(uint4*)(zb + ((size_t)n << 6) + (ck << 2)) = o;
    }
}

// out1b = bf16(zb @ W1 + b1).  Block: 64 nodes x 256 cols, 4 waves.
__global__ __launch_bounds__(256) void gemm1_kernel(const uint* __restrict__ zb,
                                                    const uint* __restrict__ W1bp,
                                                    const float* __restrict__ b1,
                                                    ushort* __restrict__ out1b, int N) {
    __shared__ uint A[64][68];
    int t = threadIdx.x;
    int n0 = blockIdx.x * 64;
    for (int i = t; i < 64 * 16; i += 256) {
        int r = i >> 4, q = i & 15;
        int node = n0 + r;
        uint4 v = make_uint4(0u, 0u, 0u, 0u);
        if (node < N) v = *(const uint4*)(zb + (size_t)node * 64 + q * 4);
        *(uint4*)(&A[r][q * 4]) = v;
    }
    __syncthreads();
    int wave = t >> 6, lane = t & 63;
    int quad = lane >> 4, lrow = lane & 15;
    f32x4 acc[4][4];
#pragma unroll
    for (int m = 0; m < 4; m++)
#pragma unroll
        for (int nt = 0; nt < 4; nt++) acc[m][nt] = (f32x4)(0.f);
#pragma unroll
    for (int kc = 0; kc < 4; kc++) {
        bf16x8 bfr[4];
#pragma unroll
        for (int nt = 0; nt < 4; nt++) {
            int c = wave * 64 + nt * 16 + lrow;
            bfr[nt] = *(const bf16x8*)(W1bp + ((size_t)(kc * 256 + c) * 16 + quad * 4));
        }
        bf16x8 afr[4];
#pragma unroll
        for (int m = 0; m < 4; m++)
            afr[m] = *(const bf16x8*)(&A[m * 16 + lrow][kc * 16 + quad * 4]);
#pragma unroll
        for (int m = 0; m < 4; m++)
#pragma unroll
            for (int nt = 0; nt < 4; nt++)
                acc[m][nt] = __builtin_amdgcn_mfma_f32_16x16x32_bf16(
                    afr[m], bfr[nt], acc[m][nt], 0, 0, 0);
    }
#pragma unroll
    for (int nt = 0; nt < 4; nt++) {
        int c = wave * 64 + nt * 16 + lrow;
        float bb = b1[c];
#pragma unroll
        for (int m = 0; m < 4; m++) {
#pragma unroll
            for (int r = 0; r < 4; r++) {
                int node = n0 + m * 16 + quad * 4 + r;
                if (node < N) out1b[(size_t)node * HID_F + c] = f2bf(acc[m][nt][r] + bb);
            }
        }
    }
}

__global__ void bnreduce_kernel(const ushort* __restrict__ out1b, float* __restrict__ sums,
                                float* __restrict__ sumsq, int N) {
    int j = threadIdx.x;
    int r0 = blockIdx.x * 128;
    float s = 0.f, sq = 0.f;
    int rend = min(128, N - r0);
    for (int r = 0; r < rend; r++) {
        float v = __uint_as_float((uint)out1b[(size_t)(r0 + r) * HID_F + j] << 16);
        s += v;
        sq = fmaf(v, v, sq);
    }
    atomicAdd(&sums[j], s);
    atomicAdd(&sumsq[j], sq);
}

// gs = bf16(dis * (relu(bn(out1b)) @ W2)).  BN scale/bias computed in-block.
// gs has N+1 rows; row N zeroed by block 0 (sentinel for agg2).
__global__ __launch_bounds__(256) void gemm2_kernel(const ushort* __restrict__ out1b,
                                                    const uint* __restrict__ W2bp,
                                                    const float* __restrict__ dis,
                                                    const float* __restrict__ bnsums,
                                                    const float* __restrict__ gamma,
                                                    const float* __restrict__ beta,
                                                    ushort* __restrict__ gs, int N) {
    __shared__ uint A[64][132];
    __shared__ float bns[256], bnb[256];
    const uint* out1u = (const uint*)out1b;
    int t = threadIdx.x;
    int n0 = blockIdx.x * 64;
    if (blockIdx.x == 0 && t < 32) ((uint*)gs)[(size_t)N * 32 + t] = 0u;  // sentinel row
    {
        float invN = 1.0f / (float)N;
        float mean = bnsums[t] * invN;
        float var = bnsums[256 + t] * invN - mean * mean;
        float sc = gamma[t] * rsqrtf(fmaxf(var, 0.f) + 1e-5f);
        bns[t] = sc;
        bnb[t] = beta[t] - mean * sc;
    }
    __syncthreads();
    for (int i = t; i < 64 * 64; i += 256) {
        int r = i >> 6, u2 = i & 63;
        int node = n0 + r;
        uint2 p = make_uint2(0u, 0u);
        if (node < N) {
            uint2 v = *(const uint2*)(out1u + (size_t)node * 128 + u2 * 2);
            float r0 = fmaxf(fmaf(bf_lo(v.x), bns[u2 * 4 + 0], bnb[u2 * 4 + 0]), 0.f);
            float r1 = fmaxf(fmaf(bf_hi(v.x), bns[u2 * 4 + 1], bnb[u2 * 4 + 1]), 0.f);
            float r2 = fmaxf(fmaf(bf_lo(v.y), bns[u2 * 4 + 2], bnb[u2 * 4 + 2]), 0.f);
            float r3 = fmaxf(fmaf(bf_hi(v.y), bns[u2 * 4 + 3], bnb[u2 * 4 + 3]), 0.f);
            p.x = (uint)f2bf(r0) | ((uint)f2bf(r1) << 16);
            p.y = (uint)f2bf(r2) | ((uint)f2bf(r3) << 16);
        }
        *(uint2*)(&A[r][u2 * 2]) = p;
    }
    __syncthreads();
    int wave = t >> 6, lane = t & 63;
    int quad = lane >> 4, lrow = lane & 15;
    int c = wave * 16 + lrow;
    f32x4 acc[4];
#pragma unroll
    for (int m = 0; m < 4; m++) acc[m] = (f32x4)(0.f);
#pragma unroll
    for (int kc = 0; kc < 8; kc++) {
        bf16x8 bfr = *(const bf16x8*)(W2bp + ((size_t)(kc * 64 + c) * 16 + quad * 4));
#pragma unroll
        for (int m = 0; m < 4; m++) {
            bf16x8 afr = *(const bf16x8*)(&A[m * 16 + lrow][kc * 16 + quad * 4]);
            acc[m] = __builtin_amdgcn_mfma_f32_16x16x32_bf16(afr, bfr, acc[m], 0, 0, 0);
        }
    }
#pragma unroll
    for (int m = 0; m < 4; m++) {
#pragma unroll
        for (int r = 0; r < 4; r++) {
            int node = n0 + m * 16 + quad * 4 + r;
            if (node < N) gs[(size_t)node * OUT_F + c] = f2bf(dis[node] * acc[m][r]);
        }
    }
}

// out[d] = dis[d]*(sum_e gs[s] + gs[d]) + b2.  One wave per node; 8 edges/round,
// 8-lane groups, uint4 per lane; trailing quad handled with a sentinel-guarded
// 4-edge mini-round (groups 4..7 read the zero row).
__global__ void agg2_kernel(const uint* __restrict__ gs, const int* __restrict__ ssrc,
                            const int* __restrict__ offsets, const int* __restrict__ deg_e,
                            const float* __restrict__ dis, const float* __restrict__ b2,
                            float* __restrict__ out, int N) {
    int lane = threadIdx.x & 63;
    int n = blockIdx.x * 4 + (threadIdx.x >> 6);
    if (n >= N) return;
    int grp = lane >> 3;
    int ck = lane & 7;
    bool g0 = (grp & 1) != 0, g1 = (grp & 2) != 0, g2 = (grp & 4) != 0;
    float acc[8];
#pragma unroll
    for (int i = 0; i < 8; i++) acc[i] = 0.f;
    int start = offsets[n], cnt = deg_e[n];  // cnt % 4 == 0
    for (int base = 0; base < cnt; base += 64) {
        int m = min(64, cnt - base);
        int idx = base + lane;
        int sv = ssrc[start + (idx < cnt ? idx : cnt - 1)];
        int rounds = m >> 3;
#pragma unroll 2
        for (int q = 0; q < rounds; q++) {
            int s0 = bcast_i(sv, 8 * q + 0);
            int s1 = bcast_i(sv, 8 * q + 1);
            int s2 = bcast_i(sv, 8 * q + 2);
            int s3 = bcast_i(sv, 8 * q + 3);
            int s4 = bcast_i(sv, 8 * q + 4);
            int s5 = bcast_i(sv, 8 * q + 5);
            int s6 = bcast_i(sv, 8 * q + 6);
            int s7 = bcast_i(sv, 8 * q + 7);
            int sA = g0 ? s1 : s0;
            int sB = g0 ? s3 : s2;
            int sC = g0 ? s5 : s4;
            int sD = g0 ? s7 : s6;
            int sE = g1 ? sB : sA;
            int sF = g1 ? sD : sC;
            int s = g2 ? sF : sE;
            uint4 u = *(const uint4*)(gs + ((size_t)s << 5) + (ck << 2));
            acc[0] += bf_lo(u.x); acc[1] += bf_hi(u.x);
            acc[2] += bf_lo(u.y); acc[3] += bf_hi(u.y);
            acc[4] += bf_lo(u.z); acc[5] += bf_hi(u.z);
            acc[6] += bf_lo(u.w); acc[7] += bf_hi(u.w);
        }
        if (m & 4) {  // trailing quad: groups 0..3 take one edge each, 4..7 sentinel
            int e = 8 * rounds;
            int s0 = bcast_i(sv, e + 0);
            int s1 = bcast_i(sv, e + 1);
            int s2 = bcast_i(sv, e + 2);
            int s3 = bcast_i(sv, e + 3);
            int sA = g0 ? s1 : s0;
            int sB = g0 ? s3 : s2;
            int s = g1 ? sB : sA;
            s = g2 ? N : s;
            uint4 u = *(const uint4*)(gs + ((size_t)s << 5) + (ck << 2));
            acc[0] += bf_lo(u.x); acc[1] += bf_hi(u.x);
            acc[2] += bf_lo(u.y); acc[3] += bf_hi(u.y);
            acc[4] += bf_lo(u.z); acc[5] += bf_hi(u.z);
            acc[6] += bf_lo(u.w); acc[7] += bf_hi(u.w);
        }
    }
#pragma unroll
    for (int i = 0; i < 8; i++) acc[i] += __shfl_down(acc[i], 32);
#pragma unroll
    for (int i = 0; i < 8; i++) acc[i] += __shfl_down(acc[i], 16);
#pragma unroll
    for (int i = 0; i < 8; i++) acc[i] += __shfl_down(acc[i], 8);
    if (grp == 0) {
        uint4 u = *(const uint4*)(gs + ((size_t)n << 5) + (ck << 2));  // self
        acc[0] += bf_lo(u.x); acc[1] += bf_hi(u.x);
        acc[2] += bf_lo(u.y); acc[3] += bf_hi(u.y);
        acc[4] += bf_lo(u.z); acc[5] += bf_hi(u.z);
        acc[6] += bf_lo(u.w); acc[7] += bf_hi(u.w);
        float dn = dis[n];
        float4 bb0 = *(const float4*)(b2 + ck * 8);
        float4 bb1 = *(const float4*)(b2 + ck * 8 + 4);
        float* op = out + (size_t)n * OUT_F + ck * 8;
        *(float4*)op = make_float4(fmaf(dn, acc[0], bb0.x), fmaf(dn, acc[1], bb0.y),
                                   fmaf(dn, acc[2], bb0.z), fmaf(dn, acc[3], bb0.w));
        *(float4*)(op + 4) = make_float4(fmaf(dn, acc[4], bb1.x), fmaf(dn, acc[5], bb1.y),
                                         fmaf(dn, acc[6], bb1.z), fmaf(dn, acc[7], bb1.w));
    }
}

extern "C" void kernel_launch(void* const* d_in, const int* in_sizes, int n_in,
                              void* d_out, int out_size, void* d_ws, size_t ws_size,
                              hipStream_t stream) {
    const float* x      = (const float*)d_in[0];
    const int*   edges  = (const int*)d_in[1];
    const float* W1     = (const float*)d_in[2];
    const float* b1     = (const float*)d_in[3];
    const float* gamma1 = (const float*)d_in[4];
    const float* beta1  = (const float*)d_in[5];
    const float* W2     = (const float*)d_in[6];
    const float* b2     = (const float*)d_in[7];
    float* out = (float*)d_out;

    int N = in_sizes[0] / IN_F;
    int E = in_sizes[1] / 2;
    const int* src = edges;
    const int* dst = edges + E;
    int NB = (N + BK_SIZE - 1) / BK_SIZE;
    int nchunks = (E + CHUNK - 1) / CHUNK;

    char* ws = (char*)d_ws;
    size_t off = 0;
    auto alloc = [&](size_t bytes) -> void* {
        void* p = ws + off;
        off += (bytes + 255) & ~(size_t)255;
        return p;
    };
    int*    deg_e   = (int*)alloc((size_t)N * 4);
    int*    offsets = (int*)alloc((size_t)N * 4);
    float*  dis     = (float*)alloc((size_t)(N + 1) * 4);
    int*    bhist   = (int*)alloc(512 * 4);
    int*    bbase   = (int*)alloc(513 * 4);
    int*    bcursor = (int*)alloc(512 * 4);
    int*    ssrc    = (int*)alloc(((size_t)E + 768 * 512 + 64) * 4);  // padded CSR
    uint*   ebuf    = (uint*)alloc((size_t)E * 4);
    uint*   xs      = (uint*)alloc((size_t)(N + 1) * (IN_F / 2) * 4); // +sentinel row
    uint*   zb      = (uint*)alloc((size_t)N * (IN_F / 2) * 4);
    ushort* out1b   = (ushort*)alloc((size_t)N * HID_F * 2);
    float*  bn      = (float*)alloc(2 * 256 * 4);                     // sums | sumsq
    ushort* W1bp    = (ushort*)alloc(4 * 256 * 32 * 2);
    ushort* W2bp    = (ushort*)alloc(8 * 64 * 32 * 2);
    ushort* gs      = (ushort*)zb;  // alias: zb dead after gemm1; (N+1) rows x 64 bf16
    // zb alloc (N*64 uints = N*256B) covers gs (N+1)*128B since N >= 1.

    hipMemsetAsync(bhist, 0, 512 * 4, stream);
    hipMemsetAsync(bn, 0, 2 * 256 * 4, stream);

    bucket_hist_kernel<<<nchunks, 256, 0, stream>>>(dst, bhist, E, NB);
    bucket_scan_kernel<<<1, 512, 0, stream>>>(bhist, bbase, bcursor, NB, E);
    bucket_scatter_kernel<<<nchunks, 256, 0, stream>>>(src, dst, bcursor, ebuf, E, NB);
    bucket_build_kernel<<<NB, 256, 0, stream>>>(ebuf, bbase, deg_e, offsets, dis, ssrc, N);

    wprep_kernel<<<192, 256, 0, stream>>>(W1, W2, W1bp, W2bp);
    xprep_kernel<<<((N + 1) * (IN_F / 2) + 255) / 256, 256, 0, stream>>>(x, dis, xs, N);
    aggx_kernel<<<(N + 3) / 4, 256, 0, stream>>>(xs, ssrc, offsets, deg_e, dis, zb, N);
    gemm1_kernel<<<(N + 63) / 64, 256, 0, stream>>>(zb, (const uint*)W1bp, b1, out1b, N);
    bnreduce_kernel<<<(N + 127) / 128, 256, 0, stream>>>(out1b, bn, bn + 256, N);
    gemm2_kernel<<<(N + 63) / 64, 256, 0, stream>>>(out1b, (const uint*)W2bp, dis, bn,
                                                    gamma1, beta1, gs, N);
    agg2_kernel<<<(N + 3) / 4, 256, 0, stream>>>((const uint*)gs, ssrc, offsets, deg_e, dis,
                                                 b2, out, N);
}

// Round 8
// 380.173 us; speedup vs baseline: 3.2061x; 1.0632x over previous
//
#include <hip/hip_runtime.h>
#include <hip/hip_bf16.h>

// GraphSAINT 2-layer GCN forward on MI355X.
// Layer 1: xs[n] = bf16(dis[n]*x[n]);  zb[d] = bf16(dis[d]*(sum_e xs[s] + xs[d]));
//          out1b = bf16(zb @ W1 + b1)   (bf16 MFMA, fp32 accum; BN stats fused).
// Layer 2: gs[n] = bf16(dis[n]*(relu(bn(out1b[n])) @ W2))  (bf16 MFMA);
//          out[d] = dis[d]*(sum_e gs[s] + gs[d]) + b2  (fp32).
// CSR via 2-level radix sort (bucket = dst>>8); edge lists sentinel-padded to
// a multiple of 4 (sentinel row N is all-zeros) so agg loops are branch-free.
// Edge->lane-group assignment in agg kernels via ds_bpermute (__shfl).

#define IN_F  128
#define HID_F 256
#define OUT_F 64
#define BK_SHIFT 8
#define BK_SIZE  256
#define CHUNK    8192

typedef unsigned int uint;
typedef unsigned short ushort;
typedef short bf16x8 __attribute__((ext_vector_type(8)));
typedef float f32x4 __attribute__((ext_vector_type(4)));

__device__ __forceinline__ ushort f2bf(float f) {
    uint u = __float_as_uint(f);
    uint r = (u + 0x7fffu + ((u >> 16) & 1u)) >> 16;  // RNE
    return (ushort)r;
}
__device__ __forceinline__ float bf_lo(uint u) { return __uint_as_float(u << 16); }
__device__ __forceinline__ float bf_hi(uint u) { return __uint_as_float(u & 0xffff0000u); }

// --- sort pipeline -----------------------------------------------------------

__global__ void bucket_hist_kernel(const int* __restrict__ dst, int* __restrict__ bhist,
                                   int E, int NB) {
    __shared__ int h[512];
    for (int i = threadIdx.x; i < NB; i += 256) h[i] = 0;
    __syncthreads();
    int base = blockIdx.x * CHUNK;
    int end = min(base + CHUNK, E);
    for (int i = base + threadIdx.x; i < end; i += 256)
        atomicAdd(&h[dst[i] >> BK_SHIFT], 1);
    __syncthreads();
    for (int i = threadIdx.x; i < NB; i += 256)
        if (h[i]) atomicAdd(&bhist[i], h[i]);
}

__global__ void bucket_scan_kernel(const int* __restrict__ bhist, int* __restrict__ bbase,
                                   int* __restrict__ bcursor, int NB, int E) {
    __shared__ int sh[512];
    int t = threadIdx.x;
    int v = (t < NB) ? bhist[t] : 0;
    sh[t] = v;
    __syncthreads();
    for (int off = 1; off < 512; off <<= 1) {
        int u = (t >= off) ? sh[t - off] : 0;
        __syncthreads();
        sh[t] += u;
        __syncthreads();
    }
    if (t < NB) { int b = sh[t] - v; bbase[t] = b; bcursor[t] = b; }
    if (t == 0) bbase[NB] = E;
}

__global__ void bucket_scatter_kernel(const int* __restrict__ src, const int* __restrict__ dst,
                                      int* __restrict__ bcursor, uint* __restrict__ ebuf,
                                      int E, int NB) {
    __shared__ int h[512];
    __shared__ int cur[512];
    for (int i = threadIdx.x; i < NB; i += 256) h[i] = 0;
    __syncthreads();
    int base = blockIdx.x * CHUNK;
    int end = min(base + CHUNK, E);
    for (int i = base + threadIdx.x; i < end; i += 256)
        atomicAdd(&h[dst[i] >> BK_SHIFT], 1);
    __syncthreads();
    for (int i = threadIdx.x; i < NB; i += 256)
        cur[i] = h[i] ? atomicAdd(&bcursor[i], h[i]) : 0;
    __syncthreads();
    for (int i = base + threadIdx.x; i < end; i += 256) {
        int d = dst[i], s = src[i];
        int b = d >> BK_SHIFT;
        int pos = atomicAdd(&cur[b], 1);
        ebuf[pos] = (uint)s | ((uint)(d & (BK_SIZE - 1)) << 24);
    }
}

// One block per bucket.  Pads each node's edge list to a multiple of 4 with
// sentinel src = N (zero feature row); padded bucket region base = bbase[b]+768*b.
__global__ void bucket_build_kernel(const uint* __restrict__ ebuf, const int* __restrict__ bbase,
                                    int* __restrict__ deg_e, int* __restrict__ offsets,
                                    float* __restrict__ dis, int* __restrict__ ssrc, int N) {
    __shared__ int cnt[256], off[256], cur[256];
    int b = blockIdx.x;
    int t = threadIdx.x;
    cnt[t] = 0;
    __syncthreads();
    int e0 = bbase[b], e1 = bbase[b + 1];
    for (int i = e0 + t; i < e1; i += 256)
        atomicAdd(&cnt[ebuf[i] >> 24], 1);
    __syncthreads();
    int v = cnt[t];
    int vpad = (v + 3) & ~3;
    off[t] = vpad;
    __syncthreads();
    for (int o = 1; o < 256; o <<= 1) {
        int u = (t >= o) ? off[t - o] : 0;
        __syncthreads();
        off[t] += u;
        __syncthreads();
    }
    int excl = off[t] - vpad;
    int base_pad = e0 + b * 768;
    int d = b * BK_SIZE + t;
    if (d < N) {
        deg_e[d] = vpad;
        offsets[d] = base_pad + excl;
        dis[d] = rsqrtf((float)(v + 1));
    }
    cur[t] = excl;
    __syncthreads();
    for (int i = e0 + t; i < e1; i += 256) {
        uint e = ebuf[i];
        int ld = e >> 24;
        int pos = atomicAdd(&cur[ld], 1);
        ssrc[base_pad + pos] = (int)(e & 0xFFFFFFu);
    }
    __syncthreads();
    for (int i = v; i < vpad; i++)
        ssrc[base_pad + excl + i] = N;
}

// --- prep: weight repack + bf16 x (fused) ------------------------------------
// W B-fragment layout: Wp[((kc*NCOL + c)*32) + kk] = bf16(W[(kc*32+kk)*NCOL + c]).
// xs has N+1 rows; row N zeros (sentinel).
__global__ void prep_kernel(const float* __restrict__ x, const float* __restrict__ dis,
                            uint* __restrict__ xs, const float* __restrict__ W1,
                            const float* __restrict__ W2, ushort* __restrict__ W1bp,
                            ushort* __restrict__ W2bp, int N) {
    int b = blockIdx.x;
    if (b < 192) {
        int i = b * 256 + threadIdx.x;  // 32768 + 16384 = 49152
        if (i < 32768) {
            int kk = i & 31, c = (i >> 5) & 255, kc = i >> 13;
            W1bp[i] = f2bf(W1[(size_t)(kc * 32 + kk) * HID_F + c]);
        } else {
            int j = i - 32768;
            int kk = j & 31, c = (j >> 5) & 63, kc = j >> 11;
            W2bp[j] = f2bf(W2[(size_t)(kc * 32 + kk) * OUT_F + c]);
        }
        return;
    }
    int i = (b - 192) * 256 + threadIdx.x;
    if (i < (N + 1) * (IN_F / 2)) {
        int n = i >> 6;
        if (n >= N) { xs[i] = 0u; return; }
        float dn = dis[n];
        float2 v = ((const float2*)x)[i];
        xs[i] = (uint)f2bf(dn * v.x) | ((uint)f2bf(dn * v.y) << 16);
    }
}

// --- compute pipeline --------------------------------------------------------

// zb[d] = bf16(dis[d]*(sum_e xs[s] + xs[d])).  One wave per node; 4 edges/round,
// 16-lane groups, uint4 per lane.  Edge index selected via __shfl (ds_bpermute).
__global__ void aggx_kernel(const uint* __restrict__ xs, const int* __restrict__ ssrc,
                            const int* __restrict__ offsets, const int* __restrict__ deg_e,
                            const float* __restrict__ dis, uint* __restrict__ zb, int N) {
    int lane = threadIdx.x & 63;
    int n = blockIdx.x * 4 + (threadIdx.x >> 6);
    if (n >= N) return;
    int grp = lane >> 4;
    int ck = lane & 15;
    float acc[8];
#pragma unroll
    for (int i = 0; i < 8; i++) acc[i] = 0.f;
    int start = offsets[n], cnt = deg_e[n];  // cnt % 4 == 0
    for (int base = 0; base < cnt; base += 64) {
        int m = min(64, cnt - base);
        int idx = base + lane;
        int sv = ssrc[start + (idx < cnt ? idx : cnt - 1)];
        int rounds = m >> 2;
#pragma unroll 2
        for (int q = 0; q < rounds; q++) {
            int s = __shfl(sv, (q << 2) | grp);
            uint4 u = *(const uint4*)(xs + ((size_t)s << 6) + (ck << 2));
            acc[0] += bf_lo(u.x); acc[1] += bf_hi(u.x);
            acc[2] += bf_lo(u.y); acc[3] += bf_hi(u.y);
            acc[4] += bf_lo(u.z); acc[5] += bf_hi(u.z);
            acc[6] += bf_lo(u.w); acc[7] += bf_hi(u.w);
        }
    }
#pragma unroll
    for (int i = 0; i < 8; i++) acc[i] += __shfl_down(acc[i], 32);
#pragma unroll
    for (int i = 0; i < 8; i++) acc[i] += __shfl_down(acc[i], 16);
    if (grp == 0) {
        uint4 u = *(const uint4*)(xs + ((size_t)n << 6) + (ck << 2));  // self
        acc[0] += bf_lo(u.x); acc[1] += bf_hi(u.x);
        acc[2] += bf_lo(u.y); acc[3] += bf_hi(u.y);
        acc[4] += bf_lo(u.z); acc[5] += bf_hi(u.z);
        acc[6] += bf_lo(u.w); acc[7] += bf_hi(u.w);
        float dn = dis[n];
        uint4 o;
        o.x = (uint)f2bf(dn * acc[0]) | ((uint)f2bf(dn * acc[1]) << 16);
        o.y = (uint)f2bf(dn * acc[2]) | ((uint)f2bf(dn * acc[3]) << 16);
        o.z = (uint)f2bf(dn * acc[4]) | ((uint)f2bf(dn * acc[5]) << 16);
        o.w = (uint)f2bf(dn * acc[6]) | ((uint)f2bf(dn * acc[7]) << 16);
        *(uint4*)(zb + ((size_t)n << 6) + (ck << 2)) = o;
    }
}

// out1b = bf16(zb @ W1 + b1), with per-column BN sum/sumsq accumulated from
// registers (cross-quad shfl reduce + 2 atomics per column per block).
__global__ __launch_bounds__(256) void gemm1_kernel(const uint* __restrict__ zb,
                                                    const uint* __restrict__ W1bp,
                                                    const float* __restrict__ b1,
                                                    ushort* __restrict__ out1b,
                                                    float* __restrict__ bnsum, int N) {
    __shared__ uint A[64][68];
    int t = threadIdx.x;
    int n0 = blockIdx.x * 64;
    for (int i = t; i < 64 * 16; i += 256) {
        int r = i >> 4, q = i & 15;
        int node = n0 + r;
        uint4 v = make_uint4(0u, 0u, 0u, 0u);
        if (node < N) v = *(const uint4*)(zb + (size_t)node * 64 + q * 4);
        *(uint4*)(&A[r][q * 4]) = v;
    }
    __syncthreads();
    int wave = t >> 6, lane = t & 63;
    int quad = lane >> 4, lrow = lane & 15;
    f32x4 acc[4][4];
#pragma unroll
    for (int m = 0; m < 4; m++)
#pragma unroll
        for (int nt = 0; nt < 4; nt++) acc[m][nt] = (f32x4)(0.f);
#pragma unroll
    for (int kc = 0; kc < 4; kc++) {
        bf16x8 bfr[4];
#pragma unroll
        for (int nt = 0; nt < 4; nt++) {
            int c = wave * 64 + nt * 16 + lrow;
            bfr[nt] = *(const bf16x8*)(W1bp + ((size_t)(kc * 256 + c) * 16 + quad * 4));
        }
        bf16x8 afr[4];
#pragma unroll
        for (int m = 0; m < 4; m++)
            afr[m] = *(const bf16x8*)(&A[m * 16 + lrow][kc * 16 + quad * 4]);
#pragma unroll
        for (int m = 0; m < 4; m++)
#pragma unroll
            for (int nt = 0; nt < 4; nt++)
                acc[m][nt] = __builtin_amdgcn_mfma_f32_16x16x32_bf16(
                    afr[m], bfr[nt], acc[m][nt], 0, 0, 0);
    }
#pragma unroll
    for (int nt = 0; nt < 4; nt++) {
        int c = wave * 64 + nt * 16 + lrow;
        float bb = b1[c];
        float s = 0.f, q = 0.f;
#pragma unroll
        for (int m = 0; m < 4; m++) {
#pragma unroll
            for (int r = 0; r < 4; r++) {
                int node = n0 + m * 16 + quad * 4 + r;
                if (node < N) {
                    float v = acc[m][nt][r] + bb;
                    out1b[(size_t)node * HID_F + c] = f2bf(v);
                    s += v;
                    q = fmaf(v, v, q);
                }
            }
        }
        s += __shfl_down(s, 32); q += __shfl_down(q, 32);
        s += __shfl_down(s, 16); q += __shfl_down(q, 16);
        if (quad == 0) {
            atomicAdd(&bnsum[c], s);
            atomicAdd(&bnsum[256 + c], q);
        }
    }
}

// gs = bf16(dis * (relu(bn(out1b)) @ W2)).  BN scale/bias computed in-block.
// gs has N+1 rows; row N zeroed by block 0 (sentinel for agg2).
__global__ __launch_bounds__(256) void gemm2_kernel(const ushort* __restrict__ out1b,
                                                    const uint* __restrict__ W2bp,
                                                    const float* __restrict__ dis,
                                                    const float* __restrict__ bnsums,
                                                    const float* __restrict__ gamma,
                                                    const float* __restrict__ beta,
                                                    ushort* __restrict__ gs, int N) {
    __shared__ uint A[64][132];
    __shared__ float bns[256], bnb[256];
    const uint* out1u = (const uint*)out1b;
    int t = threadIdx.x;
    int n0 = blockIdx.x * 64;
    if (blockIdx.x == 0 && t < 32) ((uint*)gs)[(size_t)N * 32 + t] = 0u;  // sentinel row
    {
        float invN = 1.0f / (float)N;
        float mean = bnsums[t] * invN;
        float var = bnsums[256 + t] * invN - mean * mean;
        float sc = gamma[t] * rsqrtf(fmaxf(var, 0.f) + 1e-5f);
        bns[t] = sc;
        bnb[t] = beta[t] - mean * sc;
    }
    __syncthreads();
    for (int i = t; i < 64 * 64; i += 256) {
        int r = i >> 6, u2 = i & 63;
        int node = n0 + r;
        uint2 p = make_uint2(0u, 0u);
        if (node < N) {
            uint2 v = *(const uint2*)(out1u + (size_t)node * 128 + u2 * 2);
            float r0 = fmaxf(fmaf(bf_lo(v.x), bns[u2 * 4 + 0], bnb[u2 * 4 + 0]), 0.f);
            float r1 = fmaxf(fmaf(bf_hi(v.x), bns[u2 * 4 + 1], bnb[u2 * 4 + 1]), 0.f);
            float r2 = fmaxf(fmaf(bf_lo(v.y), bns[u2 * 4 + 2], bnb[u2 * 4 + 2]), 0.f);
            float r3 = fmaxf(fmaf(bf_hi(v.y), bns[u2 * 4 + 3], bnb[u2 * 4 + 3]), 0.f);
            p.x = (uint)f2bf(r0) | ((uint)f2bf(r1) << 16);
            p.y = (uint)f2bf(r2) | ((uint)f2bf(r3) << 16);
        }
        *(uint2*)(&A[r][u2 * 2]) = p;
    }
    __syncthreads();
    int wave = t >> 6, lane = t & 63;
    int quad = lane >> 4, lrow = lane & 15;
    int c = wave * 16 + lrow;
    f32x4 acc[4];
#pragma unroll
    for (int m = 0; m < 4; m++) acc[m] = (f32x4)(0.f);
#pragma unroll
    for (int kc = 0; kc < 8; kc++) {
        bf16x8 bfr = *(const bf16x8*)(W2bp + ((size_t)(kc * 64 + c) * 16 + quad * 4));
#pragma unroll
        for (int m = 0; m < 4; m++) {
            bf16x8 afr = *(const bf16x8*)(&A[m * 16 + lrow][kc * 16 + quad * 4]);
            acc[m] = __builtin_amdgcn_mfma_f32_16x16x32_bf16(afr, bfr, acc[m], 0, 0, 0);
        }
    }
#pragma unroll
    for (int m = 0; m < 4; m++) {
#pragma unroll
        for (int r = 0; r < 4; r++) {
            int node = n0 + m * 16 + quad * 4 + r;
            if (node < N) gs[(size_t)node * OUT_F + c] = f2bf(dis[node] * acc[m][r]);
        }
    }
}

// out[d] = dis[d]*(sum_e gs[s] + gs[d]) + b2.  One wave per node; 8 edges/round,
// 8-lane groups, uint4 per lane; trailing quad sentinel-guarded.
__global__ void agg2_kernel(const uint* __restrict__ gs, const int* __restrict__ ssrc,
                            const int* __restrict__ offsets, const int* __restrict__ deg_e,
                            const float* __restrict__ dis, const float* __restrict__ b2,
                            float* __restrict__ out, int N) {
    int lane = threadIdx.x & 63;
    int n = blockIdx.x * 4 + (threadIdx.x >> 6);
    if (n >= N) return;
    int grp = lane >> 3;
    int ck = lane & 7;
    float acc[8];
#pragma unroll
    for (int i = 0; i < 8; i++) acc[i] = 0.f;
    int start = offsets[n], cnt = deg_e[n];  // cnt % 4 == 0
    for (int base = 0; base < cnt; base += 64) {
        int m = min(64, cnt - base);
        int idx = base + lane;
        int sv = ssrc[start + (idx < cnt ? idx : cnt - 1)];
        int rounds = m >> 3;
#pragma unroll 2
        for (int q = 0; q < rounds; q++) {
            int s = __shfl(sv, (q << 3) | grp);
            uint4 u = *(const uint4*)(gs + ((size_t)s << 5) + (ck << 2));
            acc[0] += bf_lo(u.x); acc[1] += bf_hi(u.x);
            acc[2] += bf_lo(u.y); acc[3] += bf_hi(u.y);
            acc[4] += bf_lo(u.z); acc[5] += bf_hi(u.z);
            acc[6] += bf_lo(u.w); acc[7] += bf_hi(u.w);
        }
        if (m & 4) {  // trailing quad: groups 0..3 one edge each, 4..7 sentinel
            int s = __shfl(sv, (rounds << 3) | (grp & 3));
            s = (grp & 4) ? N : s;
            uint4 u = *(const uint4*)(gs + ((size_t)s << 5) + (ck << 2));
            acc[0] += bf_lo(u.x); acc[1] += bf_hi(u.x);
            acc[2] += bf_lo(u.y); acc[3] += bf_hi(u.y);
            acc[4] += bf_lo(u.z); acc[5] += bf_hi(u.z);
            acc[6] += bf_lo(u.w); acc[7] += bf_hi(u.w);
        }
    }
#pragma unroll
    for (int i = 0; i < 8; i++) acc[i] += __shfl_down(acc[i], 32);
#pragma unroll
    for (int i = 0; i < 8; i++) acc[i] += __shfl_down(acc[i], 16);
#pragma unroll
    for (int i = 0; i < 8; i++) acc[i] += __shfl_down(acc[i], 8);
    if (grp == 0) {
        uint4 u = *(const uint4*)(gs + ((size_t)n << 5) + (ck << 2));  // self
        acc[0] += bf_lo(u.x); acc[1] += bf_hi(u.x);
        acc[2] += bf_lo(u.y); acc[3] += bf_hi(u.y);
        acc[4] += bf_lo(u.z); acc[5] += bf_hi(u.z);
        acc[6] += bf_lo(u.w); acc[7] += bf_hi(u.w);
        float dn = dis[n];
        float4 bb0 = *(const float4*)(b2 + ck * 8);
        float4 bb1 = *(const float4*)(b2 + ck * 8 + 4);
        float* op = out + (size_t)n * OUT_F + ck * 8;
        *(float4*)op = make_float4(fmaf(dn, acc[0], bb0.x), fmaf(dn, acc[1], bb0.y),
                                   fmaf(dn, acc[2], bb0.z), fmaf(dn, acc[3], bb0.w));
        *(float4*)(op + 4) = make_float4(fmaf(dn, acc[4], bb1.x), fmaf(dn, acc[5], bb1.y),
                                         fmaf(dn, acc[6], bb1.z), fmaf(dn, acc[7], bb1.w));
    }
}

extern "C" void kernel_launch(void* const* d_in, const int* in_sizes, int n_in,
                              void* d_out, int out_size, void* d_ws, size_t ws_size,
                              hipStream_t stream) {
    const float* x      = (const float*)d_in[0];
    const int*   edges  = (const int*)d_in[1];
    const float* W1     = (const float*)d_in[2];
    const float* b1     = (const float*)d_in[3];
    const float* gamma1 = (const float*)d_in[4];
    const float* beta1  = (const float*)d_in[5];
    const float* W2     = (const float*)d_in[6];
    const float* b2     = (const float*)d_in[7];
    float* out = (float*)d_out;

    int N = in_sizes[0] / IN_F;
    int E = in_sizes[1] / 2;
    const int* src = edges;
    const int* dst = edges + E;
    int NB = (N + BK_SIZE - 1) / BK_SIZE;
    int nchunks = (E + CHUNK - 1) / CHUNK;

    char* ws = (char*)d_ws;
    size_t off = 0;
    auto alloc = [&](size_t bytes) -> void* {
        void* p = ws + off;
        off += (bytes + 255) & ~(size_t)255;
        return p;
    };
    int*    deg_e   = (int*)alloc((size_t)N * 4);
    int*    offsets = (int*)alloc((size_t)N * 4);
    float*  dis     = (float*)alloc((size_t)(N + 1) * 4);
    int*    bhist   = (int*)alloc(512 * 4);
    int*    bbase   = (int*)alloc(513 * 4);
    int*    bcursor = (int*)alloc(512 * 4);
    int*    ssrc    = (int*)alloc(((size_t)E + 768 * 512 + 64) * 4);  // padded CSR
    uint*   ebuf    = (uint*)alloc((size_t)E * 4);
    uint*   xs      = (uint*)alloc((size_t)(N + 1) * (IN_F / 2) * 4); // +sentinel row
    uint*   zb      = (uint*)alloc((size_t)N * (IN_F / 2) * 4);
    ushort* out1b   = (ushort*)alloc((size_t)N * HID_F * 2);
    float*  bn      = (float*)alloc(2 * 256 * 4);                     // sums | sumsq
    ushort* W1bp    = (ushort*)alloc(4 * 256 * 32 * 2);
    ushort* W2bp    = (ushort*)alloc(8 * 64 * 32 * 2);
    ushort* gs      = (ushort*)zb;  // alias: zb dead after gemm1; (N+1) rows x 64 bf16

    hipMemsetAsync(bhist, 0, 512 * 4, stream);
    hipMemsetAsync(bn, 0, 2 * 256 * 4, stream);

    bucket_hist_kernel<<<nchunks, 256, 0, stream>>>(dst, bhist, E, NB);
    bucket_scan_kernel<<<1, 512, 0, stream>>>(bhist, bbase, bcursor, NB, E);
    bucket_scatter_kernel<<<nchunks, 256, 0, stream>>>(src, dst, bcursor, ebuf, E, NB);
    bucket_build_kernel<<<NB, 256, 0, stream>>>(ebuf, bbase, deg_e, offsets, dis, ssrc, N);

    int xblocks = ((N + 1) * (IN_F / 2) + 255) / 256;
    prep_kernel<<<192 + xblocks, 256, 0, stream>>>(x, dis, xs, W1, W2, W1bp, W2bp, N);
    aggx_kernel<<<(N + 3) / 4, 256, 0, stream>>>(xs, ssrc, offsets, deg_e, dis, zb, N);
    gemm1_kernel<<<(N + 63) / 64, 256, 0, stream>>>(zb, (const uint*)W1bp, b1, out1b, bn, N);
    gemm2_kernel<<<(N + 63) / 64, 256, 0, stream>>>(out1b, (const uint*)W2bp, dis, bn,
                                                    gamma1, beta1, gs, N);
    agg2_kernel<<<(N + 3) / 4, 256, 0, stream>>>((const uint*)gs, ssrc, offsets, deg_e, dis,
                                                 b2, out, N);
}

// Round 9
// 360.046 us; speedup vs baseline: 3.3854x; 1.0559x over previous
//
#include <hip/hip_runtime.h>
#include <hip/hip_bf16.h>

// GraphSAINT 2-layer GCN forward on MI355X.
// Layer 1: xs[n] = bf16(dis[n]*x[n]);  zb[d] = bf16(dis[d]*(sum_e xs[s] + xs[d]));
//          out1b = bf16(zb @ W1 + b1)   (bf16 MFMA; BN partials fused).
// Layer 2: gs[n] = bf16(dis[n]*(relu(bn(out1b[n])) @ W2))  (bf16 MFMA);
//          out[d] = dis[d]*(sum_e gs[s] + gs[d]) + b2  (fp32).
// CSR via 2-level radix sort; sentinel-padded edge lists (row N = zeros).
// GEMMs: XOR-swizzled LDS A-tiles (conflict-free b128) + LDS-staged coalesced
// uint4 C-stores (no partial-line write amplification); BN via block partials
// + 2-stage tree reduce (no contended atomics).

#define IN_F  128
#define HID_F 256
#define OUT_F 64
#define BK_SHIFT 8
#define BK_SIZE  256
#define CHUNK    8192

typedef unsigned int uint;
typedef unsigned short ushort;
typedef short bf16x8 __attribute__((ext_vector_type(8)));
typedef float f32x4 __attribute__((ext_vector_type(4)));

__device__ __forceinline__ ushort f2bf(float f) {
    uint u = __float_as_uint(f);
    uint r = (u + 0x7fffu + ((u >> 16) & 1u)) >> 16;  // RNE
    return (ushort)r;
}
__device__ __forceinline__ float bf_lo(uint u) { return __uint_as_float(u << 16); }
__device__ __forceinline__ float bf_hi(uint u) { return __uint_as_float(u & 0xffff0000u); }

// --- sort pipeline -----------------------------------------------------------

__global__ void bucket_hist_kernel(const int* __restrict__ dst, int* __restrict__ bhist,
                                   int E, int NB) {
    __shared__ int h[512];
    for (int i = threadIdx.x; i < NB; i += 256) h[i] = 0;
    __syncthreads();
    int base = blockIdx.x * CHUNK;
    int end = min(base + CHUNK, E);
    for (int i = base + threadIdx.x; i < end; i += 256)
        atomicAdd(&h[dst[i] >> BK_SHIFT], 1);
    __syncthreads();
    for (int i = threadIdx.x; i < NB; i += 256)
        if (h[i]) atomicAdd(&bhist[i], h[i]);
}

__global__ void bucket_scan_kernel(const int* __restrict__ bhist, int* __restrict__ bbase,
                                   int* __restrict__ bcursor, int NB, int E) {
    __shared__ int sh[512];
    int t = threadIdx.x;
    int v = (t < NB) ? bhist[t] : 0;
    sh[t] = v;
    __syncthreads();
    for (int off = 1; off < 512; off <<= 1) {
        int u = (t >= off) ? sh[t - off] : 0;
        __syncthreads();
        sh[t] += u;
        __syncthreads();
    }
    if (t < NB) { int b = sh[t] - v; bbase[t] = b; bcursor[t] = b; }
    if (t == 0) bbase[NB] = E;
}

__global__ void bucket_scatter_kernel(const int* __restrict__ src, const int* __restrict__ dst,
                                      int* __restrict__ bcursor, uint* __restrict__ ebuf,
                                      int E, int NB) {
    __shared__ int h[512];
    __shared__ int cur[512];
    for (int i = threadIdx.x; i < NB; i += 256) h[i] = 0;
    __syncthreads();
    int base = blockIdx.x * CHUNK;
    int end = min(base + CHUNK, E);
    for (int i = base + threadIdx.x; i < end; i += 256)
        atomicAdd(&h[dst[i] >> BK_SHIFT], 1);
    __syncthreads();
    for (int i = threadIdx.x; i < NB; i += 256)
        cur[i] = h[i] ? atomicAdd(&bcursor[i], h[i]) : 0;
    __syncthreads();
    for (int i = base + threadIdx.x; i < end; i += 256) {
        int d = dst[i], s = src[i];
        int b = d >> BK_SHIFT;
        int pos = atomicAdd(&cur[b], 1);
        ebuf[pos] = (uint)s | ((uint)(d & (BK_SIZE - 1)) << 24);
    }
}

__global__ void bucket_build_kernel(const uint* __restrict__ ebuf, const int* __restrict__ bbase,
                                    int* __restrict__ deg_e, int* __restrict__ offsets,
                                    float* __restrict__ dis, int* __restrict__ ssrc, int N) {
    __shared__ int cnt[256], off[256], cur[256];
    int b = blockIdx.x;
    int t = threadIdx.x;
    cnt[t] = 0;
    __syncthreads();
    int e0 = bbase[b], e1 = bbase[b + 1];
    for (int i = e0 + t; i < e1; i += 256)
        atomicAdd(&cnt[ebuf[i] >> 24], 1);
    __syncthreads();
    int v = cnt[t];
    int vpad = (v + 3) & ~3;
    off[t] = vpad;
    __syncthreads();
    for (int o = 1; o < 256; o <<= 1) {
        int u = (t >= o) ? off[t - o] : 0;
        __syncthreads();
        off[t] += u;
        __syncthreads();
    }
    int excl = off[t] - vpad;
    int base_pad = e0 + b * 768;
    int d = b * BK_SIZE + t;
    if (d < N) {
        deg_e[d] = vpad;
        offsets[d] = base_pad + excl;
        dis[d] = rsqrtf((float)(v + 1));
    }
    cur[t] = excl;
    __syncthreads();
    for (int i = e0 + t; i < e1; i += 256) {
        uint e = ebuf[i];
        int ld = e >> 24;
        int pos = atomicAdd(&cur[ld], 1);
        ssrc[base_pad + pos] = (int)(e & 0xFFFFFFu);
    }
    __syncthreads();
    for (int i = v; i < vpad; i++)
        ssrc[base_pad + excl + i] = N;
}

// --- prep: weight repack + bf16 x (fused) ------------------------------------
__global__ void prep_kernel(const float* __restrict__ x, const float* __restrict__ dis,
                            uint* __restrict__ xs, const float* __restrict__ W1,
                            const float* __restrict__ W2, ushort* __restrict__ W1bp,
                            ushort* __restrict__ W2bp, int N) {
    int b = blockIdx.x;
    if (b < 192) {
        int i = b * 256 + threadIdx.x;
        if (i < 32768) {
            int kk = i & 31, c = (i >> 5) & 255, kc = i >> 13;
            W1bp[i] = f2bf(W1[(size_t)(kc * 32 + kk) * HID_F + c]);
        } else {
            int j = i - 32768;
            int kk = j & 31, c = (j >> 5) & 63, kc = j >> 11;
            W2bp[j] = f2bf(W2[(size_t)(kc * 32 + kk) * OUT_F + c]);
        }
        return;
    }
    int i = (b - 192) * 256 + threadIdx.x;
    if (i < (N + 1) * (IN_F / 2)) {
        int n = i >> 6;
        if (n >= N) { xs[i] = 0u; return; }
        float dn = dis[n];
        float2 v = ((const float2*)x)[i];
        xs[i] = (uint)f2bf(dn * v.x) | ((uint)f2bf(dn * v.y) << 16);
    }
}

// --- compute pipeline --------------------------------------------------------

// zb[d] = bf16(dis[d]*(sum_e xs[s] + xs[d])).
__global__ void aggx_kernel(const uint* __restrict__ xs, const int* __restrict__ ssrc,
                            const int* __restrict__ offsets, const int* __restrict__ deg_e,
                            const float* __restrict__ dis, uint* __restrict__ zb, int N) {
    int lane = threadIdx.x & 63;
    int n = blockIdx.x * 4 + (threadIdx.x >> 6);
    if (n >= N) return;
    int grp = lane >> 4;
    int ck = lane & 15;
    float acc[8];
#pragma unroll
    for (int i = 0; i < 8; i++) acc[i] = 0.f;
    int start = offsets[n], cnt = deg_e[n];  // cnt % 4 == 0
    for (int base = 0; base < cnt; base += 64) {
        int m = min(64, cnt - base);
        int idx = base + lane;
        int sv = ssrc[start + (idx < cnt ? idx : cnt - 1)];
        int rounds = m >> 2;
#pragma unroll 2
        for (int q = 0; q < rounds; q++) {
            int s = __shfl(sv, (q << 2) | grp);
            uint4 u = *(const uint4*)(xs + ((size_t)s << 6) + (ck << 2));
            acc[0] += bf_lo(u.x); acc[1] += bf_hi(u.x);
            acc[2] += bf_lo(u.y); acc[3] += bf_hi(u.y);
            acc[4] += bf_lo(u.z); acc[5] += bf_hi(u.z);
            acc[6] += bf_lo(u.w); acc[7] += bf_hi(u.w);
        }
    }
#pragma unroll
    for (int i = 0; i < 8; i++) acc[i] += __shfl_down(acc[i], 32);
#pragma unroll
    for (int i = 0; i < 8; i++) acc[i] += __shfl_down(acc[i], 16);
    if (grp == 0) {
        uint4 u = *(const uint4*)(xs + ((size_t)n << 6) + (ck << 2));  // self
        acc[0] += bf_lo(u.x); acc[1] += bf_hi(u.x);
        acc[2] += bf_lo(u.y); acc[3] += bf_hi(u.y);
        acc[4] += bf_lo(u.z); acc[5] += bf_hi(u.z);
        acc[6] += bf_lo(u.w); acc[7] += bf_hi(u.w);
        float dn = dis[n];
        uint4 o;
        o.x = (uint)f2bf(dn * acc[0]) | ((uint)f2bf(dn * acc[1]) << 16);
        o.y = (uint)f2bf(dn * acc[2]) | ((uint)f2bf(dn * acc[3]) << 16);
        o.z = (uint)f2bf(dn * acc[4]) | ((uint)f2bf(dn * acc[5]) << 16);
        o.w = (uint)f2bf(dn * acc[6]) | ((uint)f2bf(dn * acc[7]) << 16);
        *(uint4*)(zb + ((size_t)n << 6) + (ck << 2)) = o;
    }
}

// out1b = bf16(zb @ W1 + b1) + per-block BN partials (no atomics).
// A-tile XOR-swizzled; C staged in LDS and stored as coalesced uint4.
__global__ __launch_bounds__(256) void gemm1_kernel(const uint* __restrict__ zb,
                                                    const uint* __restrict__ W1bp,
                                                    const float* __restrict__ b1,
                                                    ushort* __restrict__ out1b,
                                                    float* __restrict__ bnp, int N) {
    __shared__ uint sbuf[8192];  // A tile (16 KB) then C staging (32 KB)
    int t = threadIdx.x;
    int n0 = blockIdx.x * 64;
    for (int i = t; i < 64 * 16; i += 256) {
        int r = i >> 4, q = i & 15;
        int node = n0 + r;
        uint4 v = make_uint4(0u, 0u, 0u, 0u);
        if (node < N) v = *(const uint4*)(zb + (size_t)node * 64 + q * 4);
        int p = q ^ (r & 15);  // XOR swizzle: conflict-free b128
        *(uint4*)(&sbuf[r * 64 + p * 4]) = v;
    }
    __syncthreads();
    int wave = t >> 6, lane = t & 63;
    int quad = lane >> 4, lrow = lane & 15;
    f32x4 acc[4][4];
#pragma unroll
    for (int m = 0; m < 4; m++)
#pragma unroll
        for (int nt = 0; nt < 4; nt++) acc[m][nt] = (f32x4)(0.f);
#pragma unroll
    for (int kc = 0; kc < 4; kc++) {
        bf16x8 bfr[4];
#pragma unroll
        for (int nt = 0; nt < 4; nt++) {
            int c = wave * 64 + nt * 16 + lrow;
            bfr[nt] = *(const bf16x8*)(W1bp + ((size_t)(kc * 256 + c) * 16 + quad * 4));
        }
        bf16x8 afr[4];
#pragma unroll
        for (int m = 0; m < 4; m++) {
            int p = (kc * 4 + quad) ^ lrow;
            afr[m] = *(const bf16x8*)(&sbuf[(m * 16 + lrow) * 64 + p * 4]);
        }
#pragma unroll
        for (int m = 0; m < 4; m++)
#pragma unroll
            for (int nt = 0; nt < 4; nt++)
                acc[m][nt] = __builtin_amdgcn_mfma_f32_16x16x32_bf16(
                    afr[m], bfr[nt], acc[m][nt], 0, 0, 0);
    }
    __syncthreads();  // A reads done; reuse sbuf for C staging
#pragma unroll
    for (int nt = 0; nt < 4; nt++) {
        int c = wave * 64 + nt * 16 + lrow;
        float bb = b1[c];
        float s = 0.f, q = 0.f;
#pragma unroll
        for (int m = 0; m < 4; m++) {
#pragma unroll
            for (int r = 0; r < 4; r++) {
                int row = m * 16 + quad * 4 + r;
                float v = acc[m][nt][r] + bb;
                if (n0 + row < N) { s += v; q = fmaf(v, v, q); }
                uint hv = (uint)f2bf(v);
                uint pv = __shfl_xor(hv, 1);
                if ((lrow & 1) == 0)
                    sbuf[row * 128 + (c >> 1)] = hv | (pv << 16);
            }
        }
        s += __shfl_down(s, 32); q += __shfl_down(q, 32);
        s += __shfl_down(s, 16); q += __shfl_down(q, 16);
        if (quad == 0) {
            bnp[(size_t)blockIdx.x * 512 + c] = s;
            bnp[(size_t)blockIdx.x * 512 + 256 + c] = q;
        }
    }
    __syncthreads();
    uint* out1g = (uint*)out1b;
    for (int i = t; i < 2048; i += 256) {  // 64 rows x 32 uint4
        int row = i >> 5;
        if (n0 + row < N)
            *(uint4*)(out1g + (size_t)(n0 + row) * 128 + (i & 31) * 4) =
                *(const uint4*)(&sbuf[i * 4]);
    }
}

// Stage 1: 32 blocks reduce bnp partials (stride-32) -> bnp2[32][512].
__global__ void bnred1_kernel(const float* __restrict__ bnp, float* __restrict__ bnp2,
                              int nblk) {
    int g = blockIdx.x, t = threadIdx.x;
    float s = 0.f, q = 0.f;
    for (int b = g; b < nblk; b += 32) {
        s += bnp[(size_t)b * 512 + t];
        q += bnp[(size_t)b * 512 + 256 + t];
    }
    bnp2[g * 512 + t] = s;
    bnp2[g * 512 + 256 + t] = q;
}

// Stage 2: final scale/bias.
__global__ void bnred2_kernel(const float* __restrict__ bnp2, const float* __restrict__ gamma,
                              const float* __restrict__ beta, float* __restrict__ bnsb, int N) {
    int t = threadIdx.x;
    float s = 0.f, q = 0.f;
    for (int g = 0; g < 32; g++) {
        s += bnp2[g * 512 + t];
        q += bnp2[g * 512 + 256 + t];
    }
    float invN = 1.0f / (float)N;
    float mean = s * invN;
    float var = q * invN - mean * mean;
    float sc = gamma[t] * rsqrtf(fmaxf(var, 0.f) + 1e-5f);
    bnsb[t] = sc;
    bnsb[256 + t] = beta[t] - mean * sc;
}

// gs = bf16(dis * (relu(bn(out1b)) @ W2)).  Same swizzle + staged stores.
__global__ __launch_bounds__(256) void gemm2_kernel(const ushort* __restrict__ out1b,
                                                    const uint* __restrict__ W2bp,
                                                    const float* __restrict__ dis,
                                                    const float* __restrict__ bnsb,
                                                    ushort* __restrict__ gs, int N) {
    __shared__ uint sbuf[8192];  // A tile (32 KB); first 8 KB reused for gs staging
    __shared__ float bns[256], bnb[256];
    const uint* out1u = (const uint*)out1b;
    int t = threadIdx.x;
    int n0 = blockIdx.x * 64;
    if (blockIdx.x == 0 && t < 32) ((uint*)gs)[(size_t)N * 32 + t] = 0u;  // sentinel row
    bns[t] = bnsb[t];
    bnb[t] = bnsb[256 + t];
    __syncthreads();
    for (int i = t; i < 64 * 32; i += 256) {
        int r = i >> 5, q = i & 31;
        int node = n0 + r;
        uint4 v = make_uint4(0u, 0u, 0u, 0u);
        if (node < N) {
            uint4 w = *(const uint4*)(out1u + (size_t)node * 128 + q * 4);
            int c0 = q * 8;
            float r0 = fmaxf(fmaf(bf_lo(w.x), bns[c0 + 0], bnb[c0 + 0]), 0.f);
            float r1 = fmaxf(fmaf(bf_hi(w.x), bns[c0 + 1], bnb[c0 + 1]), 0.f);
            float r2 = fmaxf(fmaf(bf_lo(w.y), bns[c0 + 2], bnb[c0 + 2]), 0.f);
            float r3 = fmaxf(fmaf(bf_hi(w.y), bns[c0 + 3], bnb[c0 + 3]), 0.f);
            float r4 = fmaxf(fmaf(bf_lo(w.z), bns[c0 + 4], bnb[c0 + 4]), 0.f);
            float r5 = fmaxf(fmaf(bf_hi(w.z), bns[c0 + 5], bnb[c0 + 5]), 0.f);
            float r6 = fmaxf(fmaf(bf_lo(w.w), bns[c0 + 6], bnb[c0 + 6]), 0.f);
            float r7 = fmaxf(fmaf(bf_hi(w.w), bns[c0 + 7], bnb[c0 + 7]), 0.f);
            v.x = (uint)f2bf(r0) | ((uint)f2bf(r1) << 16);
            v.y = (uint)f2bf(r2) | ((uint)f2bf(r3) << 16);
            v.z = (uint)f2bf(r4) | ((uint)f2bf(r5) << 16);
            v.w = (uint)f2bf(r6) | ((uint)f2bf(r7) << 16);
        }
        int p = (q & 16) | ((q & 15) ^ (r & 15));  // XOR swizzle (low 4 bits)
        *(uint4*)(&sbuf[r * 128 + p * 4]) = v;
    }
    __syncthreads();
    int wave = t >> 6, lane = t & 63;
    int quad = lane >> 4, lrow = lane & 15;
    int c = wave * 16 + lrow;
    f32x4 acc[4];
#pragma unroll
    for (int m = 0; m < 4; m++) acc[m] = (f32x4)(0.f);
#pragma unroll
    for (int kc = 0; kc < 8; kc++) {
        bf16x8 bfr = *(const bf16x8*)(W2bp + ((size_t)(kc * 64 + c) * 16 + quad * 4));
#pragma unroll
        for (int m = 0; m < 4; m++) {
            int q = kc * 4 + quad;
            int p = (q & 16) | ((q & 15) ^ lrow);
            bf16x8 afr = *(const bf16x8*)(&sbuf[(m * 16 + lrow) * 128 + p * 4]);
            acc[m] = __builtin_amdgcn_mfma_f32_16x16x32_bf16(afr, bfr, acc[m], 0, 0, 0);
        }
    }
    __syncthreads();  // reuse sbuf[0..2047] for gs staging
#pragma unroll
    for (int m = 0; m < 4; m++) {
#pragma unroll
        for (int r = 0; r < 4; r++) {
            int row = m * 16 + quad * 4 + r;
            int node = n0 + row;
            float dn = (node < N) ? dis[node] : 0.f;
            uint hv = (uint)f2bf(dn * acc[m][r]);
            uint pv = __shfl_xor(hv, 1);
            if ((lrow & 1) == 0)
                sbuf[row * 32 + (c >> 1)] = hv | (pv << 16);
        }
    }
    __syncthreads();
    uint* gsg = (uint*)gs;
    for (int i = t; i < 512; i += 256) {  // 64 rows x 8 uint4
        int row = i >> 3;
        if (n0 + row < N)
            *(uint4*)(gsg + (size_t)(n0 + row) * 32 + (i & 7) * 4) =
                *(const uint4*)(&sbuf[i * 4]);
    }
}

// out[d] = dis[d]*(sum_e gs[s] + gs[d]) + b2.
__global__ void agg2_kernel(const uint* __restrict__ gs, const int* __restrict__ ssrc,
                            const int* __restrict__ offsets, const int* __restrict__ deg_e,
                            const float* __restrict__ dis, const float* __restrict__ b2,
                            float* __restrict__ out, int N) {
    int lane = threadIdx.x & 63;
    int n = blockIdx.x * 4 + (threadIdx.x >> 6);
    if (n >= N) return;
    int grp = lane >> 3;
    int ck = lane & 7;
    float acc[8];
#pragma unroll
    for (int i = 0; i < 8; i++) acc[i] = 0.f;
    int start = offsets[n], cnt = deg_e[n];  // cnt % 4 == 0
    for (int base = 0; base < cnt; base += 64) {
        int m = min(64, cnt - base);
        int idx = base + lane;
        int sv = ssrc[start + (idx < cnt ? idx : cnt - 1)];
        int rounds = m >> 3;
#pragma unroll 2
        for (int q = 0; q < rounds; q++) {
            int s = __shfl(sv, (q << 3) | grp);
            uint4 u = *(const uint4*)(gs + ((size_t)s << 5) + (ck << 2));
            acc[0] += bf_lo(u.x); acc[1] += bf_hi(u.x);
            acc[2] += bf_lo(u.y); acc[3] += bf_hi(u.y);
            acc[4] += bf_lo(u.z); acc[5] += bf_hi(u.z);
            acc[6] += bf_lo(u.w); acc[7] += bf_hi(u.w);
        }
        if (m & 4) {
            int s = __shfl(sv, (rounds << 3) | (grp & 3));
            s = (grp & 4) ? N : s;
            uint4 u = *(const uint4*)(gs + ((size_t)s << 5) + (ck << 2));
            acc[0] += bf_lo(u.x); acc[1] += bf_hi(u.x);
            acc[2] += bf_lo(u.y); acc[3] += bf_hi(u.y);
            acc[4] += bf_lo(u.z); acc[5] += bf_hi(u.z);
            acc[6] += bf_lo(u.w); acc[7] += bf_hi(u.w);
        }
    }
#pragma unroll
    for (int i = 0; i < 8; i++) acc[i] += __shfl_down(acc[i], 32);
#pragma unroll
    for (int i = 0; i < 8; i++) acc[i] += __shfl_down(acc[i], 16);
#pragma unroll
    for (int i = 0; i < 8; i++) acc[i] += __shfl_down(acc[i], 8);
    if (grp == 0) {
        uint4 u = *(const uint4*)(gs + ((size_t)n << 5) + (ck << 2));  // self
        acc[0] += bf_lo(u.x); acc[1] += bf_hi(u.x);
        acc[2] += bf_lo(u.y); acc[3] += bf_hi(u.y);
        acc[4] += bf_lo(u.z); acc[5] += bf_hi(u.z);
        acc[6] += bf_lo(u.w); acc[7] += bf_hi(u.w);
        float dn = dis[n];
        float4 bb0 = *(const float4*)(b2 + ck * 8);
        float4 bb1 = *(const float4*)(b2 + ck * 8 + 4);
        float* op = out + (size_t)n * OUT_F + ck * 8;
        *(float4*)op = make_float4(fmaf(dn, acc[0], bb0.x), fmaf(dn, acc[1], bb0.y),
                                   fmaf(dn, acc[2], bb0.z), fmaf(dn, acc[3], bb0.w));
        *(float4*)(op + 4) = make_float4(fmaf(dn, acc[4], bb1.x), fmaf(dn, acc[5], bb1.y),
                                         fmaf(dn, acc[6], bb1.z), fmaf(dn, acc[7], bb1.w));
    }
}

extern "C" void kernel_launch(void* const* d_in, const int* in_sizes, int n_in,
                              void* d_out, int out_size, void* d_ws, size_t ws_size,
                              hipStream_t stream) {
    const float* x      = (const float*)d_in[0];
    const int*   edges  = (const int*)d_in[1];
    const float* W1     = (const float*)d_in[2];
    const float* b1     = (const float*)d_in[3];
    const float* gamma1 = (const float*)d_in[4];
    const float* beta1  = (const float*)d_in[5];
    const float* W2     = (const float*)d_in[6];
    const float* b2     = (const float*)d_in[7];
    float* out = (float*)d_out;

    int N = in_sizes[0] / IN_F;
    int E = in_sizes[1] / 2;
    const int* src = edges;
    const int* dst = edges + E;
    int NB = (N + BK_SIZE - 1) / BK_SIZE;
    int nchunks = (E + CHUNK - 1) / CHUNK;
    int nblk1 = (N + 63) / 64;

    char* ws = (char*)d_ws;
    size_t off = 0;
    auto alloc = [&](size_t bytes) -> void* {
        void* p = ws + off;
        off += (bytes + 255) & ~(size_t)255;
        return p;
    };
    int*    deg_e   = (int*)alloc((size_t)N * 4);
    int*    offsets = (int*)alloc((size_t)N * 4);
    float*  dis     = (float*)alloc((size_t)(N + 1) * 4);
    int*    bhist   = (int*)alloc(512 * 4);
    int*    bbase   = (int*)alloc(513 * 4);
    int*    bcursor = (int*)alloc(512 * 4);
    int*    ssrc    = (int*)alloc(((size_t)E + 768 * 512 + 64) * 4);  // padded CSR
    uint*   ebuf    = (uint*)alloc((size_t)E * 4);
    uint*   xs      = (uint*)alloc((size_t)(N + 1) * (IN_F / 2) * 4); // +sentinel row
    uint*   zb      = (uint*)alloc((size_t)N * (IN_F / 2) * 4);
    ushort* out1b   = (ushort*)alloc((size_t)N * HID_F * 2);
    float*  bnp     = (float*)alloc((size_t)nblk1 * 512 * 4);         // block partials
    float*  bnp2    = (float*)alloc(32 * 512 * 4);
    float*  bnsb    = (float*)alloc(512 * 4);                         // scale | bias
    ushort* W1bp    = (ushort*)alloc(4 * 256 * 32 * 2);
    ushort* W2bp    = (ushort*)alloc(8 * 64 * 32 * 2);
    ushort* gs      = (ushort*)zb;  // alias: zb dead after gemm1; (N+1) rows x 64 bf16

    hipMemsetAsync(bhist, 0, 512 * 4, stream);

    bucket_hist_kernel<<<nchunks, 256, 0, stream>>>(dst, bhist, E, NB);
    bucket_scan_kernel<<<1, 512, 0, stream>>>(bhist, bbase, bcursor, NB, E);
    bucket_scatter_kernel<<<nchunks, 256, 0, stream>>>(src, dst, bcursor, ebuf, E, NB);
    bucket_build_kernel<<<NB, 256, 0, stream>>>(ebuf, bbase, deg_e, offsets, dis, ssrc, N);

    int xblocks = ((N + 1) * (IN_F / 2) + 255) / 256;
    prep_kernel<<<192 + xblocks, 256, 0, stream>>>(x, dis, xs, W1, W2, W1bp, W2bp, N);
    aggx_kernel<<<(N + 3) / 4, 256, 0, stream>>>(xs, ssrc, offsets, deg_e, dis, zb, N);
    gemm1_kernel<<<nblk1, 256, 0, stream>>>(zb, (const uint*)W1bp, b1, out1b, bnp, N);
    bnred1_kernel<<<32, 256, 0, stream>>>(bnp, bnp2, nblk1);
    bnred2_kernel<<<1, 256, 0, stream>>>(bnp2, gamma1, beta1, bnsb, N);
    gemm2_kernel<<<nblk1, 256, 0, stream>>>(out1b, (const uint*)W2bp, dis, bnsb, gs, N);
    agg2_kernel<<<(N + 3) / 4, 256, 0, stream>>>((const uint*)gs, ssrc, offsets, deg_e, dis,
                                                 b2, out, N);
}

// Round 10
// 353.599 us; speedup vs baseline: 3.4471x; 1.0182x over previous
//
#include <hip/hip_runtime.h>
#include <hip/hip_bf16.h>

// GraphSAINT 2-layer GCN forward on MI355X.
// Layer 1: xs[n] = bf16(dis[n]*x[n]);  zb[d] = bf16(dis[d]*(sum_e xs[s] + xs[d]));
//          out1b = bf16(zb @ W1 + b1)   (bf16 MFMA; BN partials fused).
// Layer 2: gs[n] = bf16(dis[n]*(relu(bn(out1b[n])) @ W2))  (bf16 MFMA);
//          out[d] = dis[d]*(sum_e gs[s] + gs[d]) + b2  (fp32).
// CSR via 2-level radix sort; sentinel-padded edge lists (row N = zeros).
// Gather kernels batch 4 (aggx) / 2 (agg2) independent row loads per iteration
// to raise memory-level parallelism (latency-bound per R9 counters).

#define IN_F  128
#define HID_F 256
#define OUT_F 64
#define BK_SHIFT 8
#define BK_SIZE  256
#define CHUNK    8192

typedef unsigned int uint;
typedef unsigned short ushort;
typedef short bf16x8 __attribute__((ext_vector_type(8)));
typedef float f32x4 __attribute__((ext_vector_type(4)));

__device__ __forceinline__ ushort f2bf(float f) {
    uint u = __float_as_uint(f);
    uint r = (u + 0x7fffu + ((u >> 16) & 1u)) >> 16;  // RNE
    return (ushort)r;
}
__device__ __forceinline__ float bf_lo(uint u) { return __uint_as_float(u << 16); }
__device__ __forceinline__ float bf_hi(uint u) { return __uint_as_float(u & 0xffff0000u); }

#define ACC8(u)                                         \
    do {                                                \
        acc[0] += bf_lo((u).x); acc[1] += bf_hi((u).x); \
        acc[2] += bf_lo((u).y); acc[3] += bf_hi((u).y); \
        acc[4] += bf_lo((u).z); acc[5] += bf_hi((u).z); \
        acc[6] += bf_lo((u).w); acc[7] += bf_hi((u).w); \
    } while (0)

// --- sort pipeline -----------------------------------------------------------

__global__ void bucket_hist_kernel(const int* __restrict__ dst, int* __restrict__ bhist,
                                   int E, int NB) {
    __shared__ int h[512];
    for (int i = threadIdx.x; i < NB; i += 256) h[i] = 0;
    __syncthreads();
    int base = blockIdx.x * CHUNK;
    int end = min(base + CHUNK, E);
    for (int i = base + threadIdx.x; i < end; i += 256)
        atomicAdd(&h[dst[i] >> BK_SHIFT], 1);
    __syncthreads();
    for (int i = threadIdx.x; i < NB; i += 256)
        if (h[i]) atomicAdd(&bhist[i], h[i]);
}

__global__ void bucket_scan_kernel(const int* __restrict__ bhist, int* __restrict__ bbase,
                                   int* __restrict__ bcursor, int NB, int E) {
    __shared__ int sh[512];
    int t = threadIdx.x;
    int v = (t < NB) ? bhist[t] : 0;
    sh[t] = v;
    __syncthreads();
    for (int off = 1; off < 512; off <<= 1) {
        int u = (t >= off) ? sh[t - off] : 0;
        __syncthreads();
        sh[t] += u;
        __syncthreads();
    }
    if (t < NB) { int b = sh[t] - v; bbase[t] = b; bcursor[t] = b; }
    if (t == 0) bbase[NB] = E;
}

__global__ void bucket_scatter_kernel(const int* __restrict__ src, const int* __restrict__ dst,
                                      int* __restrict__ bcursor, uint* __restrict__ ebuf,
                                      int E, int NB) {
    __shared__ int h[512];
    __shared__ int cur[512];
    for (int i = threadIdx.x; i < NB; i += 256) h[i] = 0;
    __syncthreads();
    int base = blockIdx.x * CHUNK;
    int end = min(base + CHUNK, E);
    for (int i = base + threadIdx.x; i < end; i += 256)
        atomicAdd(&h[dst[i] >> BK_SHIFT], 1);
    __syncthreads();
    for (int i = threadIdx.x; i < NB; i += 256)
        cur[i] = h[i] ? atomicAdd(&bcursor[i], h[i]) : 0;
    __syncthreads();
    for (int i = base + threadIdx.x; i < end; i += 256) {
        int d = dst[i], s = src[i];
        int b = d >> BK_SHIFT;
        int pos = atomicAdd(&cur[b], 1);
        ebuf[pos] = (uint)s | ((uint)(d & (BK_SIZE - 1)) << 24);
    }
}

__global__ void bucket_build_kernel(const uint* __restrict__ ebuf, const int* __restrict__ bbase,
                                    int* __restrict__ deg_e, int* __restrict__ offsets,
                                    float* __restrict__ dis, int* __restrict__ ssrc, int N) {
    __shared__ int cnt[256], off[256], cur[256];
    int b = blockIdx.x;
    int t = threadIdx.x;
    cnt[t] = 0;
    __syncthreads();
    int e0 = bbase[b], e1 = bbase[b + 1];
    for (int i = e0 + t; i < e1; i += 256)
        atomicAdd(&cnt[ebuf[i] >> 24], 1);
    __syncthreads();
    int v = cnt[t];
    int vpad = (v + 3) & ~3;
    off[t] = vpad;
    __syncthreads();
    for (int o = 1; o < 256; o <<= 1) {
        int u = (t >= o) ? off[t - o] : 0;
        __syncthreads();
        off[t] += u;
        __syncthreads();
    }
    int excl = off[t] - vpad;
    int base_pad = e0 + b * 768;
    int d = b * BK_SIZE + t;
    if (d < N) {
        deg_e[d] = vpad;
        offsets[d] = base_pad + excl;
        dis[d] = rsqrtf((float)(v + 1));
    }
    cur[t] = excl;
    __syncthreads();
    for (int i = e0 + t; i < e1; i += 256) {
        uint e = ebuf[i];
        int ld = e >> 24;
        int pos = atomicAdd(&cur[ld], 1);
        ssrc[base_pad + pos] = (int)(e & 0xFFFFFFu);
    }
    __syncthreads();
    for (int i = v; i < vpad; i++)
        ssrc[base_pad + excl + i] = N;
}

// --- prep: weight repack + bf16 x (fused) ------------------------------------
__global__ void prep_kernel(const float* __restrict__ x, const float* __restrict__ dis,
                            uint* __restrict__ xs, const float* __restrict__ W1,
                            const float* __restrict__ W2, ushort* __restrict__ W1bp,
                            ushort* __restrict__ W2bp, int N) {
    int b = blockIdx.x;
    if (b < 192) {
        int i = b * 256 + threadIdx.x;
        if (i < 32768) {
            int kk = i & 31, c = (i >> 5) & 255, kc = i >> 13;
            W1bp[i] = f2bf(W1[(size_t)(kc * 32 + kk) * HID_F + c]);
        } else {
            int j = i - 32768;
            int kk = j & 31, c = (j >> 5) & 63, kc = j >> 11;
            W2bp[j] = f2bf(W2[(size_t)(kc * 32 + kk) * OUT_F + c]);
        }
        return;
    }
    int i = (b - 192) * 256 + threadIdx.x;
    if (i < (N + 1) * (IN_F / 2)) {
        int n = i >> 6;
        if (n >= N) { xs[i] = 0u; return; }
        float dn = dis[n];
        float2 v = ((const float2*)x)[i];
        xs[i] = (uint)f2bf(dn * v.x) | ((uint)f2bf(dn * v.y) << 16);
    }
}

// --- compute pipeline --------------------------------------------------------

// zb[d] = bf16(dis[d]*(sum_e xs[s] + xs[d])).  4 edges/round, batches of 4
// rounds with all 4 row loads in flight (MLP=4).
__global__ void aggx_kernel(const uint* __restrict__ xs, const int* __restrict__ ssrc,
                            const int* __restrict__ offsets, const int* __restrict__ deg_e,
                            const float* __restrict__ dis, uint* __restrict__ zb, int N) {
    int lane = threadIdx.x & 63;
    int n = blockIdx.x * 4 + (threadIdx.x >> 6);
    if (n >= N) return;
    int grp = lane >> 4;
    int ck = lane & 15;
    float acc[8];
#pragma unroll
    for (int i = 0; i < 8; i++) acc[i] = 0.f;
    int start = offsets[n], cnt = deg_e[n];  // cnt % 4 == 0
    for (int base = 0; base < cnt; base += 64) {
        int m = min(64, cnt - base);
        int idx = base + lane;
        int sv = ssrc[start + (idx < cnt ? idx : cnt - 1)];
        int rounds = m >> 2;
        int q = 0;
        for (; q + 4 <= rounds; q += 4) {
            int sA = __shfl(sv, ((q + 0) << 2) | grp);
            int sB = __shfl(sv, ((q + 1) << 2) | grp);
            int sC = __shfl(sv, ((q + 2) << 2) | grp);
            int sD = __shfl(sv, ((q + 3) << 2) | grp);
            uint4 uA = *(const uint4*)(xs + ((size_t)sA << 6) + (ck << 2));
            uint4 uB = *(const uint4*)(xs + ((size_t)sB << 6) + (ck << 2));
            uint4 uC = *(const uint4*)(xs + ((size_t)sC << 6) + (ck << 2));
            uint4 uD = *(const uint4*)(xs + ((size_t)sD << 6) + (ck << 2));
            ACC8(uA); ACC8(uB); ACC8(uC); ACC8(uD);
        }
        for (; q < rounds; q++) {
            int s = __shfl(sv, (q << 2) | grp);
            uint4 u = *(const uint4*)(xs + ((size_t)s << 6) + (ck << 2));
            ACC8(u);
        }
    }
#pragma unroll
    for (int i = 0; i < 8; i++) acc[i] += __shfl_down(acc[i], 32);
#pragma unroll
    for (int i = 0; i < 8; i++) acc[i] += __shfl_down(acc[i], 16);
    if (grp == 0) {
        uint4 u = *(const uint4*)(xs + ((size_t)n << 6) + (ck << 2));  // self
        ACC8(u);
        float dn = dis[n];
        uint4 o;
        o.x = (uint)f2bf(dn * acc[0]) | ((uint)f2bf(dn * acc[1]) << 16);
        o.y = (uint)f2bf(dn * acc[2]) | ((uint)f2bf(dn * acc[3]) << 16);
        o.z = (uint)f2bf(dn * acc[4]) | ((uint)f2bf(dn * acc[5]) << 16);
        o.w = (uint)f2bf(dn * acc[6]) | ((uint)f2bf(dn * acc[7]) << 16);
        *(uint4*)(zb + ((size_t)n << 6) + (ck << 2)) = o;
    }
}

// out1b = bf16(zb @ W1 + b1) + per-block BN partials (no atomics).
__global__ __launch_bounds__(256) void gemm1_kernel(const uint* __restrict__ zb,
                                                    const uint* __restrict__ W1bp,
                                                    const float* __restrict__ b1,
                                                    ushort* __restrict__ out1b,
                                                    float* __restrict__ bnp, int N) {
    __shared__ uint sbuf[8192];  // A tile (16 KB) then C staging (32 KB)
    int t = threadIdx.x;
    int n0 = blockIdx.x * 64;
    for (int i = t; i < 64 * 16; i += 256) {
        int r = i >> 4, q = i & 15;
        int node = n0 + r;
        uint4 v = make_uint4(0u, 0u, 0u, 0u);
        if (node < N) v = *(const uint4*)(zb + (size_t)node * 64 + q * 4);
        int p = q ^ (r & 15);  // XOR swizzle: conflict-free b128
        *(uint4*)(&sbuf[r * 64 + p * 4]) = v;
    }
    __syncthreads();
    int wave = t >> 6, lane = t & 63;
    int quad = lane >> 4, lrow = lane & 15;
    f32x4 acc[4][4];
#pragma unroll
    for (int m = 0; m < 4; m++)
#pragma unroll
        for (int nt = 0; nt < 4; nt++) acc[m][nt] = (f32x4)(0.f);
#pragma unroll
    for (int kc = 0; kc < 4; kc++) {
        bf16x8 bfr[4];
#pragma unroll
        for (int nt = 0; nt < 4; nt++) {
            int c = wave * 64 + nt * 16 + lrow;
            bfr[nt] = *(const bf16x8*)(W1bp + ((size_t)(kc * 256 + c) * 16 + quad * 4));
        }
        bf16x8 afr[4];
#pragma unroll
        for (int m = 0; m < 4; m++) {
            int p = (kc * 4 + quad) ^ lrow;
            afr[m] = *(const bf16x8*)(&sbuf[(m * 16 + lrow) * 64 + p * 4]);
        }
#pragma unroll
        for (int m = 0; m < 4; m++)
#pragma unroll
            for (int nt = 0; nt < 4; nt++)
                acc[m][nt] = __builtin_amdgcn_mfma_f32_16x16x32_bf16(
                    afr[m], bfr[nt], acc[m][nt], 0, 0, 0);
    }
    __syncthreads();  // A reads done; reuse sbuf for C staging
#pragma unroll
    for (int nt = 0; nt < 4; nt++) {
        int c = wave * 64 + nt * 16 + lrow;
        float bb = b1[c];
        float s = 0.f, q = 0.f;
#pragma unroll
        for (int m = 0; m < 4; m++) {
#pragma unroll
            for (int r = 0; r < 4; r++) {
                int row = m * 16 + quad * 4 + r;
                float v = acc[m][nt][r] + bb;
                if (n0 + row < N) { s += v; q = fmaf(v, v, q); }
                uint hv = (uint)f2bf(v);
                uint pv = __shfl_xor(hv, 1);
                if ((lrow & 1) == 0)
                    sbuf[row * 128 + (c >> 1)] = hv | (pv << 16);
            }
        }
        s += __shfl_down(s, 32); q += __shfl_down(q, 32);
        s += __shfl_down(s, 16); q += __shfl_down(q, 16);
        if (quad == 0) {
            bnp[(size_t)blockIdx.x * 512 + c] = s;
            bnp[(size_t)blockIdx.x * 512 + 256 + c] = q;
        }
    }
    __syncthreads();
    uint* out1g = (uint*)out1b;
    for (int i = t; i < 2048; i += 256) {  // 64 rows x 32 uint4
        int row = i >> 5;
        if (n0 + row < N)
            *(uint4*)(out1g + (size_t)(n0 + row) * 128 + (i & 31) * 4) =
                *(const uint4*)(&sbuf[i * 4]);
    }
}

__global__ void bnred1_kernel(const float* __restrict__ bnp, float* __restrict__ bnp2,
                              int nblk) {
    int g = blockIdx.x, t = threadIdx.x;
    float s = 0.f, q = 0.f;
    for (int b = g; b < nblk; b += 32) {
        s += bnp[(size_t)b * 512 + t];
        q += bnp[(size_t)b * 512 + 256 + t];
    }
    bnp2[g * 512 + t] = s;
    bnp2[g * 512 + 256 + t] = q;
}

__global__ void bnred2_kernel(const float* __restrict__ bnp2, const float* __restrict__ gamma,
                              const float* __restrict__ beta, float* __restrict__ bnsb, int N) {
    int t = threadIdx.x;
    float s = 0.f, q = 0.f;
    for (int g = 0; g < 32; g++) {
        s += bnp2[g * 512 + t];
        q += bnp2[g * 512 + 256 + t];
    }
    float invN = 1.0f / (float)N;
    float mean = s * invN;
    float var = q * invN - mean * mean;
    float sc = gamma[t] * rsqrtf(fmaxf(var, 0.f) + 1e-5f);
    bnsb[t] = sc;
    bnsb[256 + t] = beta[t] - mean * sc;
}

// gs = bf16(dis * (relu(bn(out1b)) @ W2)).
__global__ __launch_bounds__(256) void gemm2_kernel(const ushort* __restrict__ out1b,
                                                    const uint* __restrict__ W2bp,
                                                    const float* __restrict__ dis,
                                                    const float* __restrict__ bnsb,
                                                    ushort* __restrict__ gs, int N) {
    __shared__ uint sbuf[8192];
    __shared__ float bns[256], bnb[256];
    const uint* out1u = (const uint*)out1b;
    int t = threadIdx.x;
    int n0 = blockIdx.x * 64;
    if (blockIdx.x == 0 && t < 32) ((uint*)gs)[(size_t)N * 32 + t] = 0u;  // sentinel row
    bns[t] = bnsb[t];
    bnb[t] = bnsb[256 + t];
    __syncthreads();
    for (int i = t; i < 64 * 32; i += 256) {
        int r = i >> 5, q = i & 31;
        int node = n0 + r;
        uint4 v = make_uint4(0u, 0u, 0u, 0u);
        if (node < N) {
            uint4 w = *(const uint4*)(out1u + (size_t)node * 128 + q * 4);
            int c0 = q * 8;
            float r0 = fmaxf(fmaf(bf_lo(w.x), bns[c0 + 0], bnb[c0 + 0]), 0.f);
            float r1 = fmaxf(fmaf(bf_hi(w.x), bns[c0 + 1], bnb[c0 + 1]), 0.f);
            float r2 = fmaxf(fmaf(bf_lo(w.y), bns[c0 + 2], bnb[c0 + 2]), 0.f);
            float r3 = fmaxf(fmaf(bf_hi(w.y), bns[c0 + 3], bnb[c0 + 3]), 0.f);
            float r4 = fmaxf(fmaf(bf_lo(w.z), bns[c0 + 4], bnb[c0 + 4]), 0.f);
            float r5 = fmaxf(fmaf(bf_hi(w.z), bns[c0 + 5], bnb[c0 + 5]), 0.f);
            float r6 = fmaxf(fmaf(bf_lo(w.w), bns[c0 + 6], bnb[c0 + 6]), 0.f);
            float r7 = fmaxf(fmaf(bf_hi(w.w), bns[c0 + 7], bnb[c0 + 7]), 0.f);
            v.x = (uint)f2bf(r0) | ((uint)f2bf(r1) << 16);
            v.y = (uint)f2bf(r2) | ((uint)f2bf(r3) << 16);
            v.z = (uint)f2bf(r4) | ((uint)f2bf(r5) << 16);
            v.w = (uint)f2bf(r6) | ((uint)f2bf(r7) << 16);
        }
        int p = (q & 16) | ((q & 15) ^ (r & 15));  // XOR swizzle (low 4 bits)
        *(uint4*)(&sbuf[r * 128 + p * 4]) = v;
    }
    __syncthreads();
    int wave = t >> 6, lane = t & 63;
    int quad = lane >> 4, lrow = lane & 15;
    int c = wave * 16 + lrow;
    f32x4 acc[4];
#pragma unroll
    for (int m = 0; m < 4; m++) acc[m] = (f32x4)(0.f);
#pragma unroll
    for (int kc = 0; kc < 8; kc++) {
        bf16x8 bfr = *(const bf16x8*)(W2bp + ((size_t)(kc * 64 + c) * 16 + quad * 4));
#pragma unroll
        for (int m = 0; m < 4; m++) {
            int q = kc * 4 + quad;
            int p = (q & 16) | ((q & 15) ^ lrow);
            bf16x8 afr = *(const bf16x8*)(&sbuf[(m * 16 + lrow) * 128 + p * 4]);
            acc[m] = __builtin_amdgcn_mfma_f32_16x16x32_bf16(afr, bfr, acc[m], 0, 0, 0);
        }
    }
    __syncthreads();
#pragma unroll
    for (int m = 0; m < 4; m++) {
#pragma unroll
        for (int r = 0; r < 4; r++) {
            int row = m * 16 + quad * 4 + r;
            int node = n0 + row;
            float dn = (node < N) ? dis[node] : 0.f;
            uint hv = (uint)f2bf(dn * acc[m][r]);
            uint pv = __shfl_xor(hv, 1);
            if ((lrow & 1) == 0)
                sbuf[row * 32 + (c >> 1)] = hv | (pv << 16);
        }
    }
    __syncthreads();
    uint* gsg = (uint*)gs;
    for (int i = t; i < 512; i += 256) {
        int row = i >> 3;
        if (n0 + row < N)
            *(uint4*)(gsg + (size_t)(n0 + row) * 32 + (i & 7) * 4) =
                *(const uint4*)(&sbuf[i * 4]);
    }
}

// out[d] = dis[d]*(sum_e gs[s] + gs[d]) + b2.  8 edges/round, batches of 2
// rounds (MLP=2), sentinel-guarded trailing quad.
__global__ void agg2_kernel(const uint* __restrict__ gs, const int* __restrict__ ssrc,
                            const int* __restrict__ offsets, const int* __restrict__ deg_e,
                            const float* __restrict__ dis, const float* __restrict__ b2,
                            float* __restrict__ out, int N) {
    int lane = threadIdx.x & 63;
    int n = blockIdx.x * 4 + (threadIdx.x >> 6);
    if (n >= N) return;
    int grp = lane >> 3;
    int ck = lane & 7;
    float acc[8];
#pragma unroll
    for (int i = 0; i < 8; i++) acc[i] = 0.f;
    int start = offsets[n], cnt = deg_e[n];  // cnt % 4 == 0
    for (int base = 0; base < cnt; base += 64) {
        int m = min(64, cnt - base);
        int idx = base + lane;
        int sv = ssrc[start + (idx < cnt ? idx : cnt - 1)];
        int rounds = m >> 3;
        int q = 0;
        for (; q + 2 <= rounds; q += 2) {
            int sA = __shfl(sv, ((q + 0) << 3) | grp);
            int sB = __shfl(sv, ((q + 1) << 3) | grp);
            uint4 uA = *(const uint4*)(gs + ((size_t)sA << 5) + (ck << 2));
            uint4 uB = *(const uint4*)(gs + ((size_t)sB << 5) + (ck << 2));
            ACC8(uA); ACC8(uB);
        }
        for (; q < rounds; q++) {
            int s = __shfl(sv, (q << 3) | grp);
            uint4 u = *(const uint4*)(gs + ((size_t)s << 5) + (ck << 2));
            ACC8(u);
        }
        if (m & 4) {  // trailing quad: groups 0..3 one edge each, 4..7 sentinel
            int s = __shfl(sv, (rounds << 3) | (grp & 3));
            s = (grp & 4) ? N : s;
            uint4 u = *(const uint4*)(gs + ((size_t)s << 5) + (ck << 2));
            ACC8(u);
        }
    }
#pragma unroll
    for (int i = 0; i < 8; i++) acc[i] += __shfl_down(acc[i], 32);
#pragma unroll
    for (int i = 0; i < 8; i++) acc[i] += __shfl_down(acc[i], 16);
#pragma unroll
    for (int i = 0; i < 8; i++) acc[i] += __shfl_down(acc[i], 8);
    if (grp == 0) {
        uint4 u = *(const uint4*)(gs + ((size_t)n << 5) + (ck << 2));  // self
        ACC8(u);
        float dn = dis[n];
        float4 bb0 = *(const float4*)(b2 + ck * 8);
        float4 bb1 = *(const float4*)(b2 + ck * 8 + 4);
        float* op = out + (size_t)n * OUT_F + ck * 8;
        *(float4*)op = make_float4(fmaf(dn, acc[0], bb0.x), fmaf(dn, acc[1], bb0.y),
                                   fmaf(dn, acc[2], bb0.z), fmaf(dn, acc[3], bb0.w));
        *(float4*)(op + 4) = make_float4(fmaf(dn, acc[4], bb1.x), fmaf(dn, acc[5], bb1.y),
                                         fmaf(dn, acc[6], bb1.z), fmaf(dn, acc[7], bb1.w));
    }
}

extern "C" void kernel_launch(void* const* d_in, const int* in_sizes, int n_in,
                              void* d_out, int out_size, void* d_ws, size_t ws_size,
                              hipStream_t stream) {
    const float* x      = (const float*)d_in[0];
    const int*   edges  = (const int*)d_in[1];
    const float* W1     = (const float*)d_in[2];
    const float* b1     = (const float*)d_in[3];
    const float* gamma1 = (const float*)d_in[4];
    const float* beta1  = (const float*)d_in[5];
    const float* W2     = (const float*)d_in[6];
    const float* b2     = (const float*)d_in[7];
    float* out = (float*)d_out;

    int N = in_sizes[0] / IN_F;
    int E = in_sizes[1] / 2;
    const int* src = edges;
    const int* dst = edges + E;
    int NB = (N + BK_SIZE - 1) / BK_SIZE;
    int nchunks = (E + CHUNK - 1) / CHUNK;
    int nblk1 = (N + 63) / 64;

    char* ws = (char*)d_ws;
    size_t off = 0;
    auto alloc = [&](size_t bytes) -> void* {
        void* p = ws + off;
        off += (bytes + 255) & ~(size_t)255;
        return p;
    };
    int*    deg_e   = (int*)alloc((size_t)N * 4);
    int*    offsets = (int*)alloc((size_t)N * 4);
    float*  dis     = (float*)alloc((size_t)(N + 1) * 4);
    int*    bhist   = (int*)alloc(512 * 4);
    int*    bbase   = (int*)alloc(513 * 4);
    int*    bcursor = (int*)alloc(512 * 4);
    int*    ssrc    = (int*)alloc(((size_t)E + 768 * 512 + 64) * 4);  // padded CSR
    uint*   ebuf    = (uint*)alloc((size_t)E * 4);
    uint*   xs      = (uint*)alloc((size_t)(N + 1) * (IN_F / 2) * 4); // +sentinel row
    uint*   zb      = (uint*)alloc((size_t)N * (IN_F / 2) * 4);
    ushort* out1b   = (ushort*)alloc((size_t)N * HID_F * 2);
    float*  bnp     = (float*)alloc((size_t)nblk1 * 512 * 4);         // block partials
    float*  bnp2    = (float*)alloc(32 * 512 * 4);
    float*  bnsb    = (float*)alloc(512 * 4);                         // scale | bias
    ushort* W1bp    = (ushort*)alloc(4 * 256 * 32 * 2);
    ushort* W2bp    = (ushort*)alloc(8 * 64 * 32 * 2);
    ushort* gs      = (ushort*)zb;  // alias: zb dead after gemm1; (N+1) rows x 64 bf16

    hipMemsetAsync(bhist, 0, 512 * 4, stream);

    bucket_hist_kernel<<<nchunks, 256, 0, stream>>>(dst, bhist, E, NB);
    bucket_scan_kernel<<<1, 512, 0, stream>>>(bhist, bbase, bcursor, NB, E);
    bucket_scatter_kernel<<<nchunks, 256, 0, stream>>>(src, dst, bcursor, ebuf, E, NB);
    bucket_build_kernel<<<NB, 256, 0, stream>>>(ebuf, bbase, deg_e, offsets, dis, ssrc, N);

    int xblocks = ((N + 1) * (IN_F / 2) + 255) / 256;
    prep_kernel<<<192 + xblocks, 256, 0, stream>>>(x, dis, xs, W1, W2, W1bp, W2bp, N);
    aggx_kernel<<<(N + 3) / 4, 256, 0, stream>>>(xs, ssrc, offsets, deg_e, dis, zb, N);
    gemm1_kernel<<<nblk1, 256, 0, stream>>>(zb, (const uint*)W1bp, b1, out1b, bnp, N);
    bnred1_kernel<<<32, 256, 0, stream>>>(bnp, bnp2, nblk1);
    bnred2_kernel<<<1, 256, 0, stream>>>(bnp2, gamma1, beta1, bnsb, N);
    gemm2_kernel<<<nblk1, 256, 0, stream>>>(out1b, (const uint*)W2bp, dis, bnsb, gs, N);
    agg2_kernel<<<(N + 3) / 4, 256, 0, stream>>>((const uint*)gs, ssrc, offsets, deg_e, dis,
                                                 b2, out, N);
}